// Round 4
// baseline (4273.056 us; speedup 1.0000x reference)
//
#include <hip/hip_runtime.h>
#include <hip/hip_bf16.h>

typedef unsigned short u16;
typedef unsigned int   u32;
typedef __attribute__((ext_vector_type(8))) short bf16x8;
typedef __attribute__((ext_vector_type(4))) float f32x4;

#define CH   192
#define NH   8
#define HWD  256
#define LDW  200   // bf16 row stride for 192-wide LDS tiles (400B)
#define LDK  40    // bf16 row stride for 24-wide V rows
#define QSTR 28
#define SCALE 0.20412414523193154f

__device__ __forceinline__ float bf2f(u16 u){ u32 v = ((u32)u) << 16; return __builtin_bit_cast(float, v); }
__device__ __forceinline__ u16 f2bf(float f){
  u32 u = __builtin_bit_cast(u32, f);
  u = (u + 0x7fffu + ((u >> 16) & 1u)) >> 16;
  return (u16)u;
}
__device__ __forceinline__ float lo2f(u32 p){ return __builtin_bit_cast(float, p << 16); }
__device__ __forceinline__ float hi2f(u32 p){ return __builtin_bit_cast(float, p & 0xffff0000u); }
__device__ __forceinline__ void up8(uint4 q, float* f){
  f[0]=lo2f(q.x); f[1]=hi2f(q.x); f[2]=lo2f(q.y); f[3]=hi2f(q.y);
  f[4]=lo2f(q.z); f[5]=hi2f(q.z); f[6]=lo2f(q.w); f[7]=hi2f(q.w);
}
__device__ __forceinline__ void ldw8(const float* __restrict__ p, float* f){
  float4 a = *reinterpret_cast<const float4*>(p);
  float4 b = *reinterpret_cast<const float4*>(p + 4);
  f[0]=a.x; f[1]=a.y; f[2]=a.z; f[3]=a.w;
  f[4]=b.x; f[5]=b.y; f[6]=b.z; f[7]=b.w;
}
__device__ __forceinline__ int refl(int v){ v = v < 0 ? -v : v; return v < HWD ? v : 2*(HWD-1) - v; }
__device__ __forceinline__ f32x4 mfma16(bf16x8 a, bf16x8 b, f32x4 c){
  return __builtin_amdgcn_mfma_f32_16x16x32_bf16(a, b, c, 0, 0, 0);
}
__device__ __forceinline__ bf16x8 afrag(const u16* pool, int base, int stride, int row, int kt, int l){
  return *reinterpret_cast<const bf16x8*>(pool + base + row*stride + kt*32 + ((l>>4)<<3));
}
__device__ __forceinline__ bf16x8 bfrag(const u16* __restrict__ w, int tile, int l){
  return *reinterpret_cast<const bf16x8*>(w + tile*512 + l*8);
}
__device__ __forceinline__ void ln_stats(const u16* buf, float* st, int tid){
  int r = tid >> 3, sub = tid & 7;
  const uint4* rp = reinterpret_cast<const uint4*>(buf + r*LDW + sub*24);
  float v[24]; up8(rp[0], v); up8(rp[1], v+8); up8(rp[2], v+16);
  float s = 0.f, s2 = 0.f;
  #pragma unroll
  for (int e = 0; e < 24; ++e){ s += v[e]; s2 += v[e]*v[e]; }
  s  += __shfl_xor(s, 1, 64);  s  += __shfl_xor(s, 2, 64);  s  += __shfl_xor(s, 4, 64);
  s2 += __shfl_xor(s2, 1, 64); s2 += __shfl_xor(s2, 2, 64); s2 += __shfl_xor(s2, 4, 64);
  if (sub == 0){
    float m = s*(1.f/192.f);
    float var = s2*(1.f/192.f) - m*m;
    st[r*2] = m; st[r*2+1] = rsqrtf(var + 1e-5f);
  }
}

// ---------------- workspace layout (bytes) ----------------
#define WS_KV   ((size_t)0)                     // 2*65536*384 bf16 = 100,663,296
#define WS_W1   ((size_t)100663296)
#define WS_WKV  (WS_W1  + 221184)
#define WS_WQ   (WS_WKV + 147456)
#define WS_WP   (WS_WQ  + 73728)
#define WS_WM1  (WS_WP  + 73728)
#define WS_WM2  (WS_WM1 + 147456)
#define WS_WO   (WS_WM2 + 147456)
#define WS_C1   (WS_WO  + 73728)
#define WS_C2   (WS_C1  + 2304)
#define WS_C1O  (WS_C2  + 2304)
#define WS_C2O  (WS_C1O + 768)
#define WS_C1M  (WS_C2O + 768)
#define WS_C2M  (WS_C1M + 1536)
#define WS_NEED (WS_C2M + 1536)                 // = 101,557,248
#define WS_XOCA WS_NEED                         // [2048][192][64] bf16 = 50,331,648
#define WS_NEED1 (WS_XOCA + 50331648)

// ---------------- prep kernels ----------------
__global__ void k_swz(const float* __restrict__ src, const float* __restrict__ gv,
                      u16* __restrict__ dst, int KT, int K){
  int tile = blockIdx.x; int nt = tile / KT, kt = tile - nt*KT;
  int l = threadIdx.x;
  int row = nt*16 + (l & 15);
  int kb  = kt*32 + ((l>>4)<<3);
  const float* s = src + (size_t)row*K + kb;
  u16* d = dst + (size_t)tile*512 + l*8;
  #pragma unroll
  for (int e = 0; e < 8; ++e){
    float w = s[e];
    if (gv) w *= gv[kb + e];
    d[e] = f2bf(w);
  }
}
__global__ void k_cvec(const float* __restrict__ W, const float* __restrict__ g,
                       const float* __restrict__ b, float* __restrict__ c1,
                       float* __restrict__ c2, int K){
  int n = blockIdx.x; int l = threadIdx.x;
  float s1 = 0.f, s2 = 0.f;
  for (int k = l; k < K; k += 64){
    float w = W[(size_t)n*K + k];
    s1 += w*g[k]; s2 += w*b[k];
  }
  #pragma unroll
  for (int d = 1; d < 64; d <<= 1){ s1 += __shfl_xor(s1, d, 64); s2 += __shfl_xor(s2, d, 64); }
  if (l == 0){ c1[n] = s1; c2[n] = s2; }
}

// ---------------- k_kv: per-pixel KV GEMM (dedup of unfold) ----------------
__global__ __launch_bounds__(512) void k_kv(const float* __restrict__ x,
                                            const u16* __restrict__ wkv,
                                            u16* __restrict__ KV){
  __shared__ __align__(16) u16 sA[64*LDW];
  const int blk = blockIdx.x;                // 2048
  const int batch = blk >> 10;
  const int pix0 = (blk & 1023) * 64;
  const float* xb = x + (size_t)batch*CH*65536;

  for (int idx = threadIdx.x; idx < 1536; idx += 512){
    int c = idx >> 3, s = idx & 7;
    const float* p = xb + (size_t)c*65536 + pix0 + s*8;
    float4 a = *reinterpret_cast<const float4*>(p);
    float4 b = *reinterpret_cast<const float4*>(p + 4);
    u16* d = &sA[(s*8)*LDW + c];
    d[0*LDW]=f2bf(a.x); d[1*LDW]=f2bf(a.y); d[2*LDW]=f2bf(a.z); d[3*LDW]=f2bf(a.w);
    d[4*LDW]=f2bf(b.x); d[5*LDW]=f2bf(b.y); d[6*LDW]=f2bf(b.z); d[7*LDW]=f2bf(b.w);
  }
  __syncthreads();

  const int w = threadIdx.x >> 6, l = threadIdx.x & 63;
  const int mt = w >> 1, half = w & 1;
  const f32x4 z4 = {0.f,0.f,0.f,0.f};
  f32x4 acc[12];
  #pragma unroll
  for (int j = 0; j < 12; ++j) acc[j] = z4;
  const int arow = mt*16 + (l & 15);
  for (int kt = 0; kt < 6; ++kt){
    bf16x8 a = afrag(sA, 0, LDW, arow, kt, l);
    #pragma unroll
    for (int j = 0; j < 12; ++j){
      int nt = half*12 + j;
      acc[j] = mfma16(a, bfrag(wkv, nt*6 + kt, l), acc[j]);
    }
  }
  u16* kvb = KV + ((size_t)batch*65536 + pix0)*384;
  const int rbase = mt*16 + ((l>>4)<<2);
  #pragma unroll
  for (int j = 0; j < 12; ++j){
    int col = (half*12 + j)*16 + (l & 15);
    #pragma unroll
    for (int r = 0; r < 4; ++r)
      kvb[(size_t)(rbase + r)*384 + col] = f2bf(acc[j][r]);
  }
}

// ---------------- k_oca_attn: cross attention; MODE0: out = x + beta*x_oca; MODE1: x_oca -> ws ----------------
#define OW_  0        // [64][200] u16: x window
#define OQ_  12800    // [64][200] u16: q; per-head slice overwritten by attn-out
#define OKF  25600    // f32 K [144][28] = 8064 u16
#define OVB  33664    // u16 V [144][40] = 5760 u16
#define XO_  25600    // x_oca [64][200] u16 (reuses K/V region post-attention)
#define OST_ 39424    // 128 f32 stats
#define OPOOLN 39680  // 79,360 bytes

template<int MODE>
__global__ __launch_bounds__(512, 4) void k_oca_attn(
    const float* __restrict__ x, const u16* __restrict__ ws16, const float* __restrict__ wsf,
    const float* __restrict__ alpha_p, float* __restrict__ out, u16* __restrict__ xoca)
{
  __shared__ __align__(16) u16 pool[OPOOLN];
  float* st = reinterpret_cast<float*>(pool + OST_);
  float* sK = reinterpret_cast<float*>(pool + OKF);
  const u16* KV = ws16 + WS_KV/2;
  const u16* WQ = ws16 + WS_WQ/2;
  const u16* WO = ws16 + WS_WO/2;
  const float* c1o = wsf + WS_C1O/4;
  const float* c2o = wsf + WS_C2O/4;

  const int tid = threadIdx.x;
  const int win = blockIdx.x;
  const int b  = win >> 10;
  const int wy = (win >> 5) & 31;
  const int wx = win & 31;
  const int hrow = wy*8, wcol = wx*8;
  const float* xb = x + (size_t)b*CH*HWD*HWD;
  float* outb = out + (size_t)b*CH*HWD*HWD;
  const size_t pixBase = (size_t)b*65536;

  // P0: window -> OW bf16
  for (int j = tid; j < 1536; j += 512){
    int c = j >> 3, ty = j & 7;
    const float* src = xb + ((size_t)c*HWD + hrow + ty)*HWD + wcol;
    float4 a = *reinterpret_cast<const float4*>(src);
    float4 q = *reinterpret_cast<const float4*>(src + 4);
    u16* dst = &pool[OW_ + (ty*8)*LDW + c];
    dst[0*LDW]=f2bf(a.x); dst[1*LDW]=f2bf(a.y); dst[2*LDW]=f2bf(a.z); dst[3*LDW]=f2bf(a.w);
    dst[4*LDW]=f2bf(q.x); dst[5*LDW]=f2bf(q.y); dst[6*LDW]=f2bf(q.z); dst[7*LDW]=f2bf(q.w);
  }
  __syncthreads();
  ln_stats(pool + OW_, st, tid);
  __syncthreads();

  const int w = tid >> 6, l = tid & 63;
  const int mt = w >> 1, half = w & 1;
  const int arow = mt*16 + (l & 15);
  const int rbase = mt*16 + ((l>>4)<<2);
  const f32x4 z4 = {0.f,0.f,0.f,0.f};

  // P1: q = rs*(x @ Wq'^T - m*c1o) + c2o -> OQ
  {
    f32x4 acc[6];
    #pragma unroll
    for (int j = 0; j < 6; ++j) acc[j] = z4;
    for (int kt = 0; kt < 6; ++kt){
      bf16x8 a = afrag(pool, OW_, LDW, arow, kt, l);
      #pragma unroll
      for (int j = 0; j < 6; ++j)
        acc[j] = mfma16(a, bfrag(WQ, (half*6 + j)*6 + kt, l), acc[j]);
    }
    float mr[4], rr[4];
    #pragma unroll
    for (int r = 0; r < 4; ++r){ mr[r] = st[(rbase+r)*2]; rr[r] = st[(rbase+r)*2+1]; }
    #pragma unroll
    for (int j = 0; j < 6; ++j){
      int col = (half*6 + j)*16 + (l & 15);
      float c1v = c1o[col], c2v = c2o[col];
      #pragma unroll
      for (int r = 0; r < 4; ++r)
        pool[OQ_ + (rbase + r)*LDW + col] = f2bf(rr[r]*(acc[j][r] - mr[r]*c1v) + c2v);
    }
  }
  __syncthreads();

  const int t8 = tid >> 3, s8 = tid & 7;
  for (int h = 0; h < NH; ++h){
    // stage K (f32) and V (bf16) for this head from KV workspace
    for (int i = tid; i < 432; i += 512){
      int tok = i / 3, seg = i - tok*3;
      int ti = tok / 12, tj = tok - ti*12;
      int pix = refl(hrow + ti - 2)*HWD + refl(wcol + tj - 2);
      const u16* src = KV + (pixBase + (size_t)pix)*384 + h*24 + seg*8;
      uint4 kk = *reinterpret_cast<const uint4*>(src);
      uint4 vv = *reinterpret_cast<const uint4*>(src + 192);
      float kf[8]; up8(kk, kf);
      float4* kd = reinterpret_cast<float4*>(sK + tok*28 + seg*8);
      kd[0] = make_float4(kf[0],kf[1],kf[2],kf[3]);
      kd[1] = make_float4(kf[4],kf[5],kf[6],kf[7]);
      *reinterpret_cast<uint4*>(pool + OVB + tok*LDK + seg*8) = vv;
    }
    __syncthreads();
    {
      float q24[24];
      #pragma unroll
      for (int seg = 0; seg < 3; ++seg){
        uint4 v = *reinterpret_cast<const uint4*>(pool + OQ_ + t8*LDW + h*24 + seg*8);
        up8(v, q24 + seg*8);
      }
      float p[18];
      #pragma unroll
      for (int j = 0; j < 18; ++j){
        int c = s8*18 + j;
        const float4* kr = reinterpret_cast<const float4*>(sK + c*28);
        float s = 0.f;
        #pragma unroll
        for (int e4 = 0; e4 < 6; ++e4){
          float4 kk = kr[e4];
          s += q24[e4*4+0]*kk.x + q24[e4*4+1]*kk.y + q24[e4*4+2]*kk.z + q24[e4*4+3]*kk.w;
        }
        p[j] = s*SCALE;
      }
      float mx = p[0];
      #pragma unroll
      for (int j = 1; j < 18; ++j) mx = fmaxf(mx, p[j]);
      mx = fmaxf(mx, __shfl_xor(mx, 1, 64));
      mx = fmaxf(mx, __shfl_xor(mx, 2, 64));
      mx = fmaxf(mx, __shfl_xor(mx, 4, 64));
      float sum = 0.f;
      #pragma unroll
      for (int j = 0; j < 18; ++j){ p[j] = __expf(p[j] - mx); sum += p[j]; }
      sum += __shfl_xor(sum, 1, 64); sum += __shfl_xor(sum, 2, 64); sum += __shfl_xor(sum, 4, 64);
      float inv = 1.f / sum;
      float o24[24];
      #pragma unroll
      for (int e = 0; e < 24; ++e) o24[e] = 0.f;
      #pragma unroll
      for (int j = 0; j < 18; ++j){
        int c = s8*18 + j;
        float v24[24];
        #pragma unroll
        for (int seg = 0; seg < 3; ++seg){
          uint4 v = *reinterpret_cast<const uint4*>(pool + OVB + c*LDK + seg*8);
          up8(v, v24 + seg*8);
        }
        #pragma unroll
        for (int e = 0; e < 24; ++e) o24[e] += p[j]*v24[e];
      }
      #pragma unroll
      for (int e = 0; e < 24; ++e){
        o24[e] += __shfl_xor(o24[e], 1, 64);
        o24[e] += __shfl_xor(o24[e], 2, 64);
        o24[e] += __shfl_xor(o24[e], 4, 64);
      }
      // overwrite this head's (dead) q-slice with attention output.
      // Safe: the 8 threads touching row t8 are one wave; q24 reads precede
      // these writes in program order.
      u16* orow = &pool[OQ_ + t8*LDW + h*24 + s8*3];
      #pragma unroll
      for (int o = 0; o < 3; ++o) orow[o] = f2bf(o24[s8*3 + o]*inv);
    }
    __syncthreads();
  }

  // P4: x_oca = attn @ oproj^T + x -> XO_ (reuses K/V region)
  {
    f32x4 acc[6];
    #pragma unroll
    for (int j = 0; j < 6; ++j) acc[j] = z4;
    for (int kt = 0; kt < 6; ++kt){
      bf16x8 a = afrag(pool, OQ_, LDW, arow, kt, l);
      #pragma unroll
      for (int j = 0; j < 6; ++j)
        acc[j] = mfma16(a, bfrag(WO, (half*6 + j)*6 + kt, l), acc[j]);
    }
    #pragma unroll
    for (int j = 0; j < 6; ++j){
      int col = (half*6 + j)*16 + (l & 15);
      #pragma unroll
      for (int r = 0; r < 4; ++r){
        int row = rbase + r;
        pool[XO_ + row*LDW + col] = f2bf(acc[j][r] + bf2f(pool[OW_ + row*LDW + col]));
      }
    }
  }
  __syncthreads();

  if (MODE == 0){
    // out = x + (1-alpha) * x_oca   (pure write; k_msa RMWs later)
    float beta = 1.f - alpha_p[0];
    for (int j = tid; j < 1536; j += 512){
      int c = j >> 3, ty = j & 7;
      size_t goff = ((size_t)c*HWD + hrow + ty)*HWD + wcol;
      const float* src = xb + goff;
      float4 a = *reinterpret_cast<const float4*>(src);
      float4 q = *reinterpret_cast<const float4*>(src + 4);
      float wv[8];
      #pragma unroll
      for (int e = 0; e < 8; ++e) wv[e] = bf2f(pool[XO_ + (ty*8 + e)*LDW + c]);
      float4 o1 = make_float4(a.x + beta*wv[0], a.y + beta*wv[1], a.z + beta*wv[2], a.w + beta*wv[3]);
      float4 o2 = make_float4(q.x + beta*wv[4], q.y + beta*wv[5], q.z + beta*wv[6], q.w + beta*wv[7]);
      *reinterpret_cast<float4*>(outb + goff)     = o1;
      *reinterpret_cast<float4*>(outb + goff + 4) = o2;
    }
  } else {
    // x_oca -> ws, channel-major [192][64] bf16 per window (coalesced full lines)
    u16* xw = xoca + (size_t)win*12288;
    for (int j = tid; j < 1536; j += 512){
      int c = j >> 3, ty = j & 7;
      u32 wds[4];
      #pragma unroll
      for (int e = 0; e < 4; ++e){
        u32 lo = pool[XO_ + (ty*8 + 2*e  )*LDW + c];
        u32 hi = pool[XO_ + (ty*8 + 2*e+1)*LDW + c];
        wds[e] = lo | (hi << 16);
      }
      uint4 o; o.x = wds[0]; o.y = wds[1]; o.z = wds[2]; o.w = wds[3];
      *reinterpret_cast<uint4*>(xw + c*64 + ty*8) = o;
    }
  }
}

// ---------------- k_msa: window MSA + MLP (MFMA); final combine ----------------
#define SX   0
#define SN   12800
#define SQKV 25600
#define SG   25600
#define SM   62464
#define SST  75264
#define POOLSZ 75520

template<int MODE>
__global__ __launch_bounds__(512) void k_msa(
    const float* __restrict__ x, const u16* __restrict__ ws16, const float* __restrict__ wsf,
    const float* __restrict__ rpe, const float* __restrict__ alpha_p, float* __restrict__ out,
    const u16* __restrict__ xoca)
{
  __shared__ __align__(16) u16 pool[POOLSZ];
  float* st = reinterpret_cast<float*>(pool + SST);
  const u16* W1  = ws16 + WS_W1/2;
  const u16* WP  = ws16 + WS_WP/2;
  const u16* WM1 = ws16 + WS_WM1/2;
  const u16* WM2 = ws16 + WS_WM2/2;
  const float* c1  = wsf + WS_C1/4;
  const float* c2  = wsf + WS_C2/4;
  const float* c1m = wsf + WS_C1M/4;
  const float* c2m = wsf + WS_C2M/4;

  const int tid = threadIdx.x;
  const int win = blockIdx.x;
  const int b  = win >> 10;
  const int wy = (win >> 5) & 31;
  const int wx = win & 31;
  const int hrow = wy*8, wcol = wx*8;
  const float* xb = x + (size_t)b*CH*HWD*HWD;
  float* outb = out + (size_t)b*CH*HWD*HWD;

  // P0: window -> sX bf16
  for (int j = tid; j < 1536; j += 512){
    int c = j >> 3, ty = j & 7;
    const float* src = xb + ((size_t)c*HWD + hrow + ty)*HWD + wcol;
    float4 a = *reinterpret_cast<const float4*>(src);
    float4 q = *reinterpret_cast<const float4*>(src + 4);
    u16* dst = &pool[SX + (ty*8)*LDW + c];
    dst[0*LDW]=f2bf(a.x); dst[1*LDW]=f2bf(a.y); dst[2*LDW]=f2bf(a.z); dst[3*LDW]=f2bf(a.w);
    dst[4*LDW]=f2bf(q.x); dst[5*LDW]=f2bf(q.y); dst[6*LDW]=f2bf(q.z); dst[7*LDW]=f2bf(q.w);
  }
  __syncthreads();
  ln_stats(pool + SX, st, tid);
  __syncthreads();

  const int w = tid >> 6, l = tid & 63;
  const int mt = w >> 1, half = w & 1;
  const int arow = mt*16 + (l & 15);
  const int rbase = mt*16 + ((l>>4)<<2);
  const f32x4 z4 = {0.f,0.f,0.f,0.f};

  // P2a: qkv (LN folded), N=576
  {
    f32x4 acc[18];
    #pragma unroll
    for (int j = 0; j < 18; ++j) acc[j] = z4;
    for (int kt = 0; kt < 6; ++kt){
      bf16x8 a = afrag(pool, SX, LDW, arow, kt, l);
      #pragma unroll
      for (int j = 0; j < 18; ++j)
        acc[j] = mfma16(a, bfrag(W1, (half*18 + j)*6 + kt, l), acc[j]);
    }
    float mr[4], rr[4];
    #pragma unroll
    for (int r = 0; r < 4; ++r){ mr[r] = st[(rbase+r)*2]; rr[r] = st[(rbase+r)*2+1]; }
    #pragma unroll
    for (int j = 0; j < 18; ++j){
      int col = (half*18 + j)*16 + (l & 15);
      float c1v = c1[col], c2v = c2[col];
      #pragma unroll
      for (int r = 0; r < 4; ++r){
        int row = rbase + r;
        float v = rr[r]*(acc[j][r] - mr[r]*c1v) + c2v;
        pool[SQKV + row*576 + (col ^ (((row>>3)&7)<<3))] = f2bf(v);
      }
    }
  }
  __syncthreads();

  // P2b: attention (XOR-swizzled qkv reads)
  {
    const int t8 = tid >> 3, s8 = tid & 7;
    const int ry = t8 >> 3, rx = t8 & 7;
    const int swq = ((t8 >> 3) & 7) << 3;
    const int swk = s8 << 3;
    for (int h = 0; h < NH; ++h){
      float q24[24];
      #pragma unroll
      for (int seg = 0; seg < 3; ++seg){
        uint4 v = *reinterpret_cast<const uint4*>(pool + SQKV + t8*576 + ((h*24 + seg*8) ^ swq));
        up8(v, q24 + seg*8);
      }
      float p[8];
      #pragma unroll
      for (int j = 0; j < 8; ++j){
        int c = s8*8 + j;
        float k24[24];
        #pragma unroll
        for (int seg = 0; seg < 3; ++seg){
          uint4 v = *reinterpret_cast<const uint4*>(pool + SQKV + c*576 + ((192 + h*24 + seg*8) ^ swk));
          up8(v, k24 + seg*8);
        }
        float s = 0.f;
        #pragma unroll
        for (int e = 0; e < 24; ++e) s += q24[e]*k24[e];
        int cy = c >> 3, cx = c & 7;
        p[j] = s*SCALE + rpe[((ry-cy+7)*15 + (rx-cx+7))*NH + h];
      }
      float mx = p[0];
      #pragma unroll
      for (int j = 1; j < 8; ++j) mx = fmaxf(mx, p[j]);
      mx = fmaxf(mx, __shfl_xor(mx, 1, 64));
      mx = fmaxf(mx, __shfl_xor(mx, 2, 64));
      mx = fmaxf(mx, __shfl_xor(mx, 4, 64));
      float sum = 0.f;
      #pragma unroll
      for (int j = 0; j < 8; ++j){ p[j] = __expf(p[j] - mx); sum += p[j]; }
      sum += __shfl_xor(sum, 1, 64); sum += __shfl_xor(sum, 2, 64); sum += __shfl_xor(sum, 4, 64);
      float inv = 1.f / sum;
      float o24[24];
      #pragma unroll
      for (int e = 0; e < 24; ++e) o24[e] = 0.f;
      #pragma unroll
      for (int j = 0; j < 8; ++j){
        int c = s8*8 + j;
        float v24[24];
        #pragma unroll
        for (int seg = 0; seg < 3; ++seg){
          uint4 v = *reinterpret_cast<const uint4*>(pool + SQKV + c*576 + ((384 + h*24 + seg*8) ^ swk));
          up8(v, v24 + seg*8);
        }
        #pragma unroll
        for (int e = 0; e < 24; ++e) o24[e] += p[j]*v24[e];
      }
      #pragma unroll
      for (int e = 0; e < 24; ++e){
        o24[e] += __shfl_xor(o24[e], 1, 64);
        o24[e] += __shfl_xor(o24[e], 2, 64);
        o24[e] += __shfl_xor(o24[e], 4, 64);
      }
      u16* mrow = &pool[SM + t8*LDW + h*24 + s8*3];
      #pragma unroll
      for (int o = 0; o < 3; ++o) mrow[o] = f2bf(o24[s8*3 + o]*inv);
    }
  }
  __syncthreads();

  // P3: xw2 = msa @ wproj^T + x -> sN
  {
    f32x4 acc[6];
    #pragma unroll
    for (int j = 0; j < 6; ++j) acc[j] = z4;
    for (int kt = 0; kt < 6; ++kt){
      bf16x8 a = afrag(pool, SM, LDW, arow, kt, l);
      #pragma unroll
      for (int j = 0; j < 6; ++j)
        acc[j] = mfma16(a, bfrag(WP, (half*6 + j)*6 + kt, l), acc[j]);
    }
    #pragma unroll
    for (int j = 0; j < 6; ++j){
      int col = (half*6 + j)*16 + (l & 15);
      #pragma unroll
      for (int r = 0; r < 4; ++r){
        int row = rbase + r;
        pool[SN + row*LDW + col] = f2bf(acc[j][r] + bf2f(pool[SX + row*LDW + col]));
      }
    }
  }
  __syncthreads();
  ln_stats(pool + SN, st, tid);
  __syncthreads();

  // P5: gelu(LN2-folded mlp1) -> sG
  {
    f32x4 acc[12];
    #pragma unroll
    for (int j = 0; j < 12; ++j) acc[j] = z4;
    for (int kt = 0; kt < 6; ++kt){
      bf16x8 a = afrag(pool, SN, LDW, arow, kt, l);
      #pragma unroll
      for (int j = 0; j < 12; ++j)
        acc[j] = mfma16(a, bfrag(WM1, (half*12 + j)*6 + kt, l), acc[j]);
    }
    float mr[4], rr[4];
    #pragma unroll
    for (int r = 0; r < 4; ++r){ mr[r] = st[(rbase+r)*2]; rr[r] = st[(rbase+r)*2+1]; }
    #pragma unroll
    for (int j = 0; j < 12; ++j){
      int col = (half*12 + j)*16 + (l & 15);
      float c1v = c1m[col], c2v = c2m[col];
      #pragma unroll
      for (int r = 0; r < 4; ++r){
        float hv = rr[r]*(acc[j][r] - mr[r]*c1v) + c2v;
        float gl = 0.5f*hv*(1.f + erff(hv*0.70710678118654752f));
        pool[SG + (rbase + r)*392 + col] = f2bf(gl);
      }
    }
  }
  __syncthreads();

  // P6: x_win = gelu @ mlp2^T + xw2 -> sM
  {
    f32x4 acc[6];
    #pragma unroll
    for (int j = 0; j < 6; ++j) acc[j] = z4;
    for (int kt = 0; kt < 12; ++kt){
      bf16x8 a = afrag(pool, SG, 392, arow, kt, l);
      #pragma unroll
      for (int j = 0; j < 6; ++j)
        acc[j] = mfma16(a, bfrag(WM2, (half*6 + j)*12 + kt, l), acc[j]);
    }
    #pragma unroll
    for (int j = 0; j < 6; ++j){
      int col = (half*6 + j)*16 + (l & 15);
      #pragma unroll
      for (int r = 0; r < 4; ++r){
        int row = rbase + r;
        pool[SM + row*LDW + col] = f2bf(acc[j][r] + bf2f(pool[SN + row*LDW + col]));
      }
    }
  }
  __syncthreads();

  // P7: final combine
  float alpha = alpha_p[0];
  if (MODE == 0){
    // out already = x + beta*x_oca; add alpha*x_win
    for (int j = tid; j < 1536; j += 512){
      int c = j >> 3, ty = j & 7;
      size_t goff = ((size_t)c*HWD + hrow + ty)*HWD + wcol;
      float* dst = outb + goff;
      float4 a = *reinterpret_cast<const float4*>(dst);
      float4 q = *reinterpret_cast<const float4*>(dst + 4);
      float wv[8];
      #pragma unroll
      for (int e = 0; e < 8; ++e) wv[e] = bf2f(pool[SM + (ty*8 + e)*LDW + c]);
      float4 o1 = make_float4(a.x + alpha*wv[0], a.y + alpha*wv[1], a.z + alpha*wv[2], a.w + alpha*wv[3]);
      float4 o2 = make_float4(q.x + alpha*wv[4], q.y + alpha*wv[5], q.z + alpha*wv[6], q.w + alpha*wv[7]);
      *reinterpret_cast<float4*>(dst)     = o1;
      *reinterpret_cast<float4*>(dst + 4) = o2;
    }
  } else {
    // out = x + alpha*x_win + beta*x_oca(ws)
    float beta = 1.f - alpha;
    const u16* xw = xoca + (size_t)win*12288;
    for (int j = tid; j < 1536; j += 512){
      int c = j >> 3, ty = j & 7;
      size_t goff = ((size_t)c*HWD + hrow + ty)*HWD + wcol;
      const float* src = xb + goff;
      float4 a = *reinterpret_cast<const float4*>(src);
      float4 q = *reinterpret_cast<const float4*>(src + 4);
      uint4 oc = *reinterpret_cast<const uint4*>(xw + c*64 + ty*8);
      float ov[8]; up8(oc, ov);
      float wv[8];
      #pragma unroll
      for (int e = 0; e < 8; ++e) wv[e] = bf2f(pool[SM + (ty*8 + e)*LDW + c]);
      float4 o1 = make_float4(a.x + alpha*wv[0] + beta*ov[0], a.y + alpha*wv[1] + beta*ov[1],
                              a.z + alpha*wv[2] + beta*ov[2], a.w + alpha*wv[3] + beta*ov[3]);
      float4 o2 = make_float4(q.x + alpha*wv[4] + beta*ov[4], q.y + alpha*wv[5] + beta*ov[5],
                              q.z + alpha*wv[6] + beta*ov[6], q.w + alpha*wv[7] + beta*ov[7]);
      *reinterpret_cast<float4*>(outb + goff)     = o1;
      *reinterpret_cast<float4*>(outb + goff + 4) = o2;
    }
  }
}

// ================= FALLBACK (round-2, VALU-only, no workspace) =================
__device__ __forceinline__ void layernorm_fb(const u16* __restrict__ src, u16* __restrict__ dst,
                                             const float* __restrict__ g, const float* __restrict__ b,
                                             int tid)
{
  int r = tid >> 3, sub = tid & 7;
  const u16* row = src + r*LDW + sub*24;
  float v[24];
  float s = 0.f, s2 = 0.f;
  #pragma unroll
  for (int e = 0; e < 24; ++e){ v[e] = bf2f(row[e]); s += v[e]; s2 += v[e]*v[e]; }
  s  += __shfl_xor(s, 1, 64);  s  += __shfl_xor(s, 2, 64);  s  += __shfl_xor(s, 4, 64);
  s2 += __shfl_xor(s2, 1, 64); s2 += __shfl_xor(s2, 2, 64); s2 += __shfl_xor(s2, 4, 64);
  float m   = s * (1.f/192.f);
  float var = s2 * (1.f/192.f) - m*m;
  float rs  = rsqrtf(var + 1e-5f);
  u16* drow = dst + r*LDW + sub*24;
  #pragma unroll
  for (int e = 0; e < 24; ++e)
    drow[e] = f2bf((v[e] - m) * rs * g[sub*24+e] + b[sub*24+e]);
}
__device__ __forceinline__ void gemm83(const u16* __restrict__ a_lds,
                                       const float* __restrict__ w0,
                                       const float* __restrict__ w1,
                                       const float* __restrict__ w2,
                                       int tg, float (*acc)[3])
{
  for (int k0 = 0; k0 < 192; k0 += 8){
    float wv[3][8];
    ldw8(w0 + k0, wv[0]); ldw8(w1 + k0, wv[1]); ldw8(w2 + k0, wv[2]);
    #pragma unroll
    for (int tt = 0; tt < 8; ++tt){
      float a[8];
      up8(*reinterpret_cast<const uint4*>(a_lds + (tg*8+tt)*LDW + k0), a);
      #pragma unroll
      for (int e = 0; e < 8; ++e){
        acc[tt][0] += a[e]*wv[0][e];
        acc[tt][1] += a[e]*wv[1][e];
        acc[tt][2] += a[e]*wv[2][e];
      }
    }
  }
}
__global__ __launch_bounds__(512) void k_msa_fb(
    const float* __restrict__ x, const float* __restrict__ g1, const float* __restrict__ b1,
    const float* __restrict__ qkv_w, const float* __restrict__ rpe, const float* __restrict__ wproj,
    const float* __restrict__ g2, const float* __restrict__ b2,
    const float* __restrict__ mlp1, const float* __restrict__ mlp2,
    const float* __restrict__ alpha_p, float* __restrict__ out)
{
  __shared__ __align__(16) u16 sX[64*LDW];
  __shared__ __align__(16) u16 sN[64*LDW];
  __shared__ __align__(16) u16 sM[64*LDW];
  __shared__ __align__(16) float sQ[64*QSTR];
  __shared__ __align__(16) float sK[64*QSTR];
  __shared__ __align__(16) float sV[64*QSTR];
  const int tid = threadIdx.x;
  const int win = blockIdx.x;
  const int b  = win >> 10;
  const int wy = (win >> 5) & 31;
  const int wx = win & 31;
  const int hrow = wy*8, wcol = wx*8;
  const float* xb = x + (size_t)b*CH*HWD*HWD;
  float* outb = out + (size_t)b*CH*HWD*HWD;
  for (int j = tid; j < 1536; j += 512){
    int c = j >> 3, ty = j & 7;
    const float* src = xb + ((size_t)c*HWD + hrow + ty)*HWD + wcol;
    float4 a = *reinterpret_cast<const float4*>(src);
    float4 q = *reinterpret_cast<const float4*>(src + 4);
    u16* dst = &sX[(ty*8)*LDW + c];
    dst[0*LDW]=f2bf(a.x); dst[1*LDW]=f2bf(a.y); dst[2*LDW]=f2bf(a.z); dst[3*LDW]=f2bf(a.w);
    dst[4*LDW]=f2bf(q.x); dst[5*LDW]=f2bf(q.y); dst[6*LDW]=f2bf(q.z); dst[7*LDW]=f2bf(q.w);
  }
  __syncthreads();
  layernorm_fb(sX, sN, g1, b1, tid);
  __syncthreads();
  const int t8 = tid >> 3, s8 = tid & 7;
  for (int h = 0; h < NH; ++h){
    {
      const u16* arow = &sN[t8*LDW];
      float acc[9];
      #pragma unroll
      for (int o = 0; o < 9; ++o) acc[o] = 0.f;
      const float* wp[9];
      #pragma unroll
      for (int o = 0; o < 3; ++o){
        const float* base = qkv_w + (size_t)(h*24 + s8*3 + o)*192;
        wp[o] = base; wp[3+o] = base + 192*192; wp[6+o] = base + 2*192*192;
      }
      for (int k0 = 0; k0 < 192; k0 += 8){
        float a[8]; up8(*reinterpret_cast<const uint4*>(arow + k0), a);
        #pragma unroll
        for (int o = 0; o < 9; ++o){
          float wv[8]; ldw8(wp[o] + k0, wv);
          #pragma unroll
          for (int e = 0; e < 8; ++e) acc[o] += a[e]*wv[e];
        }
      }
      #pragma unroll
      for (int o = 0; o < 3; ++o){
        sQ[t8*QSTR + s8*3 + o] = acc[o];
        sK[t8*QSTR + s8*3 + o] = acc[3+o];
        sV[t8*QSTR + s8*3 + o] = acc[6+o];
      }
    }
    __syncthreads();
    {
      float q24[24];
      #pragma unroll
      for (int e = 0; e < 24; ++e) q24[e] = sQ[t8*QSTR + e];
      const int ry = t8 >> 3, rx = t8 & 7;
      float p[8];
      #pragma unroll
      for (int j = 0; j < 8; ++j){
        int c = s8*8 + j;
        const float* kr = &sK[c*QSTR];
        float s = 0.f;
        #pragma unroll
        for (int e = 0; e < 24; ++e) s += q24[e]*kr[e];
        int cy = c >> 3, cx = c & 7;
        p[j] = s*SCALE + rpe[((ry-cy+7)*15 + (rx-cx+7))*NH + h];
      }
      float mx = p[0];
      #pragma unroll
      for (int j = 1; j < 8; ++j) mx = fmaxf(mx, p[j]);
      mx = fmaxf(mx, __shfl_xor(mx, 1, 64));
      mx = fmaxf(mx, __shfl_xor(mx, 2, 64));
      mx = fmaxf(mx, __shfl_xor(mx, 4, 64));
      float sum = 0.f;
      #pragma unroll
      for (int j = 0; j < 8; ++j){ p[j] = __expf(p[j] - mx); sum += p[j]; }
      sum += __shfl_xor(sum, 1, 64); sum += __shfl_xor(sum, 2, 64); sum += __shfl_xor(sum, 4, 64);
      float inv = 1.f / sum;
      float o24[24];
      #pragma unroll
      for (int e = 0; e < 24; ++e) o24[e] = 0.f;
      #pragma unroll
      for (int j = 0; j < 8; ++j){
        const float* vr = &sV[(s8*8 + j)*QSTR];
        #pragma unroll
        for (int e = 0; e < 24; ++e) o24[e] += p[j]*vr[e];
      }
      #pragma unroll
      for (int e = 0; e < 24; ++e){
        o24[e] += __shfl_xor(o24[e], 1, 64);
        o24[e] += __shfl_xor(o24[e], 2, 64);
        o24[e] += __shfl_xor(o24[e], 4, 64);
      }
      u16* mrow = &sM[t8*LDW + h*24 + s8*3];
      #pragma unroll
      for (int o = 0; o < 3; ++o) mrow[o] = f2bf(o24[s8*3 + o]*inv);
    }
    __syncthreads();
  }
  const int tg = tid >> 6, cg = tid & 63;
  {
    float acc[8][3];
    #pragma unroll
    for (int tt = 0; tt < 8; ++tt){ acc[tt][0]=0.f; acc[tt][1]=0.f; acc[tt][2]=0.f; }
    gemm83(sM, wproj + (size_t)(cg*3+0)*192, wproj + (size_t)(cg*3+1)*192, wproj + (size_t)(cg*3+2)*192, tg, acc);
    #pragma unroll
    for (int tt = 0; tt < 8; ++tt)
      #pragma unroll
      for (int j = 0; j < 3; ++j){
        int t = tg*8+tt, c = cg*3+j;
        sN[t*LDW + c] = f2bf(acc[tt][j] + bf2f(sX[t*LDW + c]));
      }
  }
  __syncthreads();
  layernorm_fb(sN, sX, g2, b2, tid);
  __syncthreads();
  float facc[8][3];
  #pragma unroll
  for (int tt = 0; tt < 8; ++tt){ facc[tt][0]=0.f; facc[tt][1]=0.f; facc[tt][2]=0.f; }
  for (int half = 0; half < 2; ++half){
    {
      float acc[8][3];
      #pragma unroll
      for (int tt = 0; tt < 8; ++tt){ acc[tt][0]=0.f; acc[tt][1]=0.f; acc[tt][2]=0.f; }
      gemm83(sX, mlp1 + (size_t)(half*192 + cg*3+0)*192, mlp1 + (size_t)(half*192 + cg*3+1)*192,
                 mlp1 + (size_t)(half*192 + cg*3+2)*192, tg, acc);
      #pragma unroll
      for (int tt = 0; tt < 8; ++tt)
        #pragma unroll
        for (int j = 0; j < 3; ++j){
          float vv = acc[tt][j];
          sM[(tg*8+tt)*LDW + cg*3+j] = f2bf(0.5f*vv*(1.f + erff(vv*0.70710678118654752f)));
        }
    }
    __syncthreads();
    gemm83(sM, mlp2 + (size_t)(cg*3+0)*384 + half*192, mlp2 + (size_t)(cg*3+1)*384 + half*192,
               mlp2 + (size_t)(cg*3+2)*384 + half*192, tg, facc);
    __syncthreads();
  }
  #pragma unroll
  for (int tt = 0; tt < 8; ++tt)
    #pragma unroll
    for (int j = 0; j < 3; ++j){
      int t = tg*8+tt, c = cg*3+j;
      sM[t*LDW + c] = f2bf(bf2f(sN[t*LDW + c]) + facc[tt][j]);
    }
  __syncthreads();
  float alpha = alpha_p[0];
  for (int j = tid; j < 1536; j += 512){
    int c = j >> 3, ty = j & 7;
    size_t goff = ((size_t)c*HWD + hrow + ty)*HWD + wcol;
    const float* src = xb + goff;
    float4 a = *reinterpret_cast<const float4*>(src);
    float4 q = *reinterpret_cast<const float4*>(src + 4);
    float wv[8];
    #pragma unroll
    for (int e = 0; e < 8; ++e) wv[e] = bf2f(sM[(ty*8 + e)*LDW + c]);
    float4 o1 = make_float4(a.x + alpha*wv[0], a.y + alpha*wv[1], a.z + alpha*wv[2], a.w + alpha*wv[3]);
    float4 o2 = make_float4(q.x + alpha*wv[4], q.y + alpha*wv[5], q.z + alpha*wv[6], q.w + alpha*wv[7]);
    *reinterpret_cast<float4*>(outb + goff)     = o1;
    *reinterpret_cast<float4*>(outb + goff + 4) = o2;
  }
}
__global__ __launch_bounds__(512) void k_oca_fb(
    const float* __restrict__ x, const float* __restrict__ og_p, const float* __restrict__ ob_p,
    const float* __restrict__ q_w, const float* __restrict__ kv_w, const float* __restrict__ oproj,
    const float* __restrict__ alpha_p, float* __restrict__ out)
{
  __shared__ __align__(16) u16 sW[64*LDW];
  __shared__ __align__(16) u16 sN[64*LDW];
  __shared__ __align__(16) u16 sQa[64*LDW];
  __shared__ __align__(16) u16 sU[144*LDW];
  __shared__ __align__(16) u16 sKb[144*32];
  __shared__ __align__(16) u16 sVb[144*32];
  const int tid = threadIdx.x;
  const int win = blockIdx.x;
  const int b  = win >> 10;
  const int wy = (win >> 5) & 31;
  const int wx = win & 31;
  const int hrow = wy*8, wcol = wx*8;
  const float* xb = x + (size_t)b*CH*HWD*HWD;
  float* outb = out + (size_t)b*CH*HWD*HWD;
  for (int j = tid; j < 1536; j += 512){
    int c = j >> 3, ty = j & 7;
    const float* src = xb + ((size_t)c*HWD + hrow + ty)*HWD + wcol;
    float4 a = *reinterpret_cast<const float4*>(src);
    float4 q = *reinterpret_cast<const float4*>(src + 4);
    u16* dst = &sW[(ty*8)*LDW + c];
    dst[0*LDW]=f2bf(a.x); dst[1*LDW]=f2bf(a.y); dst[2*LDW]=f2bf(a.z); dst[3*LDW]=f2bf(a.w);
    dst[4*LDW]=f2bf(q.x); dst[5*LDW]=f2bf(q.y); dst[6*LDW]=f2bf(q.z); dst[7*LDW]=f2bf(q.w);
  }
  for (int i = tid; i < 144*192; i += 512){
    int c = i / 144, t = i - c*144;
    int ti = t / 12, tj = t - ti*12;
    sU[t*LDW + c] = f2bf(xb[((size_t)c*HWD + refl(hrow + ti - 2))*HWD + refl(wcol + tj - 2)]);
  }
  __syncthreads();
  layernorm_fb(sW, sN, og_p, ob_p, tid);
  __syncthreads();
  const int tg = tid >> 6, cg = tid & 63;
  {
    float acc[8][3];
    #pragma unroll
    for (int tt = 0; tt < 8; ++tt){ acc[tt][0]=0.f; acc[tt][1]=0.f; acc[tt][2]=0.f; }
    gemm83(sN, q_w + (size_t)(cg*3+0)*192, q_w + (size_t)(cg*3+1)*192, q_w + (size_t)(cg*3+2)*192, tg, acc);
    #pragma unroll
    for (int tt = 0; tt < 8; ++tt)
      #pragma unroll
      for (int j = 0; j < 3; ++j)
        sQa[(tg*8+tt)*LDW + cg*3+j] = f2bf(acc[tt][j]);
  }
  __syncthreads();
  const int t8 = tid >> 3, s8 = tid & 7;
  for (int h = 0; h < NH; ++h){
    for (int i = tid; i < 144*24; i += 512){
      int tok = i / 24, d = i - tok*24;
      const float* kw = kv_w + (size_t)(h*24 + d)*192;
      const float* vw = kv_w + (size_t)(192 + h*24 + d)*192;
      const u16* arow = &sU[tok*LDW];
      float ka[4] = {0.f,0.f,0.f,0.f}, va[4] = {0.f,0.f,0.f,0.f};
      for (int k0 = 0; k0 < 192; k0 += 8){
        float a[8]; up8(*reinterpret_cast<const uint4*>(arow + k0), a);
        float kk[8]; ldw8(kw + k0, kk);
        float vv[8]; ldw8(vw + k0, vv);
        #pragma unroll
        for (int e = 0; e < 8; ++e){ ka[e&3] += a[e]*kk[e]; va[e&3] += a[e]*vv[e]; }
      }
      sKb[tok*32 + d] = f2bf(ka[0]+ka[1]+ka[2]+ka[3]);
      sVb[tok*32 + d] = f2bf(va[0]+va[1]+va[2]+va[3]);
    }
    __syncthreads();
    {
      float q24[24];
      #pragma unroll
      for (int e = 0; e < 24; ++e) q24[e] = bf2f(sQa[t8*LDW + h*24 + e]);
      float p[18];
      #pragma unroll
      for (int j = 0; j < 18; ++j){
        int c = s8*18 + j;
        const u16* kr = &sKb[c*32];
        float s = 0.f;
        #pragma unroll
        for (int e = 0; e < 24; ++e) s += q24[e]*bf2f(kr[e]);
        p[j] = s*SCALE;
      }
      float mx = p[0];
      #pragma unroll
      for (int j = 1; j < 18; ++j) mx = fmaxf(mx, p[j]);
      mx = fmaxf(mx, __shfl_xor(mx, 1, 64));
      mx = fmaxf(mx, __shfl_xor(mx, 2, 64));
      mx = fmaxf(mx, __shfl_xor(mx, 4, 64));
      float sum = 0.f;
      #pragma unroll
      for (int j = 0; j < 18; ++j){ p[j] = __expf(p[j] - mx); sum += p[j]; }
      sum += __shfl_xor(sum, 1, 64); sum += __shfl_xor(sum, 2, 64); sum += __shfl_xor(sum, 4, 64);
      float inv = 1.f / sum;
      float o24[24];
      #pragma unroll
      for (int e = 0; e < 24; ++e) o24[e] = 0.f;
      #pragma unroll
      for (int j = 0; j < 18; ++j){
        const u16* vr = &sVb[(s8*18 + j)*32];
        #pragma unroll
        for (int e = 0; e < 24; ++e) o24[e] += p[j]*bf2f(vr[e]);
      }
      #pragma unroll
      for (int e = 0; e < 24; ++e){
        o24[e] += __shfl_xor(o24[e], 1, 64);
        o24[e] += __shfl_xor(o24[e], 2, 64);
        o24[e] += __shfl_xor(o24[e], 4, 64);
      }
      u16* orow = &sN[t8*LDW + h*24 + s8*3];
      #pragma unroll
      for (int o = 0; o < 3; ++o) orow[o] = f2bf(o24[s8*3 + o]*inv);
    }
    __syncthreads();
  }
  {
    float acc[8][3];
    #pragma unroll
    for (int tt = 0; tt < 8; ++tt){ acc[tt][0]=0.f; acc[tt][1]=0.f; acc[tt][2]=0.f; }
    gemm83(sN, oproj + (size_t)(cg*3+0)*192, oproj + (size_t)(cg*3+1)*192, oproj + (size_t)(cg*3+2)*192, tg, acc);
    #pragma unroll
    for (int tt = 0; tt < 8; ++tt)
      #pragma unroll
      for (int j = 0; j < 3; ++j){
        int t = tg*8+tt, c = cg*3+j;
        sQa[t*LDW + c] = f2bf(acc[tt][j] + bf2f(sW[t*LDW + c]));
      }
  }
  __syncthreads();
  float beta = 1.f - alpha_p[0];
  for (int j = tid; j < 1536; j += 512){
    int c = j >> 3, ty = j & 7;
    size_t goff = ((size_t)c*HWD + hrow + ty)*HWD + wcol;
    float* dst = outb + goff;
    float4 a = *reinterpret_cast<const float4*>(dst);
    float4 q = *reinterpret_cast<const float4*>(dst + 4);
    float wv[8];
    #pragma unroll
    for (int e = 0; e < 8; ++e) wv[e] = bf2f(sQa[(ty*8 + e)*LDW + c]);
    float4 o1 = make_float4(a.x + beta*wv[0], a.y + beta*wv[1], a.z + beta*wv[2], a.w + beta*wv[3]);
    float4 o2 = make_float4(q.x + beta*wv[4], q.y + beta*wv[5], q.z + beta*wv[6], q.w + beta*wv[7]);
    *reinterpret_cast<float4*>(dst)     = o1;
    *reinterpret_cast<float4*>(dst + 4) = o2;
  }
}

extern "C" void kernel_launch(void* const* d_in, const int* in_sizes, int n_in,
                              void* d_out, int out_size, void* d_ws, size_t ws_size,
                              hipStream_t stream) {
  const float* x     = (const float*)d_in[0];
  const float* g1    = (const float*)d_in[1];
  const float* b1    = (const float*)d_in[2];
  const float* qkvw  = (const float*)d_in[3];
  const float* rpe   = (const float*)d_in[4];
  const float* wproj = (const float*)d_in[5];
  const float* g2    = (const float*)d_in[6];
  const float* b2    = (const float*)d_in[7];
  const float* mlp1  = (const float*)d_in[8];
  const float* mlp2  = (const float*)d_in[9];
  const float* alpha = (const float*)d_in[10];
  const float* og    = (const float*)d_in[11];
  const float* ob    = (const float*)d_in[12];
  const float* q_w   = (const float*)d_in[13];
  const float* kv_w  = (const float*)d_in[14];
  const float* oproj = (const float*)d_in[15];
  float* out = (float*)d_out;

  if (ws_size >= (size_t)WS_NEED) {
    u16*   ws16 = (u16*)d_ws;
    float* wsf  = (float*)d_ws;
    k_swz<<<36*6, 64, 0, stream>>>(qkvw,  g1,      ws16 + WS_W1/2,  6, 192);
    k_swz<<<24*6, 64, 0, stream>>>(kv_w,  nullptr, ws16 + WS_WKV/2, 6, 192);
    k_swz<<<12*6, 64, 0, stream>>>(q_w,   og,      ws16 + WS_WQ/2,  6, 192);
    k_swz<<<12*6, 64, 0, stream>>>(wproj, nullptr, ws16 + WS_WP/2,  6, 192);
    k_swz<<<24*6, 64, 0, stream>>>(mlp1,  g2,      ws16 + WS_WM1/2, 6, 192);
    k_swz<<<12*12,64, 0, stream>>>(mlp2,  nullptr, ws16 + WS_WM2/2, 12, 384);
    k_swz<<<12*6, 64, 0, stream>>>(oproj, nullptr, ws16 + WS_WO/2,  6, 192);
    k_cvec<<<576, 64, 0, stream>>>(qkvw, g1, b1, (float*)((char*)d_ws + WS_C1),  (float*)((char*)d_ws + WS_C2),  192);
    k_cvec<<<192, 64, 0, stream>>>(q_w,  og, ob, (float*)((char*)d_ws + WS_C1O), (float*)((char*)d_ws + WS_C2O), 192);
    k_cvec<<<384, 64, 0, stream>>>(mlp1, g2, b2, (float*)((char*)d_ws + WS_C1M), (float*)((char*)d_ws + WS_C2M), 192);
    k_kv<<<2048, 512, 0, stream>>>(x, ws16 + WS_WKV/2, ws16 + WS_KV/2);
    if (ws_size >= (size_t)WS_NEED1) {
      u16* xoca = ws16 + WS_XOCA/2;
      k_oca_attn<1><<<2048, 512, 0, stream>>>(x, ws16, wsf, alpha, out, xoca);
      k_msa<1><<<2048, 512, 0, stream>>>(x, ws16, wsf, rpe, alpha, out, xoca);
    } else {
      k_oca_attn<0><<<2048, 512, 0, stream>>>(x, ws16, wsf, alpha, out, nullptr);
      k_msa<0><<<2048, 512, 0, stream>>>(x, ws16, wsf, rpe, alpha, out, nullptr);
    }
  } else {
    k_msa_fb<<<2048, 512, 0, stream>>>(x, g1, b1, qkvw, rpe, wproj, g2, b2, mlp1, mlp2, alpha, out);
    k_oca_fb<<<2048, 512, 0, stream>>>(x, og, ob, q_w, kv_w, oproj, alpha, out);
  }
}

// Round 5
// 1735.231 us; speedup vs baseline: 2.4625x; 2.4625x over previous
//
#include <hip/hip_runtime.h>
#include <hip/hip_bf16.h>

typedef unsigned short u16;
typedef unsigned int   u32;
typedef __attribute__((ext_vector_type(8))) short bf16x8;
typedef __attribute__((ext_vector_type(4))) float f32x4;

#define CH   192
#define NH   8
#define HWD  256
#define LDW  200   // bf16 row stride for 192-wide LDS tiles (400B)
#define LDK  40    // bf16 row stride for 24-wide V rows
#define QSTR 28
#define SCALE 0.20412414523193154f

__device__ __forceinline__ float bf2f(u16 u){ u32 v = ((u32)u) << 16; return __builtin_bit_cast(float, v); }
__device__ __forceinline__ u16 f2bf(float f){
  u32 u = __builtin_bit_cast(u32, f);
  u = (u + 0x7fffu + ((u >> 16) & 1u)) >> 16;
  return (u16)u;
}
__device__ __forceinline__ float lo2f(u32 p){ return __builtin_bit_cast(float, p << 16); }
__device__ __forceinline__ float hi2f(u32 p){ return __builtin_bit_cast(float, p & 0xffff0000u); }
__device__ __forceinline__ void up8(uint4 q, float* f){
  f[0]=lo2f(q.x); f[1]=hi2f(q.x); f[2]=lo2f(q.y); f[3]=hi2f(q.y);
  f[4]=lo2f(q.z); f[5]=hi2f(q.z); f[6]=lo2f(q.w); f[7]=hi2f(q.w);
}
__device__ __forceinline__ void ldw8(const float* __restrict__ p, float* f){
  float4 a = *reinterpret_cast<const float4*>(p);
  float4 b = *reinterpret_cast<const float4*>(p + 4);
  f[0]=a.x; f[1]=a.y; f[2]=a.z; f[3]=a.w;
  f[4]=b.x; f[5]=b.y; f[6]=b.z; f[7]=b.w;
}
__device__ __forceinline__ int refl(int v){ v = v < 0 ? -v : v; return v < HWD ? v : 2*(HWD-1) - v; }
__device__ __forceinline__ f32x4 mfma16(bf16x8 a, bf16x8 b, f32x4 c){
  return __builtin_amdgcn_mfma_f32_16x16x32_bf16(a, b, c, 0, 0, 0);
}
__device__ __forceinline__ bf16x8 afrag(const u16* pool, int base, int stride, int row, int kt, int l){
  return *reinterpret_cast<const bf16x8*>(pool + base + row*stride + kt*32 + ((l>>4)<<3));
}
__device__ __forceinline__ bf16x8 bfrag(const u16* __restrict__ w, int tile, int l){
  return *reinterpret_cast<const bf16x8*>(w + tile*512 + l*8);
}
__device__ __forceinline__ void ln_stats(const u16* buf, float* st, int tid){
  int r = tid >> 3, sub = tid & 7;
  const uint4* rp = reinterpret_cast<const uint4*>(buf + r*LDW + sub*24);
  float v[24]; up8(rp[0], v); up8(rp[1], v+8); up8(rp[2], v+16);
  float s = 0.f, s2 = 0.f;
  #pragma unroll
  for (int e = 0; e < 24; ++e){ s += v[e]; s2 += v[e]*v[e]; }
  s  += __shfl_xor(s, 1, 64);  s  += __shfl_xor(s, 2, 64);  s  += __shfl_xor(s, 4, 64);
  s2 += __shfl_xor(s2, 1, 64); s2 += __shfl_xor(s2, 2, 64); s2 += __shfl_xor(s2, 4, 64);
  if (sub == 0){
    float m = s*(1.f/192.f);
    float var = s2*(1.f/192.f) - m*m;
    st[r*2] = m; st[r*2+1] = rsqrtf(var + 1e-5f);
  }
}

// ---------------- workspace layout (bytes) ----------------
#define WS_KV   ((size_t)0)                     // 2*65536*384 bf16 = 100,663,296
#define WS_W1   ((size_t)100663296)
#define WS_WKV  (WS_W1  + 221184)
#define WS_WQ   (WS_WKV + 147456)
#define WS_WP   (WS_WQ  + 73728)
#define WS_WM1  (WS_WP  + 73728)
#define WS_WM2  (WS_WM1 + 147456)
#define WS_WO   (WS_WM2 + 147456)
#define WS_C1   (WS_WO  + 73728)
#define WS_C2   (WS_C1  + 2304)
#define WS_C1O  (WS_C2  + 2304)
#define WS_C2O  (WS_C1O + 768)
#define WS_C1M  (WS_C2O + 768)
#define WS_C2M  (WS_C1M + 1536)
#define WS_NEED (WS_C2M + 1536)                 // = 101,557,248
#define WS_XOCA WS_NEED                         // [2048][192][64] bf16 = 50,331,648
#define WS_NEED1 (WS_XOCA + 50331648)

// ---------------- prep kernels ----------------
__global__ void k_swz(const float* __restrict__ src, const float* __restrict__ gv,
                      u16* __restrict__ dst, int KT, int K){
  int tile = blockIdx.x; int nt = tile / KT, kt = tile - nt*KT;
  int l = threadIdx.x;
  int row = nt*16 + (l & 15);
  int kb  = kt*32 + ((l>>4)<<3);
  const float* s = src + (size_t)row*K + kb;
  u16* d = dst + (size_t)tile*512 + l*8;
  #pragma unroll
  for (int e = 0; e < 8; ++e){
    float w = s[e];
    if (gv) w *= gv[kb + e];
    d[e] = f2bf(w);
  }
}
__global__ void k_cvec(const float* __restrict__ W, const float* __restrict__ g,
                       const float* __restrict__ b, float* __restrict__ c1,
                       float* __restrict__ c2, int K){
  int n = blockIdx.x; int l = threadIdx.x;
  float s1 = 0.f, s2 = 0.f;
  for (int k = l; k < K; k += 64){
    float w = W[(size_t)n*K + k];
    s1 += w*g[k]; s2 += w*b[k];
  }
  #pragma unroll
  for (int d = 1; d < 64; d <<= 1){ s1 += __shfl_xor(s1, d, 64); s2 += __shfl_xor(s2, d, 64); }
  if (l == 0){ c1[n] = s1; c2[n] = s2; }
}

// ---------------- k_kv: per-pixel KV GEMM (dedup of unfold) ----------------
__global__ __launch_bounds__(512) void k_kv(const float* __restrict__ x,
                                            const u16* __restrict__ wkv,
                                            u16* __restrict__ KV){
  __shared__ __align__(16) u16 sA[64*LDW];
  const int blk = blockIdx.x;                // 2048
  const int batch = blk >> 10;
  const int pix0 = (blk & 1023) * 64;
  const float* xb = x + (size_t)batch*CH*65536;

  for (int idx = threadIdx.x; idx < 1536; idx += 512){
    int c = idx >> 3, s = idx & 7;
    const float* p = xb + (size_t)c*65536 + pix0 + s*8;
    float4 a = *reinterpret_cast<const float4*>(p);
    float4 b = *reinterpret_cast<const float4*>(p + 4);
    u16* d = &sA[(s*8)*LDW + c];
    d[0*LDW]=f2bf(a.x); d[1*LDW]=f2bf(a.y); d[2*LDW]=f2bf(a.z); d[3*LDW]=f2bf(a.w);
    d[4*LDW]=f2bf(b.x); d[5*LDW]=f2bf(b.y); d[6*LDW]=f2bf(b.z); d[7*LDW]=f2bf(b.w);
  }
  __syncthreads();

  const int w = threadIdx.x >> 6, l = threadIdx.x & 63;
  const int mt = w >> 1, half = w & 1;
  const f32x4 z4 = {0.f,0.f,0.f,0.f};
  f32x4 acc[12];
  #pragma unroll
  for (int j = 0; j < 12; ++j) acc[j] = z4;
  const int arow = mt*16 + (l & 15);
  for (int kt = 0; kt < 6; ++kt){
    bf16x8 a = afrag(sA, 0, LDW, arow, kt, l);
    #pragma unroll
    for (int j = 0; j < 12; ++j){
      int nt = half*12 + j;
      acc[j] = mfma16(a, bfrag(wkv, nt*6 + kt, l), acc[j]);
    }
  }
  u16* kvb = KV + ((size_t)batch*65536 + pix0)*384;
  const int rbase = mt*16 + ((l>>4)<<2);
  #pragma unroll
  for (int j = 0; j < 12; ++j){
    int col = (half*12 + j)*16 + (l & 15);
    #pragma unroll
    for (int r = 0; r < 4; ++r)
      kvb[(size_t)(rbase + r)*384 + col] = f2bf(acc[j][r]);
  }
}

// ---------------- k_oca_attn: cross attention; MODE0: out = x + beta*x_oca; MODE1: x_oca -> ws ----------------
#define OW_  0        // [64][200] u16: x window
#define OQ_  12800    // [64][200] u16: q; per-head slice overwritten by attn-out
#define OKF  25600    // f32 K [144][28] = 8064 u16
#define OVB  33664    // u16 V [144][40] = 5760 u16
#define XO_  25600    // x_oca [64][200] u16 (reuses K/V region post-attention)
#define OST_ 39424    // 128 f32 stats
#define OPOOLN 39680  // 79,360 bytes

template<int MODE>
__global__ __launch_bounds__(512) void k_oca_attn(
    const float* __restrict__ x, const u16* __restrict__ ws16, const float* __restrict__ wsf,
    const float* __restrict__ alpha_p, float* __restrict__ out, u16* __restrict__ xoca)
{
  __shared__ __align__(16) u16 pool[OPOOLN];
  float* st = reinterpret_cast<float*>(pool + OST_);
  float* sK = reinterpret_cast<float*>(pool + OKF);
  const u16* KV = ws16 + WS_KV/2;
  const u16* WQ = ws16 + WS_WQ/2;
  const u16* WO = ws16 + WS_WO/2;
  const float* c1o = wsf + WS_C1O/4;
  const float* c2o = wsf + WS_C2O/4;

  const int tid = threadIdx.x;
  const int win = blockIdx.x;
  const int b  = win >> 10;
  const int wy = (win >> 5) & 31;
  const int wx = win & 31;
  const int hrow = wy*8, wcol = wx*8;
  const float* xb = x + (size_t)b*CH*HWD*HWD;
  float* outb = out + (size_t)b*CH*HWD*HWD;
  const size_t pixBase = (size_t)b*65536;

  // P0: window -> OW bf16
  for (int j = tid; j < 1536; j += 512){
    int c = j >> 3, ty = j & 7;
    const float* src = xb + ((size_t)c*HWD + hrow + ty)*HWD + wcol;
    float4 a = *reinterpret_cast<const float4*>(src);
    float4 q = *reinterpret_cast<const float4*>(src + 4);
    u16* dst = &pool[OW_ + (ty*8)*LDW + c];
    dst[0*LDW]=f2bf(a.x); dst[1*LDW]=f2bf(a.y); dst[2*LDW]=f2bf(a.z); dst[3*LDW]=f2bf(a.w);
    dst[4*LDW]=f2bf(q.x); dst[5*LDW]=f2bf(q.y); dst[6*LDW]=f2bf(q.z); dst[7*LDW]=f2bf(q.w);
  }
  __syncthreads();
  ln_stats(pool + OW_, st, tid);
  __syncthreads();

  const int w = tid >> 6, l = tid & 63;
  const int mt = w >> 1, half = w & 1;
  const int arow = mt*16 + (l & 15);
  const int rbase = mt*16 + ((l>>4)<<2);
  const f32x4 z4 = {0.f,0.f,0.f,0.f};

  // P1: q = rs*(x @ Wq'^T - m*c1o) + c2o -> OQ
  {
    f32x4 acc[6];
    #pragma unroll
    for (int j = 0; j < 6; ++j) acc[j] = z4;
    for (int kt = 0; kt < 6; ++kt){
      bf16x8 a = afrag(pool, OW_, LDW, arow, kt, l);
      #pragma unroll
      for (int j = 0; j < 6; ++j)
        acc[j] = mfma16(a, bfrag(WQ, (half*6 + j)*6 + kt, l), acc[j]);
    }
    float mr[4], rr[4];
    #pragma unroll
    for (int r = 0; r < 4; ++r){ mr[r] = st[(rbase+r)*2]; rr[r] = st[(rbase+r)*2+1]; }
    #pragma unroll
    for (int j = 0; j < 6; ++j){
      int col = (half*6 + j)*16 + (l & 15);
      float c1v = c1o[col], c2v = c2o[col];
      #pragma unroll
      for (int r = 0; r < 4; ++r)
        pool[OQ_ + (rbase + r)*LDW + col] = f2bf(rr[r]*(acc[j][r] - mr[r]*c1v) + c2v);
    }
  }
  __syncthreads();

  const int t8 = tid >> 3, s8 = tid & 7;
  for (int h = 0; h < NH; ++h){
    // stage K (f32) and V (bf16) for this head from KV workspace
    for (int i = tid; i < 432; i += 512){
      int tok = i / 3, seg = i - tok*3;
      int ti = tok / 12, tj = tok - ti*12;
      int pix = refl(hrow + ti - 2)*HWD + refl(wcol + tj - 2);
      const u16* src = KV + (pixBase + (size_t)pix)*384 + h*24 + seg*8;
      uint4 kk = *reinterpret_cast<const uint4*>(src);
      uint4 vv = *reinterpret_cast<const uint4*>(src + 192);
      float kf[8]; up8(kk, kf);
      float4* kd = reinterpret_cast<float4*>(sK + tok*28 + seg*8);
      kd[0] = make_float4(kf[0],kf[1],kf[2],kf[3]);
      kd[1] = make_float4(kf[4],kf[5],kf[6],kf[7]);
      *reinterpret_cast<uint4*>(pool + OVB + tok*LDK + seg*8) = vv;
    }
    __syncthreads();
    {
      // ---- QK phase ----
      float p[18];
      {
        float q24[24];
        #pragma unroll
        for (int seg = 0; seg < 3; ++seg){
          uint4 v = *reinterpret_cast<const uint4*>(pool + OQ_ + t8*LDW + h*24 + seg*8);
          up8(v, q24 + seg*8);
        }
        #pragma unroll
        for (int j = 0; j < 18; ++j){
          int c = s8*18 + j;
          const float4* kr = reinterpret_cast<const float4*>(sK + c*28);
          float s = 0.f;
          #pragma unroll
          for (int e4 = 0; e4 < 6; ++e4){
            float4 kk = kr[e4];
            s += q24[e4*4+0]*kk.x + q24[e4*4+1]*kk.y + q24[e4*4+2]*kk.z + q24[e4*4+3]*kk.w;
          }
          p[j] = s*SCALE;
        }
      }
      float mx = p[0];
      #pragma unroll
      for (int j = 1; j < 18; ++j) mx = fmaxf(mx, p[j]);
      mx = fmaxf(mx, __shfl_xor(mx, 1, 64));
      mx = fmaxf(mx, __shfl_xor(mx, 2, 64));
      mx = fmaxf(mx, __shfl_xor(mx, 4, 64));
      float sum = 0.f;
      #pragma unroll
      for (int j = 0; j < 18; ++j){ p[j] = __expf(p[j] - mx); sum += p[j]; }
      sum += __shfl_xor(sum, 1, 64); sum += __shfl_xor(sum, 2, 64); sum += __shfl_xor(sum, 4, 64);
      float inv = 1.f / sum;
      // ---- PV phase: segment-major to cap live registers (v8 transient) ----
      float o24[24];
      #pragma unroll
      for (int seg = 0; seg < 3; ++seg){
        float o8[8];
        #pragma unroll
        for (int e = 0; e < 8; ++e) o8[e] = 0.f;
        #pragma unroll
        for (int j = 0; j < 18; ++j){
          int c = s8*18 + j;
          uint4 v = *reinterpret_cast<const uint4*>(pool + OVB + c*LDK + seg*8);
          float v8[8]; up8(v, v8);
          #pragma unroll
          for (int e = 0; e < 8; ++e) o8[e] += p[j]*v8[e];
        }
        #pragma unroll
        for (int e = 0; e < 8; ++e) o24[seg*8 + e] = o8[e];
      }
      #pragma unroll
      for (int e = 0; e < 24; ++e){
        o24[e] += __shfl_xor(o24[e], 1, 64);
        o24[e] += __shfl_xor(o24[e], 2, 64);
        o24[e] += __shfl_xor(o24[e], 4, 64);
      }
      // overwrite this head's (dead) q-slice with attention output (same-wave, program-ordered)
      u16* orow = &pool[OQ_ + t8*LDW + h*24 + s8*3];
      #pragma unroll
      for (int o = 0; o < 3; ++o) orow[o] = f2bf(o24[s8*3 + o]*inv);
    }
    __syncthreads();
  }

  // P4: x_oca = attn @ oproj^T + x -> XO_ (reuses K/V region)
  {
    f32x4 acc[6];
    #pragma unroll
    for (int j = 0; j < 6; ++j) acc[j] = z4;
    for (int kt = 0; kt < 6; ++kt){
      bf16x8 a = afrag(pool, OQ_, LDW, arow, kt, l);
      #pragma unroll
      for (int j = 0; j < 6; ++j)
        acc[j] = mfma16(a, bfrag(WO, (half*6 + j)*6 + kt, l), acc[j]);
    }
    #pragma unroll
    for (int j = 0; j < 6; ++j){
      int col = (half*6 + j)*16 + (l & 15);
      #pragma unroll
      for (int r = 0; r < 4; ++r){
        int row = rbase + r;
        pool[XO_ + row*LDW + col] = f2bf(acc[j][r] + bf2f(pool[OW_ + row*LDW + col]));
      }
    }
  }
  __syncthreads();

  if (MODE == 0){
    float beta = 1.f - alpha_p[0];
    for (int j = tid; j < 1536; j += 512){
      int c = j >> 3, ty = j & 7;
      size_t goff = ((size_t)c*HWD + hrow + ty)*HWD + wcol;
      const float* src = xb + goff;
      float4 a = *reinterpret_cast<const float4*>(src);
      float4 q = *reinterpret_cast<const float4*>(src + 4);
      float wv[8];
      #pragma unroll
      for (int e = 0; e < 8; ++e) wv[e] = bf2f(pool[XO_ + (ty*8 + e)*LDW + c]);
      float4 o1 = make_float4(a.x + beta*wv[0], a.y + beta*wv[1], a.z + beta*wv[2], a.w + beta*wv[3]);
      float4 o2 = make_float4(q.x + beta*wv[4], q.y + beta*wv[5], q.z + beta*wv[6], q.w + beta*wv[7]);
      *reinterpret_cast<float4*>(outb + goff)     = o1;
      *reinterpret_cast<float4*>(outb + goff + 4) = o2;
    }
  } else {
    u16* xw = xoca + (size_t)win*12288;
    for (int j = tid; j < 1536; j += 512){
      int c = j >> 3, ty = j & 7;
      u32 wds[4];
      #pragma unroll
      for (int e = 0; e < 4; ++e){
        u32 lo = pool[XO_ + (ty*8 + 2*e  )*LDW + c];
        u32 hi = pool[XO_ + (ty*8 + 2*e+1)*LDW + c];
        wds[e] = lo | (hi << 16);
      }
      uint4 o; o.x = wds[0]; o.y = wds[1]; o.z = wds[2]; o.w = wds[3];
      *reinterpret_cast<uint4*>(xw + c*64 + ty*8) = o;
    }
  }
}

// ---------------- k_msa: window MSA + MLP (MFMA); final combine ----------------
#define SX   0
#define SN   12800
#define SQKV 25600
#define SG   25600
#define SM   62464
#define SST  75264
#define POOLSZ 75520

template<int MODE>
__global__ __launch_bounds__(512) void k_msa(
    const float* __restrict__ x, const u16* __restrict__ ws16, const float* __restrict__ wsf,
    const float* __restrict__ rpe, const float* __restrict__ alpha_p, float* __restrict__ out,
    const u16* __restrict__ xoca)
{
  __shared__ __align__(16) u16 pool[POOLSZ];
  float* st = reinterpret_cast<float*>(pool + SST);
  const u16* W1  = ws16 + WS_W1/2;
  const u16* WP  = ws16 + WS_WP/2;
  const u16* WM1 = ws16 + WS_WM1/2;
  const u16* WM2 = ws16 + WS_WM2/2;
  const float* c1  = wsf + WS_C1/4;
  const float* c2  = wsf + WS_C2/4;
  const float* c1m = wsf + WS_C1M/4;
  const float* c2m = wsf + WS_C2M/4;

  const int tid = threadIdx.x;
  const int win = blockIdx.x;
  const int b  = win >> 10;
  const int wy = (win >> 5) & 31;
  const int wx = win & 31;
  const int hrow = wy*8, wcol = wx*8;
  const float* xb = x + (size_t)b*CH*HWD*HWD;
  float* outb = out + (size_t)b*CH*HWD*HWD;

  // P0: window -> sX bf16
  for (int j = tid; j < 1536; j += 512){
    int c = j >> 3, ty = j & 7;
    const float* src = xb + ((size_t)c*HWD + hrow + ty)*HWD + wcol;
    float4 a = *reinterpret_cast<const float4*>(src);
    float4 q = *reinterpret_cast<const float4*>(src + 4);
    u16* dst = &pool[SX + (ty*8)*LDW + c];
    dst[0*LDW]=f2bf(a.x); dst[1*LDW]=f2bf(a.y); dst[2*LDW]=f2bf(a.z); dst[3*LDW]=f2bf(a.w);
    dst[4*LDW]=f2bf(q.x); dst[5*LDW]=f2bf(q.y); dst[6*LDW]=f2bf(q.z); dst[7*LDW]=f2bf(q.w);
  }
  __syncthreads();
  ln_stats(pool + SX, st, tid);
  __syncthreads();

  const int w = tid >> 6, l = tid & 63;
  const int mt = w >> 1, half = w & 1;
  const int arow = mt*16 + (l & 15);
  const int rbase = mt*16 + ((l>>4)<<2);
  const f32x4 z4 = {0.f,0.f,0.f,0.f};

  // P2a: qkv (LN folded), N=576
  {
    f32x4 acc[18];
    #pragma unroll
    for (int j = 0; j < 18; ++j) acc[j] = z4;
    for (int kt = 0; kt < 6; ++kt){
      bf16x8 a = afrag(pool, SX, LDW, arow, kt, l);
      #pragma unroll
      for (int j = 0; j < 18; ++j)
        acc[j] = mfma16(a, bfrag(W1, (half*18 + j)*6 + kt, l), acc[j]);
    }
    float mr[4], rr[4];
    #pragma unroll
    for (int r = 0; r < 4; ++r){ mr[r] = st[(rbase+r)*2]; rr[r] = st[(rbase+r)*2+1]; }
    #pragma unroll
    for (int j = 0; j < 18; ++j){
      int col = (half*18 + j)*16 + (l & 15);
      float c1v = c1[col], c2v = c2[col];
      #pragma unroll
      for (int r = 0; r < 4; ++r){
        int row = rbase + r;
        float v = rr[r]*(acc[j][r] - mr[r]*c1v) + c2v;
        pool[SQKV + row*576 + (col ^ (((row>>3)&7)<<3))] = f2bf(v);
      }
    }
  }
  __syncthreads();

  // P2b: attention (XOR-swizzled qkv reads)
  {
    const int t8 = tid >> 3, s8 = tid & 7;
    const int ry = t8 >> 3, rx = t8 & 7;
    const int swq = ((t8 >> 3) & 7) << 3;
    const int swk = s8 << 3;
    for (int h = 0; h < NH; ++h){
      float p[8];
      {
        float q24[24];
        #pragma unroll
        for (int seg = 0; seg < 3; ++seg){
          uint4 v = *reinterpret_cast<const uint4*>(pool + SQKV + t8*576 + ((h*24 + seg*8) ^ swq));
          up8(v, q24 + seg*8);
        }
        #pragma unroll
        for (int j = 0; j < 8; ++j){
          int c = s8*8 + j;
          float k24[24];
          #pragma unroll
          for (int seg = 0; seg < 3; ++seg){
            uint4 v = *reinterpret_cast<const uint4*>(pool + SQKV + c*576 + ((192 + h*24 + seg*8) ^ swk));
            up8(v, k24 + seg*8);
          }
          float s = 0.f;
          #pragma unroll
          for (int e = 0; e < 24; ++e) s += q24[e]*k24[e];
          int cy = c >> 3, cx = c & 7;
          p[j] = s*SCALE + rpe[((ry-cy+7)*15 + (rx-cx+7))*NH + h];
        }
      }
      float mx = p[0];
      #pragma unroll
      for (int j = 1; j < 8; ++j) mx = fmaxf(mx, p[j]);
      mx = fmaxf(mx, __shfl_xor(mx, 1, 64));
      mx = fmaxf(mx, __shfl_xor(mx, 2, 64));
      mx = fmaxf(mx, __shfl_xor(mx, 4, 64));
      float sum = 0.f;
      #pragma unroll
      for (int j = 0; j < 8; ++j){ p[j] = __expf(p[j] - mx); sum += p[j]; }
      sum += __shfl_xor(sum, 1, 64); sum += __shfl_xor(sum, 2, 64); sum += __shfl_xor(sum, 4, 64);
      float inv = 1.f / sum;
      float o24[24];
      #pragma unroll
      for (int seg = 0; seg < 3; ++seg){
        float o8[8];
        #pragma unroll
        for (int e = 0; e < 8; ++e) o8[e] = 0.f;
        #pragma unroll
        for (int j = 0; j < 8; ++j){
          int c = s8*8 + j;
          uint4 v = *reinterpret_cast<const uint4*>(pool + SQKV + c*576 + ((384 + h*24 + seg*8) ^ swk));
          float v8[8]; up8(v, v8);
          #pragma unroll
          for (int e = 0; e < 8; ++e) o8[e] += p[j]*v8[e];
        }
        #pragma unroll
        for (int e = 0; e < 8; ++e) o24[seg*8 + e] = o8[e];
      }
      #pragma unroll
      for (int e = 0; e < 24; ++e){
        o24[e] += __shfl_xor(o24[e], 1, 64);
        o24[e] += __shfl_xor(o24[e], 2, 64);
        o24[e] += __shfl_xor(o24[e], 4, 64);
      }
      u16* mrow = &pool[SM + t8*LDW + h*24 + s8*3];
      #pragma unroll
      for (int o = 0; o < 3; ++o) mrow[o] = f2bf(o24[s8*3 + o]*inv);
    }
  }
  __syncthreads();

  // P3: xw2 = msa @ wproj^T + x -> sN
  {
    f32x4 acc[6];
    #pragma unroll
    for (int j = 0; j < 6; ++j) acc[j] = z4;
    for (int kt = 0; kt < 6; ++kt){
      bf16x8 a = afrag(pool, SM, LDW, arow, kt, l);
      #pragma unroll
      for (int j = 0; j < 6; ++j)
        acc[j] = mfma16(a, bfrag(WP, (half*6 + j)*6 + kt, l), acc[j]);
    }
    #pragma unroll
    for (int j = 0; j < 6; ++j){
      int col = (half*6 + j)*16 + (l & 15);
      #pragma unroll
      for (int r = 0; r < 4; ++r){
        int row = rbase + r;
        pool[SN + row*LDW + col] = f2bf(acc[j][r] + bf2f(pool[SX + row*LDW + col]));
      }
    }
  }
  __syncthreads();
  ln_stats(pool + SN, st, tid);
  __syncthreads();

  // P5: gelu(LN2-folded mlp1) -> sG
  {
    f32x4 acc[12];
    #pragma unroll
    for (int j = 0; j < 12; ++j) acc[j] = z4;
    for (int kt = 0; kt < 6; ++kt){
      bf16x8 a = afrag(pool, SN, LDW, arow, kt, l);
      #pragma unroll
      for (int j = 0; j < 12; ++j)
        acc[j] = mfma16(a, bfrag(WM1, (half*12 + j)*6 + kt, l), acc[j]);
    }
    float mr[4], rr[4];
    #pragma unroll
    for (int r = 0; r < 4; ++r){ mr[r] = st[(rbase+r)*2]; rr[r] = st[(rbase+r)*2+1]; }
    #pragma unroll
    for (int j = 0; j < 12; ++j){
      int col = (half*12 + j)*16 + (l & 15);
      float c1v = c1m[col], c2v = c2m[col];
      #pragma unroll
      for (int r = 0; r < 4; ++r){
        float hv = rr[r]*(acc[j][r] - mr[r]*c1v) + c2v;
        float gl = 0.5f*hv*(1.f + erff(hv*0.70710678118654752f));
        pool[SG + (rbase + r)*392 + col] = f2bf(gl);
      }
    }
  }
  __syncthreads();

  // P6: x_win = gelu @ mlp2^T + xw2 -> sM
  {
    f32x4 acc[6];
    #pragma unroll
    for (int j = 0; j < 6; ++j) acc[j] = z4;
    for (int kt = 0; kt < 12; ++kt){
      bf16x8 a = afrag(pool, SG, 392, arow, kt, l);
      #pragma unroll
      for (int j = 0; j < 6; ++j)
        acc[j] = mfma16(a, bfrag(WM2, (half*6 + j)*12 + kt, l), acc[j]);
    }
    #pragma unroll
    for (int j = 0; j < 6; ++j){
      int col = (half*6 + j)*16 + (l & 15);
      #pragma unroll
      for (int r = 0; r < 4; ++r){
        int row = rbase + r;
        pool[SM + row*LDW + col] = f2bf(acc[j][r] + bf2f(pool[SN + row*LDW + col]));
      }
    }
  }
  __syncthreads();

  // P7: final combine
  float alpha = alpha_p[0];
  if (MODE == 0){
    for (int j = tid; j < 1536; j += 512){
      int c = j >> 3, ty = j & 7;
      size_t goff = ((size_t)c*HWD + hrow + ty)*HWD + wcol;
      float* dst = outb + goff;
      float4 a = *reinterpret_cast<const float4*>(dst);
      float4 q = *reinterpret_cast<const float4*>(dst + 4);
      float wv[8];
      #pragma unroll
      for (int e = 0; e < 8; ++e) wv[e] = bf2f(pool[SM + (ty*8 + e)*LDW + c]);
      float4 o1 = make_float4(a.x + alpha*wv[0], a.y + alpha*wv[1], a.z + alpha*wv[2], a.w + alpha*wv[3]);
      float4 o2 = make_float4(q.x + alpha*wv[4], q.y + alpha*wv[5], q.z + alpha*wv[6], q.w + alpha*wv[7]);
      *reinterpret_cast<float4*>(dst)     = o1;
      *reinterpret_cast<float4*>(dst + 4) = o2;
    }
  } else {
    float beta = 1.f - alpha;
    const u16* xw = xoca + (size_t)win*12288;
    for (int j = tid; j < 1536; j += 512){
      int c = j >> 3, ty = j & 7;
      size_t goff = ((size_t)c*HWD + hrow + ty)*HWD + wcol;
      const float* src = xb + goff;
      float4 a = *reinterpret_cast<const float4*>(src);
      float4 q = *reinterpret_cast<const float4*>(src + 4);
      uint4 oc = *reinterpret_cast<const uint4*>(xw + c*64 + ty*8);
      float ov[8]; up8(oc, ov);
      float wv[8];
      #pragma unroll
      for (int e = 0; e < 8; ++e) wv[e] = bf2f(pool[SM + (ty*8 + e)*LDW + c]);
      float4 o1 = make_float4(a.x + alpha*wv[0] + beta*ov[0], a.y + alpha*wv[1] + beta*ov[1],
                              a.z + alpha*wv[2] + beta*ov[2], a.w + alpha*wv[3] + beta*ov[3]);
      float4 o2 = make_float4(q.x + alpha*wv[4] + beta*ov[4], q.y + alpha*wv[5] + beta*ov[5],
                              q.z + alpha*wv[6] + beta*ov[6], q.w + alpha*wv[7] + beta*ov[7]);
      *reinterpret_cast<float4*>(outb + goff)     = o1;
      *reinterpret_cast<float4*>(outb + goff + 4) = o2;
    }
  }
}

// ================= FALLBACK (round-2, VALU-only, no workspace) =================
__device__ __forceinline__ void layernorm_fb(const u16* __restrict__ src, u16* __restrict__ dst,
                                             const float* __restrict__ g, const float* __restrict__ b,
                                             int tid)
{
  int r = tid >> 3, sub = tid & 7;
  const u16* row = src + r*LDW + sub*24;
  float v[24];
  float s = 0.f, s2 = 0.f;
  #pragma unroll
  for (int e = 0; e < 24; ++e){ v[e] = bf2f(row[e]); s += v[e]; s2 += v[e]*v[e]; }
  s  += __shfl_xor(s, 1, 64);  s  += __shfl_xor(s, 2, 64);  s  += __shfl_xor(s, 4, 64);
  s2 += __shfl_xor(s2, 1, 64); s2 += __shfl_xor(s2, 2, 64); s2 += __shfl_xor(s2, 4, 64);
  float m   = s * (1.f/192.f);
  float var = s2 * (1.f/192.f) - m*m;
  float rs  = rsqrtf(var + 1e-5f);
  u16* drow = dst + r*LDW + sub*24;
  #pragma unroll
  for (int e = 0; e < 24; ++e)
    drow[e] = f2bf((v[e] - m) * rs * g[sub*24+e] + b[sub*24+e]);
}
__device__ __forceinline__ void gemm83(const u16* __restrict__ a_lds,
                                       const float* __restrict__ w0,
                                       const float* __restrict__ w1,
                                       const float* __restrict__ w2,
                                       int tg, float (*acc)[3])
{
  for (int k0 = 0; k0 < 192; k0 += 8){
    float wv[3][8];
    ldw8(w0 + k0, wv[0]); ldw8(w1 + k0, wv[1]); ldw8(w2 + k0, wv[2]);
    #pragma unroll
    for (int tt = 0; tt < 8; ++tt){
      float a[8];
      up8(*reinterpret_cast<const uint4*>(a_lds + (tg*8+tt)*LDW + k0), a);
      #pragma unroll
      for (int e = 0; e < 8; ++e){
        acc[tt][0] += a[e]*wv[0][e];
        acc[tt][1] += a[e]*wv[1][e];
        acc[tt][2] += a[e]*wv[2][e];
      }
    }
  }
}
__global__ __launch_bounds__(512) void k_msa_fb(
    const float* __restrict__ x, const float* __restrict__ g1, const float* __restrict__ b1,
    const float* __restrict__ qkv_w, const float* __restrict__ rpe, const float* __restrict__ wproj,
    const float* __restrict__ g2, const float* __restrict__ b2,
    const float* __restrict__ mlp1, const float* __restrict__ mlp2,
    const float* __restrict__ alpha_p, float* __restrict__ out)
{
  __shared__ __align__(16) u16 sX[64*LDW];
  __shared__ __align__(16) u16 sN[64*LDW];
  __shared__ __align__(16) u16 sM[64*LDW];
  __shared__ __align__(16) float sQ[64*QSTR];
  __shared__ __align__(16) float sK[64*QSTR];
  __shared__ __align__(16) float sV[64*QSTR];
  const int tid = threadIdx.x;
  const int win = blockIdx.x;
  const int b  = win >> 10;
  const int wy = (win >> 5) & 31;
  const int wx = win & 31;
  const int hrow = wy*8, wcol = wx*8;
  const float* xb = x + (size_t)b*CH*HWD*HWD;
  float* outb = out + (size_t)b*CH*HWD*HWD;
  for (int j = tid; j < 1536; j += 512){
    int c = j >> 3, ty = j & 7;
    const float* src = xb + ((size_t)c*HWD + hrow + ty)*HWD + wcol;
    float4 a = *reinterpret_cast<const float4*>(src);
    float4 q = *reinterpret_cast<const float4*>(src + 4);
    u16* dst = &sX[(ty*8)*LDW + c];
    dst[0*LDW]=f2bf(a.x); dst[1*LDW]=f2bf(a.y); dst[2*LDW]=f2bf(a.z); dst[3*LDW]=f2bf(a.w);
    dst[4*LDW]=f2bf(q.x); dst[5*LDW]=f2bf(q.y); dst[6*LDW]=f2bf(q.z); dst[7*LDW]=f2bf(q.w);
  }
  __syncthreads();
  layernorm_fb(sX, sN, g1, b1, tid);
  __syncthreads();
  const int t8 = tid >> 3, s8 = tid & 7;
  for (int h = 0; h < NH; ++h){
    {
      const u16* arow = &sN[t8*LDW];
      float acc[9];
      #pragma unroll
      for (int o = 0; o < 9; ++o) acc[o] = 0.f;
      const float* wp[9];
      #pragma unroll
      for (int o = 0; o < 3; ++o){
        const float* base = qkv_w + (size_t)(h*24 + s8*3 + o)*192;
        wp[o] = base; wp[3+o] = base + 192*192; wp[6+o] = base + 2*192*192;
      }
      for (int k0 = 0; k0 < 192; k0 += 8){
        float a[8]; up8(*reinterpret_cast<const uint4*>(arow + k0), a);
        #pragma unroll
        for (int o = 0; o < 9; ++o){
          float wv[8]; ldw8(wp[o] + k0, wv);
          #pragma unroll
          for (int e = 0; e < 8; ++e) acc[o] += a[e]*wv[e];
        }
      }
      #pragma unroll
      for (int o = 0; o < 3; ++o){
        sQ[t8*QSTR + s8*3 + o] = acc[o];
        sK[t8*QSTR + s8*3 + o] = acc[3+o];
        sV[t8*QSTR + s8*3 + o] = acc[6+o];
      }
    }
    __syncthreads();
    {
      float q24[24];
      #pragma unroll
      for (int e = 0; e < 24; ++e) q24[e] = sQ[t8*QSTR + e];
      const int ry = t8 >> 3, rx = t8 & 7;
      float p[8];
      #pragma unroll
      for (int j = 0; j < 8; ++j){
        int c = s8*8 + j;
        const float* kr = &sK[c*QSTR];
        float s = 0.f;
        #pragma unroll
        for (int e = 0; e < 24; ++e) s += q24[e]*kr[e];
        int cy = c >> 3, cx = c & 7;
        p[j] = s*SCALE + rpe[((ry-cy+7)*15 + (rx-cx+7))*NH + h];
      }
      float mx = p[0];
      #pragma unroll
      for (int j = 1; j < 8; ++j) mx = fmaxf(mx, p[j]);
      mx = fmaxf(mx, __shfl_xor(mx, 1, 64));
      mx = fmaxf(mx, __shfl_xor(mx, 2, 64));
      mx = fmaxf(mx, __shfl_xor(mx, 4, 64));
      float sum = 0.f;
      #pragma unroll
      for (int j = 0; j < 8; ++j){ p[j] = __expf(p[j] - mx); sum += p[j]; }
      sum += __shfl_xor(sum, 1, 64); sum += __shfl_xor(sum, 2, 64); sum += __shfl_xor(sum, 4, 64);
      float inv = 1.f / sum;
      float o24[24];
      #pragma unroll
      for (int e = 0; e < 24; ++e) o24[e] = 0.f;
      #pragma unroll
      for (int j = 0; j < 8; ++j){
        const float* vr = &sV[(s8*8 + j)*QSTR];
        #pragma unroll
        for (int e = 0; e < 24; ++e) o24[e] += p[j]*vr[e];
      }
      #pragma unroll
      for (int e = 0; e < 24; ++e){
        o24[e] += __shfl_xor(o24[e], 1, 64);
        o24[e] += __shfl_xor(o24[e], 2, 64);
        o24[e] += __shfl_xor(o24[e], 4, 64);
      }
      u16* mrow = &sM[t8*LDW + h*24 + s8*3];
      #pragma unroll
      for (int o = 0; o < 3; ++o) mrow[o] = f2bf(o24[s8*3 + o]*inv);
    }
    __syncthreads();
  }
  const int tg = tid >> 6, cg = tid & 63;
  {
    float acc[8][3];
    #pragma unroll
    for (int tt = 0; tt < 8; ++tt){ acc[tt][0]=0.f; acc[tt][1]=0.f; acc[tt][2]=0.f; }
    gemm83(sM, wproj + (size_t)(cg*3+0)*192, wproj + (size_t)(cg*3+1)*192, wproj + (size_t)(cg*3+2)*192, tg, acc);
    #pragma unroll
    for (int tt = 0; tt < 8; ++tt)
      #pragma unroll
      for (int j = 0; j < 3; ++j){
        int t = tg*8+tt, c = cg*3+j;
        sN[t*LDW + c] = f2bf(acc[tt][j] + bf2f(sX[t*LDW + c]));
      }
  }
  __syncthreads();
  layernorm_fb(sN, sX, g2, b2, tid);
  __syncthreads();
  float facc[8][3];
  #pragma unroll
  for (int tt = 0; tt < 8; ++tt){ facc[tt][0]=0.f; facc[tt][1]=0.f; facc[tt][2]=0.f; }
  for (int half = 0; half < 2; ++half){
    {
      float acc[8][3];
      #pragma unroll
      for (int tt = 0; tt < 8; ++tt){ acc[tt][0]=0.f; acc[tt][1]=0.f; acc[tt][2]=0.f; }
      gemm83(sX, mlp1 + (size_t)(half*192 + cg*3+0)*192, mlp1 + (size_t)(half*192 + cg*3+1)*192,
                 mlp1 + (size_t)(half*192 + cg*3+2)*192, tg, acc);
      #pragma unroll
      for (int tt = 0; tt < 8; ++tt)
        #pragma unroll
        for (int j = 0; j < 3; ++j){
          float vv = acc[tt][j];
          sM[(tg*8+tt)*LDW + cg*3+j] = f2bf(0.5f*vv*(1.f + erff(vv*0.70710678118654752f)));
        }
    }
    __syncthreads();
    gemm83(sM, mlp2 + (size_t)(cg*3+0)*384 + half*192, mlp2 + (size_t)(cg*3+1)*384 + half*192,
               mlp2 + (size_t)(cg*3+2)*384 + half*192, tg, facc);
    __syncthreads();
  }
  #pragma unroll
  for (int tt = 0; tt < 8; ++tt)
    #pragma unroll
    for (int j = 0; j < 3; ++j){
      int t = tg*8+tt, c = cg*3+j;
      sM[t*LDW + c] = f2bf(bf2f(sN[t*LDW + c]) + facc[tt][j]);
    }
  __syncthreads();
  float alpha = alpha_p[0];
  for (int j = tid; j < 1536; j += 512){
    int c = j >> 3, ty = j & 7;
    size_t goff = ((size_t)c*HWD + hrow + ty)*HWD + wcol;
    const float* src = xb + goff;
    float4 a = *reinterpret_cast<const float4*>(src);
    float4 q = *reinterpret_cast<const float4*>(src + 4);
    float wv[8];
    #pragma unroll
    for (int e = 0; e < 8; ++e) wv[e] = bf2f(sM[(ty*8 + e)*LDW + c]);
    float4 o1 = make_float4(a.x + alpha*wv[0], a.y + alpha*wv[1], a.z + alpha*wv[2], a.w + alpha*wv[3]);
    float4 o2 = make_float4(q.x + alpha*wv[4], q.y + alpha*wv[5], q.z + alpha*wv[6], q.w + alpha*wv[7]);
    *reinterpret_cast<float4*>(outb + goff)     = o1;
    *reinterpret_cast<float4*>(outb + goff + 4) = o2;
  }
}
__global__ __launch_bounds__(512) void k_oca_fb(
    const float* __restrict__ x, const float* __restrict__ og_p, const float* __restrict__ ob_p,
    const float* __restrict__ q_w, const float* __restrict__ kv_w, const float* __restrict__ oproj,
    const float* __restrict__ alpha_p, float* __restrict__ out)
{
  __shared__ __align__(16) u16 sW[64*LDW];
  __shared__ __align__(16) u16 sN[64*LDW];
  __shared__ __align__(16) u16 sQa[64*LDW];
  __shared__ __align__(16) u16 sU[144*LDW];
  __shared__ __align__(16) u16 sKb[144*32];
  __shared__ __align__(16) u16 sVb[144*32];
  const int tid = threadIdx.x;
  const int win = blockIdx.x;
  const int b  = win >> 10;
  const int wy = (win >> 5) & 31;
  const int wx = win & 31;
  const int hrow = wy*8, wcol = wx*8;
  const float* xb = x + (size_t)b*CH*HWD*HWD;
  float* outb = out + (size_t)b*CH*HWD*HWD;
  for (int j = tid; j < 1536; j += 512){
    int c = j >> 3, ty = j & 7;
    const float* src = xb + ((size_t)c*HWD + hrow + ty)*HWD + wcol;
    float4 a = *reinterpret_cast<const float4*>(src);
    float4 q = *reinterpret_cast<const float4*>(src + 4);
    u16* dst = &sW[(ty*8)*LDW + c];
    dst[0*LDW]=f2bf(a.x); dst[1*LDW]=f2bf(a.y); dst[2*LDW]=f2bf(a.z); dst[3*LDW]=f2bf(a.w);
    dst[4*LDW]=f2bf(q.x); dst[5*LDW]=f2bf(q.y); dst[6*LDW]=f2bf(q.z); dst[7*LDW]=f2bf(q.w);
  }
  for (int i = tid; i < 144*192; i += 512){
    int c = i / 144, t = i - c*144;
    int ti = t / 12, tj = t - ti*12;
    sU[t*LDW + c] = f2bf(xb[((size_t)c*HWD + refl(hrow + ti - 2))*HWD + refl(wcol + tj - 2)]);
  }
  __syncthreads();
  layernorm_fb(sW, sN, og_p, ob_p, tid);
  __syncthreads();
  const int tg = tid >> 6, cg = tid & 63;
  {
    float acc[8][3];
    #pragma unroll
    for (int tt = 0; tt < 8; ++tt){ acc[tt][0]=0.f; acc[tt][1]=0.f; acc[tt][2]=0.f; }
    gemm83(sN, q_w + (size_t)(cg*3+0)*192, q_w + (size_t)(cg*3+1)*192, q_w + (size_t)(cg*3+2)*192, tg, acc);
    #pragma unroll
    for (int tt = 0; tt < 8; ++tt)
      #pragma unroll
      for (int j = 0; j < 3; ++j)
        sQa[(tg*8+tt)*LDW + cg*3+j] = f2bf(acc[tt][j]);
  }
  __syncthreads();
  const int t8 = tid >> 3, s8 = tid & 7;
  for (int h = 0; h < NH; ++h){
    for (int i = tid; i < 144*24; i += 512){
      int tok = i / 24, d = i - tok*24;
      const float* kw = kv_w + (size_t)(h*24 + d)*192;
      const float* vw = kv_w + (size_t)(192 + h*24 + d)*192;
      const u16* arow = &sU[tok*LDW];
      float ka[4] = {0.f,0.f,0.f,0.f}, va[4] = {0.f,0.f,0.f,0.f};
      for (int k0 = 0; k0 < 192; k0 += 8){
        float a[8]; up8(*reinterpret_cast<const uint4*>(arow + k0), a);
        float kk[8]; ldw8(kw + k0, kk);
        float vv[8]; ldw8(vw + k0, vv);
        #pragma unroll
        for (int e = 0; e < 8; ++e){ ka[e&3] += a[e]*kk[e]; va[e&3] += a[e]*vv[e]; }
      }
      sKb[tok*32 + d] = f2bf(ka[0]+ka[1]+ka[2]+ka[3]);
      sVb[tok*32 + d] = f2bf(va[0]+va[1]+va[2]+va[3]);
    }
    __syncthreads();
    {
      float q24[24];
      #pragma unroll
      for (int e = 0; e < 24; ++e) q24[e] = bf2f(sQa[t8*LDW + h*24 + e]);
      float p[18];
      #pragma unroll
      for (int j = 0; j < 18; ++j){
        int c = s8*18 + j;
        const u16* kr = &sKb[c*32];
        float s = 0.f;
        #pragma unroll
        for (int e = 0; e < 24; ++e) s += q24[e]*bf2f(kr[e]);
        p[j] = s*SCALE;
      }
      float mx = p[0];
      #pragma unroll
      for (int j = 1; j < 18; ++j) mx = fmaxf(mx, p[j]);
      mx = fmaxf(mx, __shfl_xor(mx, 1, 64));
      mx = fmaxf(mx, __shfl_xor(mx, 2, 64));
      mx = fmaxf(mx, __shfl_xor(mx, 4, 64));
      float sum = 0.f;
      #pragma unroll
      for (int j = 0; j < 18; ++j){ p[j] = __expf(p[j] - mx); sum += p[j]; }
      sum += __shfl_xor(sum, 1, 64); sum += __shfl_xor(sum, 2, 64); sum += __shfl_xor(sum, 4, 64);
      float inv = 1.f / sum;
      float o24[24];
      #pragma unroll
      for (int e = 0; e < 24; ++e) o24[e] = 0.f;
      #pragma unroll
      for (int j = 0; j < 18; ++j){
        const u16* vr = &sVb[(s8*18 + j)*32];
        #pragma unroll
        for (int e = 0; e < 24; ++e) o24[e] += p[j]*bf2f(vr[e]);
      }
      #pragma unroll
      for (int e = 0; e < 24; ++e){
        o24[e] += __shfl_xor(o24[e], 1, 64);
        o24[e] += __shfl_xor(o24[e], 2, 64);
        o24[e] += __shfl_xor(o24[e], 4, 64);
      }
      u16* orow = &sN[t8*LDW + h*24 + s8*3];
      #pragma unroll
      for (int o = 0; o < 3; ++o) orow[o] = f2bf(o24[s8*3 + o]*inv);
    }
    __syncthreads();
  }
  {
    float acc[8][3];
    #pragma unroll
    for (int tt = 0; tt < 8; ++tt){ acc[tt][0]=0.f; acc[tt][1]=0.f; acc[tt][2]=0.f; }
    gemm83(sN, oproj + (size_t)(cg*3+0)*192, oproj + (size_t)(cg*3+1)*192, oproj + (size_t)(cg*3+2)*192, tg, acc);
    #pragma unroll
    for (int tt = 0; tt < 8; ++tt)
      #pragma unroll
      for (int j = 0; j < 3; ++j){
        int t = tg*8+tt, c = cg*3+j;
        sQa[t*LDW + c] = f2bf(acc[tt][j] + bf2f(sW[t*LDW + c]));
      }
  }
  __syncthreads();
  float beta = 1.f - alpha_p[0];
  for (int j = tid; j < 1536; j += 512){
    int c = j >> 3, ty = j & 7;
    size_t goff = ((size_t)c*HWD + hrow + ty)*HWD + wcol;
    float* dst = outb + goff;
    float4 a = *reinterpret_cast<const float4*>(dst);
    float4 q = *reinterpret_cast<const float4*>(dst + 4);
    float wv[8];
    #pragma unroll
    for (int e = 0; e < 8; ++e) wv[e] = bf2f(sQa[(ty*8 + e)*LDW + c]);
    float4 o1 = make_float4(a.x + beta*wv[0], a.y + beta*wv[1], a.z + beta*wv[2], a.w + beta*wv[3]);
    float4 o2 = make_float4(q.x + beta*wv[4], q.y + beta*wv[5], q.z + beta*wv[6], q.w + beta*wv[7]);
    *reinterpret_cast<float4*>(dst)     = o1;
    *reinterpret_cast<float4*>(dst + 4) = o2;
  }
}

extern "C" void kernel_launch(void* const* d_in, const int* in_sizes, int n_in,
                              void* d_out, int out_size, void* d_ws, size_t ws_size,
                              hipStream_t stream) {
  const float* x     = (const float*)d_in[0];
  const float* g1    = (const float*)d_in[1];
  const float* b1    = (const float*)d_in[2];
  const float* qkvw  = (const float*)d_in[3];
  const float* rpe   = (const float*)d_in[4];
  const float* wproj = (const float*)d_in[5];
  const float* g2    = (const float*)d_in[6];
  const float* b2    = (const float*)d_in[7];
  const float* mlp1  = (const float*)d_in[8];
  const float* mlp2  = (const float*)d_in[9];
  const float* alpha = (const float*)d_in[10];
  const float* og    = (const float*)d_in[11];
  const float* ob    = (const float*)d_in[12];
  const float* q_w   = (const float*)d_in[13];
  const float* kv_w  = (const float*)d_in[14];
  const float* oproj = (const float*)d_in[15];
  float* out = (float*)d_out;

  if (ws_size >= (size_t)WS_NEED) {
    u16*   ws16 = (u16*)d_ws;
    float* wsf  = (float*)d_ws;
    k_swz<<<36*6, 64, 0, stream>>>(qkvw,  g1,      ws16 + WS_W1/2,  6, 192);
    k_swz<<<24*6, 64, 0, stream>>>(kv_w,  nullptr, ws16 + WS_WKV/2, 6, 192);
    k_swz<<<12*6, 64, 0, stream>>>(q_w,   og,      ws16 + WS_WQ/2,  6, 192);
    k_swz<<<12*6, 64, 0, stream>>>(wproj, nullptr, ws16 + WS_WP/2,  6, 192);
    k_swz<<<24*6, 64, 0, stream>>>(mlp1,  g2,      ws16 + WS_WM1/2, 6, 192);
    k_swz<<<12*12,64, 0, stream>>>(mlp2,  nullptr, ws16 + WS_WM2/2, 12, 384);
    k_swz<<<12*6, 64, 0, stream>>>(oproj, nullptr, ws16 + WS_WO/2,  6, 192);
    k_cvec<<<576, 64, 0, stream>>>(qkvw, g1, b1, (float*)((char*)d_ws + WS_C1),  (float*)((char*)d_ws + WS_C2),  192);
    k_cvec<<<192, 64, 0, stream>>>(q_w,  og, ob, (float*)((char*)d_ws + WS_C1O), (float*)((char*)d_ws + WS_C2O), 192);
    k_cvec<<<384, 64, 0, stream>>>(mlp1, g2, b2, (float*)((char*)d_ws + WS_C1M), (float*)((char*)d_ws + WS_C2M), 192);
    k_kv<<<2048, 512, 0, stream>>>(x, ws16 + WS_WKV/2, ws16 + WS_KV/2);
    if (ws_size >= (size_t)WS_NEED1) {
      u16* xoca = ws16 + WS_XOCA/2;
      k_oca_attn<1><<<2048, 512, 0, stream>>>(x, ws16, wsf, alpha, out, xoca);
      k_msa<1><<<2048, 512, 0, stream>>>(x, ws16, wsf, rpe, alpha, out, xoca);
    } else {
      k_oca_attn<0><<<2048, 512, 0, stream>>>(x, ws16, wsf, alpha, out, nullptr);
      k_msa<0><<<2048, 512, 0, stream>>>(x, ws16, wsf, rpe, alpha, out, nullptr);
    }
  } else {
    k_msa_fb<<<2048, 512, 0, stream>>>(x, g1, b1, qkvw, rpe, wproj, g2, b2, mlp1, mlp2, alpha, out);
    k_oca_fb<<<2048, 512, 0, stream>>>(x, og, ob, q_w, kv_w, oproj, alpha, out);
  }
}

// Round 7
// 1070.410 us; speedup vs baseline: 3.9920x; 1.6211x over previous
//
#include <hip/hip_runtime.h>
#include <hip/hip_bf16.h>

typedef unsigned short u16;
typedef unsigned int   u32;
typedef __attribute__((ext_vector_type(8))) short bf16x8;
typedef __attribute__((ext_vector_type(4))) float f32x4;

#define CH   192
#define NH   8
#define HWD  256
#define LDW  200   // bf16 row stride for 192-wide LDS tiles (400B)
#define QSTR 28
#define SCALE 0.20412414523193154f

__device__ __forceinline__ float bf2f(u16 u){ u32 v = ((u32)u) << 16; return __builtin_bit_cast(float, v); }
__device__ __forceinline__ u16 f2bf(float f){
  u32 u = __builtin_bit_cast(u32, f);
  u = (u + 0x7fffu + ((u >> 16) & 1u)) >> 16;
  return (u16)u;
}
__device__ __forceinline__ float lo2f(u32 p){ return __builtin_bit_cast(float, p << 16); }
__device__ __forceinline__ float hi2f(u32 p){ return __builtin_bit_cast(float, p & 0xffff0000u); }
__device__ __forceinline__ void up8(uint4 q, float* f){
  f[0]=lo2f(q.x); f[1]=hi2f(q.x); f[2]=lo2f(q.y); f[3]=hi2f(q.y);
  f[4]=lo2f(q.z); f[5]=hi2f(q.z); f[6]=lo2f(q.w); f[7]=hi2f(q.w);
}
__device__ __forceinline__ void ldw8(const float* __restrict__ p, float* f){
  float4 a = *reinterpret_cast<const float4*>(p);
  float4 b = *reinterpret_cast<const float4*>(p + 4);
  f[0]=a.x; f[1]=a.y; f[2]=a.z; f[3]=a.w;
  f[4]=b.x; f[5]=b.y; f[6]=b.z; f[7]=b.w;
}
__device__ __forceinline__ int refl(int v){ v = v < 0 ? -v : v; return v < HWD ? v : 2*(HWD-1) - v; }
__device__ __forceinline__ f32x4 mfma16(bf16x8 a, bf16x8 b, f32x4 c){
  return __builtin_amdgcn_mfma_f32_16x16x32_bf16(a, b, c, 0, 0, 0);
}
__device__ __forceinline__ bf16x8 afrag(const u16* pool, int base, int stride, int row, int kt, int l){
  return *reinterpret_cast<const bf16x8*>(pool + base + row*stride + kt*32 + ((l>>4)<<3));
}
__device__ __forceinline__ bf16x8 bfrag(const u16* __restrict__ w, int tile, int l){
  return *reinterpret_cast<const bf16x8*>(w + tile*512 + l*8);
}
__device__ __forceinline__ void ln_stats(const u16* buf, float* st, int tid){
  int r = tid >> 3, sub = tid & 7;
  const uint4* rp = reinterpret_cast<const uint4*>(buf + r*LDW + sub*24);
  float v[24]; up8(rp[0], v); up8(rp[1], v+8); up8(rp[2], v+16);
  float s = 0.f, s2 = 0.f;
  #pragma unroll
  for (int e = 0; e < 24; ++e){ s += v[e]; s2 += v[e]*v[e]; }
  s  += __shfl_xor(s, 1, 64);  s  += __shfl_xor(s, 2, 64);  s  += __shfl_xor(s, 4, 64);
  s2 += __shfl_xor(s2, 1, 64); s2 += __shfl_xor(s2, 2, 64); s2 += __shfl_xor(s2, 4, 64);
  if (sub == 0){
    float m = s*(1.f/192.f);
    float var = s2*(1.f/192.f) - m*m;
    st[r*2] = m; st[r*2+1] = rsqrtf(var + 1e-5f);
  }
}

// ---------------- workspace layout (bytes) ----------------
#define WS_KV   ((size_t)0)                     // 2*65536*384 bf16 = 100,663,296
#define WS_W1   ((size_t)100663296)
#define WS_WKV  (WS_W1  + 221184)
#define WS_WQ   (WS_WKV + 147456)
#define WS_WP   (WS_WQ  + 73728)
#define WS_WM1  (WS_WP  + 73728)
#define WS_WM2  (WS_WM1 + 147456)
#define WS_WO   (WS_WM2 + 147456)
#define WS_C1   (WS_WO  + 73728)
#define WS_C2   (WS_C1  + 2304)
#define WS_C1O  (WS_C2  + 2304)
#define WS_C2O  (WS_C1O + 768)
#define WS_C1M  (WS_C2O + 768)
#define WS_C2M  (WS_C1M + 1536)
#define WS_NEED (WS_C2M + 1536)                 // = 101,557,248
#define WS_XOCA WS_NEED                         // [2048][192][64] bf16 = 50,331,648
#define WS_NEED1 (WS_XOCA + 50331648)

// ---------------- prep kernels ----------------
__global__ void k_swz(const float* __restrict__ src, const float* __restrict__ gv,
                      u16* __restrict__ dst, int KT, int K){
  int tile = blockIdx.x; int nt = tile / KT, kt = tile - nt*KT;
  int l = threadIdx.x;
  int row = nt*16 + (l & 15);
  int kb  = kt*32 + ((l>>4)<<3);
  const float* s = src + (size_t)row*K + kb;
  u16* d = dst + (size_t)tile*512 + l*8;
  #pragma unroll
  for (int e = 0; e < 8; ++e){
    float w = s[e];
    if (gv) w *= gv[kb + e];
    d[e] = f2bf(w);
  }
}
__global__ void k_cvec(const float* __restrict__ W, const float* __restrict__ g,
                       const float* __restrict__ b, float* __restrict__ c1,
                       float* __restrict__ c2, int K){
  int n = blockIdx.x; int l = threadIdx.x;
  float s1 = 0.f, s2 = 0.f;
  for (int k = l; k < K; k += 64){
    float w = W[(size_t)n*K + k];
    s1 += w*g[k]; s2 += w*b[k];
  }
  #pragma unroll
  for (int d = 1; d < 64; d <<= 1){ s1 += __shfl_xor(s1, d, 64); s2 += __shfl_xor(s2, d, 64); }
  if (l == 0){ c1[n] = s1; c2[n] = s2; }
}

// ---------------- k_kv: per-pixel KV GEMM (dedup of unfold) ----------------
__global__ __launch_bounds__(512) void k_kv(const float* __restrict__ x,
                                            const u16* __restrict__ wkv,
                                            u16* __restrict__ KV){
  __shared__ __align__(16) u16 sA[64*LDW];
  const int blk = blockIdx.x;                // 2048
  const int batch = blk >> 10;
  const int pix0 = (blk & 1023) * 64;
  const float* xb = x + (size_t)batch*CH*65536;

  for (int idx = threadIdx.x; idx < 1536; idx += 512){
    int c = idx >> 3, s = idx & 7;
    const float* p = xb + (size_t)c*65536 + pix0 + s*8;
    float4 a = *reinterpret_cast<const float4*>(p);
    float4 b = *reinterpret_cast<const float4*>(p + 4);
    u16* d = &sA[(s*8)*LDW + c];
    d[0*LDW]=f2bf(a.x); d[1*LDW]=f2bf(a.y); d[2*LDW]=f2bf(a.z); d[3*LDW]=f2bf(a.w);
    d[4*LDW]=f2bf(b.x); d[5*LDW]=f2bf(b.y); d[6*LDW]=f2bf(b.z); d[7*LDW]=f2bf(b.w);
  }
  __syncthreads();

  const int w = threadIdx.x >> 6, l = threadIdx.x & 63;
  const int mt = w >> 1, half = w & 1;
  const f32x4 z4 = {0.f,0.f,0.f,0.f};
  f32x4 acc[12];
  #pragma unroll
  for (int j = 0; j < 12; ++j) acc[j] = z4;
  const int arow = mt*16 + (l & 15);
  for (int kt = 0; kt < 6; ++kt){
    bf16x8 a = afrag(sA, 0, LDW, arow, kt, l);
    #pragma unroll
    for (int j = 0; j < 12; ++j){
      int nt = half*12 + j;
      acc[j] = mfma16(a, bfrag(wkv, nt*6 + kt, l), acc[j]);
    }
  }
  u16* kvb = KV + ((size_t)batch*65536 + pix0)*384;
  const int rbase = mt*16 + ((l>>4)<<2);
  #pragma unroll
  for (int j = 0; j < 12; ++j){
    int col = (half*12 + j)*16 + (l & 15);
    #pragma unroll
    for (int r = 0; r < 4; ++r)
      kvb[(size_t)(rbase + r)*384 + col] = f2bf(acc[j][r]);
  }
}

// ---------------- k_oca_attn: MFMA cross attention ----------------
// LDS layout (u16 offsets):
#define P_   0        // x window [64][200] during P0/P1; then P [64][168] bf16; then XO [64][200]
#define OW_  0
#define XO_  0
#define OQ_  12800    // q [64][200]; per-head slice overwritten by attn-out
#define KF_  25600    // K in B-frag order: 9 tiles x 512 u16
#define VT_  30208    // V^T [32][168] bf16
#define STM_ 35584    // row max  [64][2] f32
#define STS_ 35840    // row sum  [64][2] f32
#define OST_ 36096    // LN stats 128 f32
#define OPOOLN 36352  // 72,704 bytes

template<int MODE>
__global__ __launch_bounds__(512) void k_oca_attn(
    const float* __restrict__ x, const u16* __restrict__ ws16, const float* __restrict__ wsf,
    const float* __restrict__ alpha_p, float* __restrict__ out, u16* __restrict__ xoca)
{
  __shared__ __align__(16) u16 pool[OPOOLN];
  float* stm = reinterpret_cast<float*>(pool + STM_);
  float* sts = reinterpret_cast<float*>(pool + STS_);
  float* st  = reinterpret_cast<float*>(pool + OST_);
  const u16* KV = ws16 + WS_KV/2;
  const u16* WQ = ws16 + WS_WQ/2;
  const u16* WO = ws16 + WS_WO/2;
  const float* c1o = wsf + WS_C1O/4;
  const float* c2o = wsf + WS_C2O/4;

  const int tid = threadIdx.x;
  const int win = blockIdx.x;
  const int b  = win >> 10;
  const int wy = (win >> 5) & 31;
  const int wx = win & 31;
  const int hrow = wy*8, wcol = wx*8;
  const float* xb = x + (size_t)b*CH*HWD*HWD;
  float* outb = out + (size_t)b*CH*HWD*HWD;
  const size_t pixBase = (size_t)b*65536;
  const f32x4 z4 = {0.f,0.f,0.f,0.f};

  // P0: window -> OW bf16
  for (int j = tid; j < 1536; j += 512){
    int c = j >> 3, ty = j & 7;
    const float* src = xb + ((size_t)c*HWD + hrow + ty)*HWD + wcol;
    float4 a = *reinterpret_cast<const float4*>(src);
    float4 q = *reinterpret_cast<const float4*>(src + 4);
    u16* dst = &pool[OW_ + (ty*8)*LDW + c];
    dst[0*LDW]=f2bf(a.x); dst[1*LDW]=f2bf(a.y); dst[2*LDW]=f2bf(a.z); dst[3*LDW]=f2bf(a.w);
    dst[4*LDW]=f2bf(q.x); dst[5*LDW]=f2bf(q.y); dst[6*LDW]=f2bf(q.z); dst[7*LDW]=f2bf(q.w);
  }
  __syncthreads();
  ln_stats(pool + OW_, st, tid);
  __syncthreads();

  const int w = tid >> 6, l = tid & 63;
  const int mt = w >> 1;
  const int arow = mt*16 + (l & 15);
  const int rbase = mt*16 + ((l>>4)<<2);

  // P1: q = SCALE * (rs*(x @ Wq'^T - m*c1o) + c2o) -> OQ  (wave w: half = w&1)
  {
    const int half = w & 1;
    f32x4 acc[6];
    #pragma unroll
    for (int j = 0; j < 6; ++j) acc[j] = z4;
    for (int kt = 0; kt < 6; ++kt){
      bf16x8 a = afrag(pool, OW_, LDW, arow, kt, l);
      #pragma unroll
      for (int j = 0; j < 6; ++j)
        acc[j] = mfma16(a, bfrag(WQ, (half*6 + j)*6 + kt, l), acc[j]);
    }
    float mr[4], rr[4];
    #pragma unroll
    for (int r = 0; r < 4; ++r){ mr[r] = st[(rbase+r)*2]; rr[r] = st[(rbase+r)*2+1]; }
    #pragma unroll
    for (int j = 0; j < 6; ++j){
      int col = (half*6 + j)*16 + (l & 15);
      float c1v = c1o[col], c2v = c2o[col];
      #pragma unroll
      for (int r = 0; r < 4; ++r)
        pool[OQ_ + (rbase + r)*LDW + col] = f2bf(SCALE*(rr[r]*(acc[j][r] - mr[r]*c1v) + c2v));
    }
  }
  __syncthreads();   // also: OW no longer needed (residual re-read from global)

  // zero pads: OQ cols 192..199 (h=7 A-frag overread; NaN x 0 = NaN!),
  //            KF k-rows 24..31 (seg3), VT everything, P key-pad cols 144..159
  {
    const uint4 zz = make_uint4(0,0,0,0);
    for (int i = tid; i < 64; i += 512)
      *reinterpret_cast<uint4*>(pool + OQ_ + i*LDW + 192) = zz;
    for (int i = tid; i < 144; i += 512)
      *reinterpret_cast<uint4*>(pool + KF_ + (i>>4)*512 + 384 + (i&15)*8) = zz;
    for (int i = tid; i < 672; i += 512)
      *reinterpret_cast<uint4*>(pool + VT_ + i*8) = zz;
    for (int i = tid; i < 128; i += 512)
      *reinterpret_cast<uint4*>(pool + P_ + (i>>1)*168 + 144 + (i&1)*8) = zz;
  }
  __syncthreads();

  const int ng   = w & 1;
  const int ntlo = ng ? 4 : 0;
  const int ntn  = ng ? 5 : 4;

  for (int h = 0; h < NH; ++h){
    // stage K (B-frag order) and V^T for this head
    for (int i = tid; i < 432; i += 512){
      int tok = i / 3, seg = i - tok*3;
      int ti = tok / 12, tj = tok - ti*12;
      int pix = refl(hrow + ti - 2)*HWD + refl(wcol + tj - 2);
      const u16* src = KV + (pixBase + (size_t)pix)*384 + h*24 + seg*8;
      uint4 kk = *reinterpret_cast<const uint4*>(src);
      uint4 vv = *reinterpret_cast<const uint4*>(src + 192);
      *reinterpret_cast<uint4*>(pool + KF_ + (tok>>4)*512 + (seg*16 + (tok&15))*8) = kk;
      const u16* vp = reinterpret_cast<const u16*>(&vv);
      #pragma unroll
      for (int e = 0; e < 8; ++e)
        pool[VT_ + (seg*8 + e)*168 + tok] = vp[e];
    }
    __syncthreads();  // B1

    // QK^T: wave (mt, ng) computes S tiles [16 rows][ntn*16 cols]
    f32x4 S[5];
    #pragma unroll
    for (int t = 0; t < 5; ++t) S[t] = z4;
    {
      bf16x8 a = *reinterpret_cast<const bf16x8*>(pool + OQ_ + arow*LDW + h*24 + ((l>>4)<<3));
      #pragma unroll
      for (int t = 0; t < 5; ++t)
        if (t < ntn)
          S[t] = mfma16(a, *reinterpret_cast<const bf16x8*>(pool + KF_ + (ntlo + t)*512 + l*8), z4);
    }
    // partial row max (C layout: row = rbase + r, col = nt*16 + (l&15))
    #pragma unroll
    for (int r = 0; r < 4; ++r){
      float mx = -3.0e38f;
      #pragma unroll
      for (int t = 0; t < 5; ++t) if (t < ntn) mx = fmaxf(mx, S[t][r]);
      mx = fmaxf(mx, __shfl_xor(mx, 1, 64));
      mx = fmaxf(mx, __shfl_xor(mx, 2, 64));
      mx = fmaxf(mx, __shfl_xor(mx, 4, 64));
      mx = fmaxf(mx, __shfl_xor(mx, 8, 64));
      if ((l & 15) == 0) stm[(rbase + r)*2 + ng] = mx;
    }
    __syncthreads();  // B2

    // exp + unnormalized P -> LDS + partial sums
    #pragma unroll
    for (int r = 0; r < 4; ++r){
      int row = rbase + r;
      float m = fmaxf(stm[row*2], stm[row*2 + 1]);
      float sum = 0.f;
      #pragma unroll
      for (int t = 0; t < 5; ++t) if (t < ntn){
        float p = __expf(S[t][r] - m);
        sum += p;
        pool[P_ + row*168 + (ntlo + t)*16 + (l & 15)] = f2bf(p);
      }
      sum += __shfl_xor(sum, 1, 64);
      sum += __shfl_xor(sum, 2, 64);
      sum += __shfl_xor(sum, 4, 64);
      sum += __shfl_xor(sum, 8, 64);
      if ((l & 15) == 0) sts[row*2 + ng] = sum;
    }
    __syncthreads();  // B3

    // PV: O[64][24] = P @ V ; wave (mt, ng): rows mt*16.., d-tile = ng
    {
      f32x4 O = z4;
      #pragma unroll
      for (int kt = 0; kt < 5; ++kt){
        bf16x8 pa = *reinterpret_cast<const bf16x8*>(pool + P_  + arow*168 + kt*32 + ((l>>4)<<3));
        bf16x8 vb = *reinterpret_cast<const bf16x8*>(pool + VT_ + (ng*16 + (l & 15))*168 + kt*32 + ((l>>4)<<3));
        O = mfma16(pa, vb, O);
      }
      int d = ng*16 + (l & 15);
      if (d < 24){
        #pragma unroll
        for (int r = 0; r < 4; ++r){
          int row = rbase + r;
          float inv = 1.f / (sts[row*2] + sts[row*2 + 1]);
          pool[OQ_ + row*LDW + h*24 + d] = f2bf(O[r]*inv);
        }
      }
    }
    __syncthreads();  // B4 (protects K/V/P for next head)
  }

  // P4: attn @ oproj^T -> XO_ (no residual; x re-read from global in epilogue)
  {
    const int half = w & 1;
    f32x4 acc[6];
    #pragma unroll
    for (int j = 0; j < 6; ++j) acc[j] = z4;
    for (int kt = 0; kt < 6; ++kt){
      bf16x8 a = afrag(pool, OQ_, LDW, arow, kt, l);
      #pragma unroll
      for (int j = 0; j < 6; ++j)
        acc[j] = mfma16(a, bfrag(WO, (half*6 + j)*6 + kt, l), acc[j]);
    }
    __syncthreads();  // XO_ overlays P region; all P reads finished (B4), barrier for ordering
    #pragma unroll
    for (int j = 0; j < 6; ++j){
      int col = (half*6 + j)*16 + (l & 15);
      #pragma unroll
      for (int r = 0; r < 4; ++r)
        pool[XO_ + (rbase + r)*LDW + col] = f2bf(acc[j][r]);
    }
  }
  __syncthreads();

  if (MODE == 0){
    // out = x + beta*(XO + x) = (1+beta)*x + beta*XO
    float beta = 1.f - alpha_p[0];
    float xg = 1.f + beta;
    for (int j = tid; j < 1536; j += 512){
      int c = j >> 3, ty = j & 7;
      size_t goff = ((size_t)c*HWD + hrow + ty)*HWD + wcol;
      const float* src = xb + goff;
      float4 a = *reinterpret_cast<const float4*>(src);
      float4 q = *reinterpret_cast<const float4*>(src + 4);
      float wv[8];
      #pragma unroll
      for (int e = 0; e < 8; ++e) wv[e] = bf2f(pool[XO_ + (ty*8 + e)*LDW + c]);
      float4 o1 = make_float4(xg*a.x + beta*wv[0], xg*a.y + beta*wv[1], xg*a.z + beta*wv[2], xg*a.w + beta*wv[3]);
      float4 o2 = make_float4(xg*q.x + beta*wv[4], xg*q.y + beta*wv[5], xg*q.z + beta*wv[6], xg*q.w + beta*wv[7]);
      *reinterpret_cast<float4*>(outb + goff)     = o1;
      *reinterpret_cast<float4*>(outb + goff + 4) = o2;
    }
  } else {
    // x_oca = XO + x -> ws, channel-major [192][64] bf16 per window
    u16* xw = xoca + (size_t)win*12288;
    for (int j = tid; j < 1536; j += 512){
      int c = j >> 3, ty = j & 7;
      size_t goff = ((size_t)c*HWD + hrow + ty)*HWD + wcol;
      const float* src = xb + goff;
      float4 a = *reinterpret_cast<const float4*>(src);
      float4 q = *reinterpret_cast<const float4*>(src + 4);
      float xv[8] = {a.x,a.y,a.z,a.w,q.x,q.y,q.z,q.w};
      u32 wds[4];
      #pragma unroll
      for (int e = 0; e < 4; ++e){
        u32 lo = f2bf(bf2f(pool[XO_ + (ty*8 + 2*e  )*LDW + c]) + xv[2*e]);
        u32 hi = f2bf(bf2f(pool[XO_ + (ty*8 + 2*e+1)*LDW + c]) + xv[2*e+1]);
        wds[e] = lo | (hi << 16);
      }
      uint4 o; o.x = wds[0]; o.y = wds[1]; o.z = wds[2]; o.w = wds[3];
      *reinterpret_cast<uint4*>(xw + c*64 + ty*8) = o;
    }
  }
}

// ---------------- k_msa: window MSA + MLP (MFMA); final combine ----------------
#define SX   0
#define SN   12800
#define SQKV 25600
#define SG   25600
#define SM   62464
#define SST  75264
#define POOLSZ 75520

template<int MODE>
__global__ __launch_bounds__(512) void k_msa(
    const float* __restrict__ x, const u16* __restrict__ ws16, const float* __restrict__ wsf,
    const float* __restrict__ rpe, const float* __restrict__ alpha_p, float* __restrict__ out,
    const u16* __restrict__ xoca)
{
  __shared__ __align__(16) u16 pool[POOLSZ];
  float* st = reinterpret_cast<float*>(pool + SST);
  const u16* W1  = ws16 + WS_W1/2;
  const u16* WP  = ws16 + WS_WP/2;
  const u16* WM1 = ws16 + WS_WM1/2;
  const u16* WM2 = ws16 + WS_WM2/2;
  const float* c1  = wsf + WS_C1/4;
  const float* c2  = wsf + WS_C2/4;
  const float* c1m = wsf + WS_C1M/4;
  const float* c2m = wsf + WS_C2M/4;

  const int tid = threadIdx.x;
  const int win = blockIdx.x;
  const int b  = win >> 10;
  const int wy = (win >> 5) & 31;
  const int wx = win & 31;
  const int hrow = wy*8, wcol = wx*8;
  const float* xb = x + (size_t)b*CH*HWD*HWD;
  float* outb = out + (size_t)b*CH*HWD*HWD;

  // P0: window -> sX bf16
  for (int j = tid; j < 1536; j += 512){
    int c = j >> 3, ty = j & 7;
    const float* src = xb + ((size_t)c*HWD + hrow + ty)*HWD + wcol;
    float4 a = *reinterpret_cast<const float4*>(src);
    float4 q = *reinterpret_cast<const float4*>(src + 4);
    u16* dst = &pool[SX + (ty*8)*LDW + c];
    dst[0*LDW]=f2bf(a.x); dst[1*LDW]=f2bf(a.y); dst[2*LDW]=f2bf(a.z); dst[3*LDW]=f2bf(a.w);
    dst[4*LDW]=f2bf(q.x); dst[5*LDW]=f2bf(q.y); dst[6*LDW]=f2bf(q.z); dst[7*LDW]=f2bf(q.w);
  }
  __syncthreads();
  ln_stats(pool + SX, st, tid);
  __syncthreads();

  const int w = tid >> 6, l = tid & 63;
  const int mt = w >> 1, half = w & 1;
  const int arow = mt*16 + (l & 15);
  const int rbase = mt*16 + ((l>>4)<<2);
  const f32x4 z4 = {0.f,0.f,0.f,0.f};

  // P2a: qkv (LN folded), N=576
  {
    f32x4 acc[18];
    #pragma unroll
    for (int j = 0; j < 18; ++j) acc[j] = z4;
    for (int kt = 0; kt < 6; ++kt){
      bf16x8 a = afrag(pool, SX, LDW, arow, kt, l);
      #pragma unroll
      for (int j = 0; j < 18; ++j)
        acc[j] = mfma16(a, bfrag(W1, (half*18 + j)*6 + kt, l), acc[j]);
    }
    float mr[4], rr[4];
    #pragma unroll
    for (int r = 0; r < 4; ++r){ mr[r] = st[(rbase+r)*2]; rr[r] = st[(rbase+r)*2+1]; }
    #pragma unroll
    for (int j = 0; j < 18; ++j){
      int col = (half*18 + j)*16 + (l & 15);
      float c1v = c1[col], c2v = c2[col];
      #pragma unroll
      for (int r = 0; r < 4; ++r){
        int row = rbase + r;
        float v = rr[r]*(acc[j][r] - mr[r]*c1v) + c2v;
        pool[SQKV + row*576 + (col ^ (((row>>3)&7)<<3))] = f2bf(v);
      }
    }
  }
  __syncthreads();

  // P2b: attention (XOR-swizzled qkv reads)
  {
    const int t8 = tid >> 3, s8 = tid & 7;
    const int ry = t8 >> 3, rx = t8 & 7;
    const int swq = ((t8 >> 3) & 7) << 3;
    const int swk = s8 << 3;
    for (int h = 0; h < NH; ++h){
      float p[8];
      {
        float q24[24];
        #pragma unroll
        for (int seg = 0; seg < 3; ++seg){
          uint4 v = *reinterpret_cast<const uint4*>(pool + SQKV + t8*576 + ((h*24 + seg*8) ^ swq));
          up8(v, q24 + seg*8);
        }
        #pragma unroll
        for (int j = 0; j < 8; ++j){
          int c = s8*8 + j;
          float k24[24];
          #pragma unroll
          for (int seg = 0; seg < 3; ++seg){
            uint4 v = *reinterpret_cast<const uint4*>(pool + SQKV + c*576 + ((192 + h*24 + seg*8) ^ swk));
            up8(v, k24 + seg*8);
          }
          float s = 0.f;
          #pragma unroll
          for (int e = 0; e < 24; ++e) s += q24[e]*k24[e];
          int cy = c >> 3, cx = c & 7;
          p[j] = s*SCALE + rpe[((ry-cy+7)*15 + (rx-cx+7))*NH + h];
        }
      }
      float mx = p[0];
      #pragma unroll
      for (int j = 1; j < 8; ++j) mx = fmaxf(mx, p[j]);
      mx = fmaxf(mx, __shfl_xor(mx, 1, 64));
      mx = fmaxf(mx, __shfl_xor(mx, 2, 64));
      mx = fmaxf(mx, __shfl_xor(mx, 4, 64));
      float sum = 0.f;
      #pragma unroll
      for (int j = 0; j < 8; ++j){ p[j] = __expf(p[j] - mx); sum += p[j]; }
      sum += __shfl_xor(sum, 1, 64); sum += __shfl_xor(sum, 2, 64); sum += __shfl_xor(sum, 4, 64);
      float inv = 1.f / sum;
      float o24[24];
      #pragma unroll
      for (int seg = 0; seg < 3; ++seg){
        float o8[8];
        #pragma unroll
        for (int e = 0; e < 8; ++e) o8[e] = 0.f;
        #pragma unroll
        for (int j = 0; j < 8; ++j){
          int c = s8*8 + j;
          uint4 v = *reinterpret_cast<const uint4*>(pool + SQKV + c*576 + ((384 + h*24 + seg*8) ^ swk));
          float v8[8]; up8(v, v8);
          #pragma unroll
          for (int e = 0; e < 8; ++e) o8[e] += p[j]*v8[e];
        }
        #pragma unroll
        for (int e = 0; e < 8; ++e) o24[seg*8 + e] = o8[e];
      }
      #pragma unroll
      for (int e = 0; e < 24; ++e){
        o24[e] += __shfl_xor(o24[e], 1, 64);
        o24[e] += __shfl_xor(o24[e], 2, 64);
        o24[e] += __shfl_xor(o24[e], 4, 64);
      }
      u16* mrow = &pool[SM + t8*LDW + h*24 + s8*3];
      #pragma unroll
      for (int o = 0; o < 3; ++o) mrow[o] = f2bf(o24[s8*3 + o]*inv);
    }
  }
  __syncthreads();

  // P3: xw2 = msa @ wproj^T + x -> sN
  {
    f32x4 acc[6];
    #pragma unroll
    for (int j = 0; j < 6; ++j) acc[j] = z4;
    for (int kt = 0; kt < 6; ++kt){
      bf16x8 a = afrag(pool, SM, LDW, arow, kt, l);
      #pragma unroll
      for (int j = 0; j < 6; ++j)
        acc[j] = mfma16(a, bfrag(WP, (half*6 + j)*6 + kt, l), acc[j]);
    }
    #pragma unroll
    for (int j = 0; j < 6; ++j){
      int col = (half*6 + j)*16 + (l & 15);
      #pragma unroll
      for (int r = 0; r < 4; ++r){
        int row = rbase + r;
        pool[SN + row*LDW + col] = f2bf(acc[j][r] + bf2f(pool[SX + row*LDW + col]));
      }
    }
  }
  __syncthreads();
  ln_stats(pool + SN, st, tid);
  __syncthreads();

  // P5: gelu(LN2-folded mlp1) -> sG
  {
    f32x4 acc[12];
    #pragma unroll
    for (int j = 0; j < 12; ++j) acc[j] = z4;
    for (int kt = 0; kt < 6; ++kt){
      bf16x8 a = afrag(pool, SN, LDW, arow, kt, l);
      #pragma unroll
      for (int j = 0; j < 12; ++j)
        acc[j] = mfma16(a, bfrag(WM1, (half*12 + j)*6 + kt, l), acc[j]);
    }
    float mr[4], rr[4];
    #pragma unroll
    for (int r = 0; r < 4; ++r){ mr[r] = st[(rbase+r)*2]; rr[r] = st[(rbase+r)*2+1]; }
    #pragma unroll
    for (int j = 0; j < 12; ++j){
      int col = (half*12 + j)*16 + (l & 15);
      float c1v = c1m[col], c2v = c2m[col];
      #pragma unroll
      for (int r = 0; r < 4; ++r){
        float hv = rr[r]*(acc[j][r] - mr[r]*c1v) + c2v;
        float gl = 0.5f*hv*(1.f + erff(hv*0.70710678118654752f));
        pool[SG + (rbase + r)*392 + col] = f2bf(gl);
      }
    }
  }
  __syncthreads();

  // P6: x_win = gelu @ mlp2^T + xw2 -> sM
  {
    f32x4 acc[6];
    #pragma unroll
    for (int j = 0; j < 6; ++j) acc[j] = z4;
    for (int kt = 0; kt < 12; ++kt){
      bf16x8 a = afrag(pool, SG, 392, arow, kt, l);
      #pragma unroll
      for (int j = 0; j < 6; ++j)
        acc[j] = mfma16(a, bfrag(WM2, (half*6 + j)*12 + kt, l), acc[j]);
    }
    #pragma unroll
    for (int j = 0; j < 6; ++j){
      int col = (half*6 + j)*16 + (l & 15);
      #pragma unroll
      for (int r = 0; r < 4; ++r){
        int row = rbase + r;
        pool[SM + row*LDW + col] = f2bf(acc[j][r] + bf2f(pool[SN + row*LDW + col]));
      }
    }
  }
  __syncthreads();

  // P7: final combine
  float alpha = alpha_p[0];
  if (MODE == 0){
    for (int j = tid; j < 1536; j += 512){
      int c = j >> 3, ty = j & 7;
      size_t goff = ((size_t)c*HWD + hrow + ty)*HWD + wcol;
      float* dst = outb + goff;
      float4 a = *reinterpret_cast<const float4*>(dst);
      float4 q = *reinterpret_cast<const float4*>(dst + 4);
      float wv[8];
      #pragma unroll
      for (int e = 0; e < 8; ++e) wv[e] = bf2f(pool[SM + (ty*8 + e)*LDW + c]);
      float4 o1 = make_float4(a.x + alpha*wv[0], a.y + alpha*wv[1], a.z + alpha*wv[2], a.w + alpha*wv[3]);
      float4 o2 = make_float4(q.x + alpha*wv[4], q.y + alpha*wv[5], q.z + alpha*wv[6], q.w + alpha*wv[7]);
      *reinterpret_cast<float4*>(dst)     = o1;
      *reinterpret_cast<float4*>(dst + 4) = o2;
    }
  } else {
    float beta = 1.f - alpha;
    const u16* xw = xoca + (size_t)win*12288;
    for (int j = tid; j < 1536; j += 512){
      int c = j >> 3, ty = j & 7;
      size_t goff = ((size_t)c*HWD + hrow + ty)*HWD + wcol;
      const float* src = xb + goff;
      float4 a = *reinterpret_cast<const float4*>(src);
      float4 q = *reinterpret_cast<const float4*>(src + 4);
      uint4 oc = *reinterpret_cast<const uint4*>(xw + c*64 + ty*8);
      float ov[8]; up8(oc, ov);
      float wv[8];
      #pragma unroll
      for (int e = 0; e < 8; ++e) wv[e] = bf2f(pool[SM + (ty*8 + e)*LDW + c]);
      float4 o1 = make_float4(a.x + alpha*wv[0] + beta*ov[0], a.y + alpha*wv[1] + beta*ov[1],
                              a.z + alpha*wv[2] + beta*ov[2], a.w + alpha*wv[3] + beta*ov[3]);
      float4 o2 = make_float4(q.x + alpha*wv[4] + beta*ov[4], q.y + alpha*wv[5] + beta*ov[5],
                              q.z + alpha*wv[6] + beta*ov[6], q.w + alpha*wv[7] + beta*ov[7]);
      *reinterpret_cast<float4*>(outb + goff)     = o1;
      *reinterpret_cast<float4*>(outb + goff + 4) = o2;
    }
  }
}

// ================= FALLBACK (round-2, VALU-only, no workspace) =================
__device__ __forceinline__ void layernorm_fb(const u16* __restrict__ src, u16* __restrict__ dst,
                                             const float* __restrict__ g, const float* __restrict__ b,
                                             int tid)
{
  int r = tid >> 3, sub = tid & 7;
  const u16* row = src + r*LDW + sub*24;
  float v[24];
  float s = 0.f, s2 = 0.f;
  #pragma unroll
  for (int e = 0; e < 24; ++e){ v[e] = bf2f(row[e]); s += v[e]; s2 += v[e]*v[e]; }
  s  += __shfl_xor(s, 1, 64);  s  += __shfl_xor(s, 2, 64);  s  += __shfl_xor(s, 4, 64);
  s2 += __shfl_xor(s2, 1, 64); s2 += __shfl_xor(s2, 2, 64); s2 += __shfl_xor(s2, 4, 64);
  float m   = s * (1.f/192.f);
  float var = s2 * (1.f/192.f) - m*m;
  float rs  = rsqrtf(var + 1e-5f);
  u16* drow = dst + r*LDW + sub*24;
  #pragma unroll
  for (int e = 0; e < 24; ++e)
    drow[e] = f2bf((v[e] - m) * rs * g[sub*24+e] + b[sub*24+e]);
}
__device__ __forceinline__ void gemm83(const u16* __restrict__ a_lds,
                                       const float* __restrict__ w0,
                                       const float* __restrict__ w1,
                                       const float* __restrict__ w2,
                                       int tg, float (*acc)[3])
{
  for (int k0 = 0; k0 < 192; k0 += 8){
    float wv[3][8];
    ldw8(w0 + k0, wv[0]); ldw8(w1 + k0, wv[1]); ldw8(w2 + k0, wv[2]);
    #pragma unroll
    for (int tt = 0; tt < 8; ++tt){
      float a[8];
      up8(*reinterpret_cast<const uint4*>(a_lds + (tg*8+tt)*LDW + k0), a);
      #pragma unroll
      for (int e = 0; e < 8; ++e){
        acc[tt][0] += a[e]*wv[0][e];
        acc[tt][1] += a[e]*wv[1][e];
        acc[tt][2] += a[e]*wv[2][e];
      }
    }
  }
}
__global__ __launch_bounds__(512) void k_msa_fb(
    const float* __restrict__ x, const float* __restrict__ g1, const float* __restrict__ b1,
    const float* __restrict__ qkv_w, const float* __restrict__ rpe, const float* __restrict__ wproj,
    const float* __restrict__ g2, const float* __restrict__ b2,
    const float* __restrict__ mlp1, const float* __restrict__ mlp2,
    const float* __restrict__ alpha_p, float* __restrict__ out)
{
  __shared__ __align__(16) u16 sX[64*LDW];
  __shared__ __align__(16) u16 sN[64*LDW];
  __shared__ __align__(16) u16 sM[64*LDW];
  __shared__ __align__(16) float sQ[64*QSTR];
  __shared__ __align__(16) float sK[64*QSTR];
  __shared__ __align__(16) float sV[64*QSTR];
  const int tid = threadIdx.x;
  const int win = blockIdx.x;
  const int b  = win >> 10;
  const int wy = (win >> 5) & 31;
  const int wx = win & 31;
  const int hrow = wy*8, wcol = wx*8;
  const float* xb = x + (size_t)b*CH*HWD*HWD;
  float* outb = out + (size_t)b*CH*HWD*HWD;
  for (int j = tid; j < 1536; j += 512){
    int c = j >> 3, ty = j & 7;
    const float* src = xb + ((size_t)c*HWD + hrow + ty)*HWD + wcol;
    float4 a = *reinterpret_cast<const float4*>(src);
    float4 q = *reinterpret_cast<const float4*>(src + 4);
    u16* dst = &sX[(ty*8)*LDW + c];
    dst[0*LDW]=f2bf(a.x); dst[1*LDW]=f2bf(a.y); dst[2*LDW]=f2bf(a.z); dst[3*LDW]=f2bf(a.w);
    dst[4*LDW]=f2bf(q.x); dst[5*LDW]=f2bf(q.y); dst[6*LDW]=f2bf(q.z); dst[7*LDW]=f2bf(q.w);
  }
  __syncthreads();
  layernorm_fb(sX, sN, g1, b1, tid);
  __syncthreads();
  const int t8 = tid >> 3, s8 = tid & 7;
  for (int h = 0; h < NH; ++h){
    {
      const u16* arow = &sN[t8*LDW];
      float acc[9];
      #pragma unroll
      for (int o = 0; o < 9; ++o) acc[o] = 0.f;
      const float* wp[9];
      #pragma unroll
      for (int o = 0; o < 3; ++o){
        const float* base = qkv_w + (size_t)(h*24 + s8*3 + o)*192;
        wp[o] = base; wp[3+o] = base + 192*192; wp[6+o] = base + 2*192*192;
      }
      for (int k0 = 0; k0 < 192; k0 += 8){
        float a[8]; up8(*reinterpret_cast<const uint4*>(arow + k0), a);
        #pragma unroll
        for (int o = 0; o < 9; ++o){
          float wv[8]; ldw8(wp[o] + k0, wv);
          #pragma unroll
          for (int e = 0; e < 8; ++e) acc[o] += a[e]*wv[e];
        }
      }
      #pragma unroll
      for (int o = 0; o < 3; ++o){
        sQ[t8*QSTR + s8*3 + o] = acc[o];
        sK[t8*QSTR + s8*3 + o] = acc[3+o];
        sV[t8*QSTR + s8*3 + o] = acc[6+o];
      }
    }
    __syncthreads();
    {
      float q24[24];
      #pragma unroll
      for (int e = 0; e < 24; ++e) q24[e] = sQ[t8*QSTR + e];
      const int ry = t8 >> 3, rx = t8 & 7;
      float p[8];
      #pragma unroll
      for (int j = 0; j < 8; ++j){
        int c = s8*8 + j;
        const float* kr = &sK[c*QSTR];
        float s = 0.f;
        #pragma unroll
        for (int e = 0; e < 24; ++e) s += q24[e]*kr[e];
        int cy = c >> 3, cx = c & 7;
        p[j] = s*SCALE + rpe[((ry-cy+7)*15 + (rx-cx+7))*NH + h];
      }
      float mx = p[0];
      #pragma unroll
      for (int j = 1; j < 8; ++j) mx = fmaxf(mx, p[j]);
      mx = fmaxf(mx, __shfl_xor(mx, 1, 64));
      mx = fmaxf(mx, __shfl_xor(mx, 2, 64));
      mx = fmaxf(mx, __shfl_xor(mx, 4, 64));
      float sum = 0.f;
      #pragma unroll
      for (int j = 0; j < 8; ++j){ p[j] = __expf(p[j] - mx); sum += p[j]; }
      sum += __shfl_xor(sum, 1, 64); sum += __shfl_xor(sum, 2, 64); sum += __shfl_xor(sum, 4, 64);
      float inv = 1.f / sum;
      float o24[24];
      #pragma unroll
      for (int e = 0; e < 24; ++e) o24[e] = 0.f;
      #pragma unroll
      for (int j = 0; j < 8; ++j){
        const float* vr = &sV[(s8*8 + j)*QSTR];
        #pragma unroll
        for (int e = 0; e < 24; ++e) o24[e] += p[j]*vr[e];
      }
      #pragma unroll
      for (int e = 0; e < 24; ++e){
        o24[e] += __shfl_xor(o24[e], 1, 64);
        o24[e] += __shfl_xor(o24[e], 2, 64);
        o24[e] += __shfl_xor(o24[e], 4, 64);
      }
      u16* mrow = &sM[t8*LDW + h*24 + s8*3];
      #pragma unroll
      for (int o = 0; o < 3; ++o) mrow[o] = f2bf(o24[s8*3 + o]*inv);
    }
    __syncthreads();
  }
  const int tg = tid >> 6, cg = tid & 63;
  {
    float acc[8][3];
    #pragma unroll
    for (int tt = 0; tt < 8; ++tt){ acc[tt][0]=0.f; acc[tt][1]=0.f; acc[tt][2]=0.f; }
    gemm83(sM, wproj + (size_t)(cg*3+0)*192, wproj + (size_t)(cg*3+1)*192, wproj + (size_t)(cg*3+2)*192, tg, acc);
    #pragma unroll
    for (int tt = 0; tt < 8; ++tt)
      #pragma unroll
      for (int j = 0; j < 3; ++j){
        int t = tg*8+tt, c = cg*3+j;
        sN[t*LDW + c] = f2bf(acc[tt][j] + bf2f(sX[t*LDW + c]));
      }
  }
  __syncthreads();
  layernorm_fb(sN, sX, g2, b2, tid);
  __syncthreads();
  float facc[8][3];
  #pragma unroll
  for (int tt = 0; tt < 8; ++tt){ facc[tt][0]=0.f; facc[tt][1]=0.f; facc[tt][2]=0.f; }
  for (int half = 0; half < 2; ++half){
    {
      float acc[8][3];
      #pragma unroll
      for (int tt = 0; tt < 8; ++tt){ acc[tt][0]=0.f; acc[tt][1]=0.f; acc[tt][2]=0.f; }
      gemm83(sX, mlp1 + (size_t)(half*192 + cg*3+0)*192, mlp1 + (size_t)(half*192 + cg*3+1)*192,
                 mlp1 + (size_t)(half*192 + cg*3+2)*192, tg, acc);
      #pragma unroll
      for (int tt = 0; tt < 8; ++tt)
        #pragma unroll
        for (int j = 0; j < 3; ++j){
          float vv = acc[tt][j];
          sM[(tg*8+tt)*LDW + cg*3+j] = f2bf(0.5f*vv*(1.f + erff(vv*0.70710678118654752f)));
        }
    }
    __syncthreads();
    gemm83(sM, mlp2 + (size_t)(cg*3+0)*384 + half*192, mlp2 + (size_t)(cg*3+1)*384 + half*192,
               mlp2 + (size_t)(cg*3+2)*384 + half*192, tg, facc);
    __syncthreads();
  }
  #pragma unroll
  for (int tt = 0; tt < 8; ++tt)
    #pragma unroll
    for (int j = 0; j < 3; ++j){
      int t = tg*8+tt, c = cg*3+j;
      sM[t*LDW + c] = f2bf(bf2f(sN[t*LDW + c]) + facc[tt][j]);
    }
  __syncthreads();
  float alpha = alpha_p[0];
  for (int j = tid; j < 1536; j += 512){
    int c = j >> 3, ty = j & 7;
    size_t goff = ((size_t)c*HWD + hrow + ty)*HWD + wcol;
    const float* src = xb + goff;
    float4 a = *reinterpret_cast<const float4*>(src);
    float4 q = *reinterpret_cast<const float4*>(src + 4);
    float wv[8];
    #pragma unroll
    for (int e = 0; e < 8; ++e) wv[e] = bf2f(sM[(ty*8 + e)*LDW + c]);
    float4 o1 = make_float4(a.x + alpha*wv[0], a.y + alpha*wv[1], a.z + alpha*wv[2], a.w + alpha*wv[3]);
    float4 o2 = make_float4(q.x + alpha*wv[4], q.y + alpha*wv[5], q.z + alpha*wv[6], q.w + alpha*wv[7]);
    *reinterpret_cast<float4*>(outb + goff)     = o1;
    *reinterpret_cast<float4*>(outb + goff + 4) = o2;
  }
}
__global__ __launch_bounds__(512) void k_oca_fb(
    const float* __restrict__ x, const float* __restrict__ og_p, const float* __restrict__ ob_p,
    const float* __restrict__ q_w, const float* __restrict__ kv_w, const float* __restrict__ oproj,
    const float* __restrict__ alpha_p, float* __restrict__ out)
{
  __shared__ __align__(16) u16 sW[64*LDW];
  __shared__ __align__(16) u16 sN[64*LDW];
  __shared__ __align__(16) u16 sQa[64*LDW];
  __shared__ __align__(16) u16 sU[144*LDW];
  __shared__ __align__(16) u16 sKb[144*32];
  __shared__ __align__(16) u16 sVb[144*32];
  const int tid = threadIdx.x;
  const int win = blockIdx.x;
  const int b  = win >> 10;
  const int wy = (win >> 5) & 31;
  const int wx = win & 31;
  const int hrow = wy*8, wcol = wx*8;
  const float* xb = x + (size_t)b*CH*HWD*HWD;
  float* outb = out + (size_t)b*CH*HWD*HWD;
  for (int j = tid; j < 1536; j += 512){
    int c = j >> 3, ty = j & 7;
    const float* src = xb + ((size_t)c*HWD + hrow + ty)*HWD + wcol;
    float4 a = *reinterpret_cast<const float4*>(src);
    float4 q = *reinterpret_cast<const float4*>(src + 4);
    u16* dst = &sW[(ty*8)*LDW + c];
    dst[0*LDW]=f2bf(a.x); dst[1*LDW]=f2bf(a.y); dst[2*LDW]=f2bf(a.z); dst[3*LDW]=f2bf(a.w);
    dst[4*LDW]=f2bf(q.x); dst[5*LDW]=f2bf(q.y); dst[6*LDW]=f2bf(q.z); dst[7*LDW]=f2bf(q.w);
  }
  for (int i = tid; i < 144*192; i += 512){
    int c = i / 144, t = i - c*144;
    int ti = t / 12, tj = t - ti*12;
    sU[t*LDW + c] = f2bf(xb[((size_t)c*HWD + refl(hrow + ti - 2))*HWD + refl(wcol + tj - 2)]);
  }
  __syncthreads();
  layernorm_fb(sW, sN, og_p, ob_p, tid);
  __syncthreads();
  const int tg = tid >> 6, cg = tid & 63;
  {
    float acc[8][3];
    #pragma unroll
    for (int tt = 0; tt < 8; ++tt){ acc[tt][0]=0.f; acc[tt][1]=0.f; acc[tt][2]=0.f; }
    gemm83(sN, q_w + (size_t)(cg*3+0)*192, q_w + (size_t)(cg*3+1)*192, q_w + (size_t)(cg*3+2)*192, tg, acc);
    #pragma unroll
    for (int tt = 0; tt < 8; ++tt)
      #pragma unroll
      for (int j = 0; j < 3; ++j)
        sQa[(tg*8+tt)*LDW + cg*3+j] = f2bf(acc[tt][j]);
  }
  __syncthreads();
  const int t8 = tid >> 3, s8 = tid & 7;
  for (int h = 0; h < NH; ++h){
    for (int i = tid; i < 144*24; i += 512){
      int tok = i / 24, d = i - tok*24;
      const float* kw = kv_w + (size_t)(h*24 + d)*192;
      const float* vw = kv_w + (size_t)(192 + h*24 + d)*192;
      const u16* arow = &sU[tok*LDW];
      float ka[4] = {0.f,0.f,0.f,0.f}, va[4] = {0.f,0.f,0.f,0.f};
      for (int k0 = 0; k0 < 192; k0 += 8){
        float a[8]; up8(*reinterpret_cast<const uint4*>(arow + k0), a);
        float kk[8]; ldw8(kw + k0, kk);
        float vv[8]; ldw8(vw + k0, vv);
        #pragma unroll
        for (int e = 0; e < 8; ++e){ ka[e&3] += a[e]*kk[e]; va[e&3] += a[e]*vv[e]; }
      }
      sKb[tok*32 + d] = f2bf(ka[0]+ka[1]+ka[2]+ka[3]);
      sVb[tok*32 + d] = f2bf(va[0]+va[1]+va[2]+va[3]);
    }
    __syncthreads();
    {
      float q24[24];
      #pragma unroll
      for (int e = 0; e < 24; ++e) q24[e] = bf2f(sQa[t8*LDW + h*24 + e]);
      float p[18];
      #pragma unroll
      for (int j = 0; j < 18; ++j){
        int c = s8*18 + j;
        const u16* kr = &sKb[c*32];
        float s = 0.f;
        #pragma unroll
        for (int e = 0; e < 24; ++e) s += q24[e]*bf2f(kr[e]);
        p[j] = s*SCALE;
      }
      float mx = p[0];
      #pragma unroll
      for (int j = 1; j < 18; ++j) mx = fmaxf(mx, p[j]);
      mx = fmaxf(mx, __shfl_xor(mx, 1, 64));
      mx = fmaxf(mx, __shfl_xor(mx, 2, 64));
      mx = fmaxf(mx, __shfl_xor(mx, 4, 64));
      float sum = 0.f;
      #pragma unroll
      for (int j = 0; j < 18; ++j){ p[j] = __expf(p[j] - mx); sum += p[j]; }
      sum += __shfl_xor(sum, 1, 64); sum += __shfl_xor(sum, 2, 64); sum += __shfl_xor(sum, 4, 64);
      float inv = 1.f / sum;
      float o24[24];
      #pragma unroll
      for (int e = 0; e < 24; ++e) o24[e] = 0.f;
      #pragma unroll
      for (int j = 0; j < 18; ++j){
        const u16* vr = &sVb[(s8*18 + j)*32];
        #pragma unroll
        for (int e = 0; e < 24; ++e) o24[e] += p[j]*bf2f(vr[e]);
      }
      #pragma unroll
      for (int e = 0; e < 24; ++e){
        o24[e] += __shfl_xor(o24[e], 1, 64);
        o24[e] += __shfl_xor(o24[e], 2, 64);
        o24[e] += __shfl_xor(o24[e], 4, 64);
      }
      u16* orow = &sN[t8*LDW + h*24 + s8*3];
      #pragma unroll
      for (int o = 0; o < 3; ++o) orow[o] = f2bf(o24[s8*3 + o]*inv);
    }
    __syncthreads();
  }
  {
    float acc[8][3];
    #pragma unroll
    for (int tt = 0; tt < 8; ++tt){ acc[tt][0]=0.f; acc[tt][1]=0.f; acc[tt][2]=0.f; }
    gemm83(sN, oproj + (size_t)(cg*3+0)*192, oproj + (size_t)(cg*3+1)*192, oproj + (size_t)(cg*3+2)*192, tg, acc);
    #pragma unroll
    for (int tt = 0; tt < 8; ++tt)
      #pragma unroll
      for (int j = 0; j < 3; ++j){
        int t = tg*8+tt, c = cg*3+j;
        sQa[t*LDW + c] = f2bf(acc[tt][j] + bf2f(sW[t*LDW + c]));
      }
  }
  __syncthreads();
  float beta = 1.f - alpha_p[0];
  for (int j = tid; j < 1536; j += 512){
    int c = j >> 3, ty = j & 7;
    size_t goff = ((size_t)c*HWD + hrow + ty)*HWD + wcol;
    float* dst = outb + goff;
    float4 a = *reinterpret_cast<const float4*>(dst);
    float4 q = *reinterpret_cast<const float4*>(dst + 4);
    float wv[8];
    #pragma unroll
    for (int e = 0; e < 8; ++e) wv[e] = bf2f(sQa[(ty*8 + e)*LDW + c]);
    float4 o1 = make_float4(a.x + beta*wv[0], a.y + beta*wv[1], a.z + beta*wv[2], a.w + beta*wv[3]);
    float4 o2 = make_float4(q.x + beta*wv[4], q.y + beta*wv[5], q.z + beta*wv[6], q.w + beta*wv[7]);
    *reinterpret_cast<float4*>(dst)     = o1;
    *reinterpret_cast<float4*>(dst + 4) = o2;
  }
}

extern "C" void kernel_launch(void* const* d_in, const int* in_sizes, int n_in,
                              void* d_out, int out_size, void* d_ws, size_t ws_size,
                              hipStream_t stream) {
  const float* x     = (const float*)d_in[0];
  const float* g1    = (const float*)d_in[1];
  const float* b1    = (const float*)d_in[2];
  const float* qkvw  = (const float*)d_in[3];
  const float* rpe   = (const float*)d_in[4];
  const float* wproj = (const float*)d_in[5];
  const float* g2    = (const float*)d_in[6];
  const float* b2    = (const float*)d_in[7];
  const float* mlp1  = (const float*)d_in[8];
  const float* mlp2  = (const float*)d_in[9];
  const float* alpha = (const float*)d_in[10];
  const float* og    = (const float*)d_in[11];
  const float* ob    = (const float*)d_in[12];
  const float* q_w   = (const float*)d_in[13];
  const float* kv_w  = (const float*)d_in[14];
  const float* oproj = (const float*)d_in[15];
  float* out = (float*)d_out;

  if (ws_size >= (size_t)WS_NEED) {
    u16*   ws16 = (u16*)d_ws;
    float* wsf  = (float*)d_ws;
    k_swz<<<36*6, 64, 0, stream>>>(qkvw,  g1,      ws16 + WS_W1/2,  6, 192);
    k_swz<<<24*6, 64, 0, stream>>>(kv_w,  nullptr, ws16 + WS_WKV/2, 6, 192);
    k_swz<<<12*6, 64, 0, stream>>>(q_w,   og,      ws16 + WS_WQ/2,  6, 192);
    k_swz<<<12*6, 64, 0, stream>>>(wproj, nullptr, ws16 + WS_WP/2,  6, 192);
    k_swz<<<24*6, 64, 0, stream>>>(mlp1,  g2,      ws16 + WS_WM1/2, 6, 192);
    k_swz<<<12*12,64, 0, stream>>>(mlp2,  nullptr, ws16 + WS_WM2/2, 12, 384);
    k_swz<<<12*6, 64, 0, stream>>>(oproj, nullptr, ws16 + WS_WO/2,  6, 192);
    k_cvec<<<576, 64, 0, stream>>>(qkvw, g1, b1, (float*)((char*)d_ws + WS_C1),  (float*)((char*)d_ws + WS_C2),  192);
    k_cvec<<<192, 64, 0, stream>>>(q_w,  og, ob, (float*)((char*)d_ws + WS_C1O), (float*)((char*)d_ws + WS_C2O), 192);
    k_cvec<<<384, 64, 0, stream>>>(mlp1, g2, b2, (float*)((char*)d_ws + WS_C1M), (float*)((char*)d_ws + WS_C2M), 192);
    k_kv<<<2048, 512, 0, stream>>>(x, ws16 + WS_WKV/2, ws16 + WS_KV/2);
    if (ws_size >= (size_t)WS_NEED1) {
      u16* xoca = ws16 + WS_XOCA/2;
      k_oca_attn<1><<<2048, 512, 0, stream>>>(x, ws16, wsf, alpha, out, xoca);
      k_msa<1><<<2048, 512, 0, stream>>>(x, ws16, wsf, rpe, alpha, out, xoca);
    } else {
      k_oca_attn<0><<<2048, 512, 0, stream>>>(x, ws16, wsf, alpha, out, nullptr);
      k_msa<0><<<2048, 512, 0, stream>>>(x, ws16, wsf, rpe, alpha, out, nullptr);
    }
  } else {
    k_msa_fb<<<2048, 512, 0, stream>>>(x, g1, b1, qkvw, rpe, wproj, g2, b2, mlp1, mlp2, alpha, out);
    k_oca_fb<<<2048, 512, 0, stream>>>(x, og, ob, q_w, kv_w, oproj, alpha, out);
  }
}

// Round 8
// 950.591 us; speedup vs baseline: 4.4952x; 1.1260x over previous
//
#include <hip/hip_runtime.h>
#include <hip/hip_bf16.h>

typedef unsigned short u16;
typedef unsigned int   u32;
typedef __attribute__((ext_vector_type(8))) short bf16x8;
typedef __attribute__((ext_vector_type(4))) float f32x4;

#define CH   192
#define NH   8
#define HWD  256
#define LDW  200   // bf16 row stride for 192-wide LDS tiles (400B)
#define QSTR 28
#define SCALE 0.20412414523193154f

__device__ __forceinline__ float bf2f(u16 u){ u32 v = ((u32)u) << 16; return __builtin_bit_cast(float, v); }
__device__ __forceinline__ u16 f2bf(float f){
  u32 u = __builtin_bit_cast(u32, f);
  u = (u + 0x7fffu + ((u >> 16) & 1u)) >> 16;
  return (u16)u;
}
__device__ __forceinline__ float lo2f(u32 p){ return __builtin_bit_cast(float, p << 16); }
__device__ __forceinline__ float hi2f(u32 p){ return __builtin_bit_cast(float, p & 0xffff0000u); }
__device__ __forceinline__ void up8(uint4 q, float* f){
  f[0]=lo2f(q.x); f[1]=hi2f(q.x); f[2]=lo2f(q.y); f[3]=hi2f(q.y);
  f[4]=lo2f(q.z); f[5]=hi2f(q.z); f[6]=lo2f(q.w); f[7]=hi2f(q.w);
}
__device__ __forceinline__ void ldw8(const float* __restrict__ p, float* f){
  float4 a = *reinterpret_cast<const float4*>(p);
  float4 b = *reinterpret_cast<const float4*>(p + 4);
  f[0]=a.x; f[1]=a.y; f[2]=a.z; f[3]=a.w;
  f[4]=b.x; f[5]=b.y; f[6]=b.z; f[7]=b.w;
}
__device__ __forceinline__ int refl(int v){ v = v < 0 ? -v : v; return v < HWD ? v : 2*(HWD-1) - v; }
__device__ __forceinline__ f32x4 mfma16(bf16x8 a, bf16x8 b, f32x4 c){
  return __builtin_amdgcn_mfma_f32_16x16x32_bf16(a, b, c, 0, 0, 0);
}
__device__ __forceinline__ bf16x8 afrag(const u16* pool, int base, int stride, int row, int kt, int l){
  return *reinterpret_cast<const bf16x8*>(pool + base + row*stride + kt*32 + ((l>>4)<<3));
}
__device__ __forceinline__ bf16x8 bfrag(const u16* __restrict__ w, int tile, int l){
  return *reinterpret_cast<const bf16x8*>(w + tile*512 + l*8);
}
__device__ __forceinline__ void ln_stats(const u16* buf, float* st, int tid){
  int r = tid >> 3, sub = tid & 7;
  const uint4* rp = reinterpret_cast<const uint4*>(buf + r*LDW + sub*24);
  float v[24]; up8(rp[0], v); up8(rp[1], v+8); up8(rp[2], v+16);
  float s = 0.f, s2 = 0.f;
  #pragma unroll
  for (int e = 0; e < 24; ++e){ s += v[e]; s2 += v[e]*v[e]; }
  s  += __shfl_xor(s, 1, 64);  s  += __shfl_xor(s, 2, 64);  s  += __shfl_xor(s, 4, 64);
  s2 += __shfl_xor(s2, 1, 64); s2 += __shfl_xor(s2, 2, 64); s2 += __shfl_xor(s2, 4, 64);
  if (sub == 0){
    float m = s*(1.f/192.f);
    float var = s2*(1.f/192.f) - m*m;
    st[r*2] = m; st[r*2+1] = rsqrtf(var + 1e-5f);
  }
}

// ---------------- workspace layout (bytes) ----------------
#define WS_KV   ((size_t)0)                     // 2*65536*384 bf16 = 100,663,296
#define WS_W1   ((size_t)100663296)
#define WS_WKV  (WS_W1  + 221184)
#define WS_WQ   (WS_WKV + 147456)
#define WS_WP   (WS_WQ  + 73728)
#define WS_WM1  (WS_WP  + 73728)
#define WS_WM2  (WS_WM1 + 147456)
#define WS_WO   (WS_WM2 + 147456)
#define WS_C1   (WS_WO  + 73728)
#define WS_C2   (WS_C1  + 2304)
#define WS_C1O  (WS_C2  + 2304)
#define WS_C2O  (WS_C1O + 768)
#define WS_C1M  (WS_C2O + 768)
#define WS_C2M  (WS_C1M + 1536)
#define WS_NEED (WS_C2M + 1536)                 // = 101,557,248
#define WS_XOCA WS_NEED                         // [2048][192][64] bf16 = 50,331,648
#define WS_NEED1 (WS_XOCA + 50331648)

// ---------------- prep kernels ----------------
__global__ void k_swz(const float* __restrict__ src, const float* __restrict__ gv,
                      u16* __restrict__ dst, int KT, int K){
  int tile = blockIdx.x; int nt = tile / KT, kt = tile - nt*KT;
  int l = threadIdx.x;
  int row = nt*16 + (l & 15);
  int kb  = kt*32 + ((l>>4)<<3);
  const float* s = src + (size_t)row*K + kb;
  u16* d = dst + (size_t)tile*512 + l*8;
  #pragma unroll
  for (int e = 0; e < 8; ++e){
    float w = s[e];
    if (gv) w *= gv[kb + e];
    d[e] = f2bf(w);
  }
}
__global__ void k_cvec(const float* __restrict__ W, const float* __restrict__ g,
                       const float* __restrict__ b, float* __restrict__ c1,
                       float* __restrict__ c2, int K){
  int n = blockIdx.x; int l = threadIdx.x;
  float s1 = 0.f, s2 = 0.f;
  for (int k = l; k < K; k += 64){
    float w = W[(size_t)n*K + k];
    s1 += w*g[k]; s2 += w*b[k];
  }
  #pragma unroll
  for (int d = 1; d < 64; d <<= 1){ s1 += __shfl_xor(s1, d, 64); s2 += __shfl_xor(s2, d, 64); }
  if (l == 0){ c1[n] = s1; c2[n] = s2; }
}

// ---------------- k_kv: per-pixel KV GEMM (dedup of unfold) ----------------
__global__ __launch_bounds__(512) void k_kv(const float* __restrict__ x,
                                            const u16* __restrict__ wkv,
                                            u16* __restrict__ KV){
  __shared__ __align__(16) u16 sA[64*LDW];
  const int blk = blockIdx.x;                // 2048
  const int batch = blk >> 10;
  const int pix0 = (blk & 1023) * 64;
  const float* xb = x + (size_t)batch*CH*65536;

  for (int idx = threadIdx.x; idx < 1536; idx += 512){
    int c = idx >> 3, s = idx & 7;
    const float* p = xb + (size_t)c*65536 + pix0 + s*8;
    float4 a = *reinterpret_cast<const float4*>(p);
    float4 b = *reinterpret_cast<const float4*>(p + 4);
    u16* d = &sA[(s*8)*LDW + c];
    d[0*LDW]=f2bf(a.x); d[1*LDW]=f2bf(a.y); d[2*LDW]=f2bf(a.z); d[3*LDW]=f2bf(a.w);
    d[4*LDW]=f2bf(b.x); d[5*LDW]=f2bf(b.y); d[6*LDW]=f2bf(b.z); d[7*LDW]=f2bf(b.w);
  }
  __syncthreads();

  const int w = threadIdx.x >> 6, l = threadIdx.x & 63;
  const int mt = w >> 1, half = w & 1;
  const f32x4 z4 = {0.f,0.f,0.f,0.f};
  f32x4 acc[12];
  #pragma unroll
  for (int j = 0; j < 12; ++j) acc[j] = z4;
  const int arow = mt*16 + (l & 15);
  for (int kt = 0; kt < 6; ++kt){
    bf16x8 a = afrag(sA, 0, LDW, arow, kt, l);
    #pragma unroll
    for (int j = 0; j < 12; ++j){
      int nt = half*12 + j;
      acc[j] = mfma16(a, bfrag(wkv, nt*6 + kt, l), acc[j]);
    }
  }
  u16* kvb = KV + ((size_t)batch*65536 + pix0)*384;
  const int rbase = mt*16 + ((l>>4)<<2);
  #pragma unroll
  for (int j = 0; j < 12; ++j){
    int col = (half*12 + j)*16 + (l & 15);
    #pragma unroll
    for (int r = 0; r < 4; ++r)
      kvb[(size_t)(rbase + r)*384 + col] = f2bf(acc[j][r]);
  }
}

// ---------------- k_oca_attn: MFMA cross attention ----------------
#define P_   0
#define OW_  0
#define XO_  0
#define OQ_  12800
#define KF_  25600
#define VT_  30208
#define STM_ 35584
#define STS_ 35840
#define OST_ 36096
#define OPOOLN 36352

template<int MODE>
__global__ __launch_bounds__(512) void k_oca_attn(
    const float* __restrict__ x, const u16* __restrict__ ws16, const float* __restrict__ wsf,
    const float* __restrict__ alpha_p, float* __restrict__ out, u16* __restrict__ xoca)
{
  __shared__ __align__(16) u16 pool[OPOOLN];
  float* stm = reinterpret_cast<float*>(pool + STM_);
  float* sts = reinterpret_cast<float*>(pool + STS_);
  float* st  = reinterpret_cast<float*>(pool + OST_);
  const u16* KV = ws16 + WS_KV/2;
  const u16* WQ = ws16 + WS_WQ/2;
  const u16* WO = ws16 + WS_WO/2;
  const float* c1o = wsf + WS_C1O/4;
  const float* c2o = wsf + WS_C2O/4;

  const int tid = threadIdx.x;
  const int win = blockIdx.x;
  const int b  = win >> 10;
  const int wy = (win >> 5) & 31;
  const int wx = win & 31;
  const int hrow = wy*8, wcol = wx*8;
  const float* xb = x + (size_t)b*CH*HWD*HWD;
  float* outb = out + (size_t)b*CH*HWD*HWD;
  const size_t pixBase = (size_t)b*65536;
  const f32x4 z4 = {0.f,0.f,0.f,0.f};

  for (int j = tid; j < 1536; j += 512){
    int c = j >> 3, ty = j & 7;
    const float* src = xb + ((size_t)c*HWD + hrow + ty)*HWD + wcol;
    float4 a = *reinterpret_cast<const float4*>(src);
    float4 q = *reinterpret_cast<const float4*>(src + 4);
    u16* dst = &pool[OW_ + (ty*8)*LDW + c];
    dst[0*LDW]=f2bf(a.x); dst[1*LDW]=f2bf(a.y); dst[2*LDW]=f2bf(a.z); dst[3*LDW]=f2bf(a.w);
    dst[4*LDW]=f2bf(q.x); dst[5*LDW]=f2bf(q.y); dst[6*LDW]=f2bf(q.z); dst[7*LDW]=f2bf(q.w);
  }
  __syncthreads();
  ln_stats(pool + OW_, st, tid);
  __syncthreads();

  const int w = tid >> 6, l = tid & 63;
  const int mt = w >> 1;
  const int arow = mt*16 + (l & 15);
  const int rbase = mt*16 + ((l>>4)<<2);

  {
    const int half = w & 1;
    f32x4 acc[6];
    #pragma unroll
    for (int j = 0; j < 6; ++j) acc[j] = z4;
    for (int kt = 0; kt < 6; ++kt){
      bf16x8 a = afrag(pool, OW_, LDW, arow, kt, l);
      #pragma unroll
      for (int j = 0; j < 6; ++j)
        acc[j] = mfma16(a, bfrag(WQ, (half*6 + j)*6 + kt, l), acc[j]);
    }
    float mr[4], rr[4];
    #pragma unroll
    for (int r = 0; r < 4; ++r){ mr[r] = st[(rbase+r)*2]; rr[r] = st[(rbase+r)*2+1]; }
    #pragma unroll
    for (int j = 0; j < 6; ++j){
      int col = (half*6 + j)*16 + (l & 15);
      float c1v = c1o[col], c2v = c2o[col];
      #pragma unroll
      for (int r = 0; r < 4; ++r)
        pool[OQ_ + (rbase + r)*LDW + col] = f2bf(SCALE*(rr[r]*(acc[j][r] - mr[r]*c1v) + c2v));
    }
  }
  __syncthreads();

  {
    const uint4 zz = make_uint4(0,0,0,0);
    for (int i = tid; i < 64; i += 512)
      *reinterpret_cast<uint4*>(pool + OQ_ + i*LDW + 192) = zz;
    for (int i = tid; i < 144; i += 512)
      *reinterpret_cast<uint4*>(pool + KF_ + (i>>4)*512 + 384 + (i&15)*8) = zz;
    for (int i = tid; i < 672; i += 512)
      *reinterpret_cast<uint4*>(pool + VT_ + i*8) = zz;
    for (int i = tid; i < 128; i += 512)
      *reinterpret_cast<uint4*>(pool + P_ + (i>>1)*168 + 144 + (i&1)*8) = zz;
  }
  __syncthreads();

  const int ng   = w & 1;
  const int ntlo = ng ? 4 : 0;
  const int ntn  = ng ? 5 : 4;

  for (int h = 0; h < NH; ++h){
    for (int i = tid; i < 432; i += 512){
      int tok = i / 3, seg = i - tok*3;
      int ti = tok / 12, tj = tok - ti*12;
      int pix = refl(hrow + ti - 2)*HWD + refl(wcol + tj - 2);
      const u16* src = KV + (pixBase + (size_t)pix)*384 + h*24 + seg*8;
      uint4 kk = *reinterpret_cast<const uint4*>(src);
      uint4 vv = *reinterpret_cast<const uint4*>(src + 192);
      *reinterpret_cast<uint4*>(pool + KF_ + (tok>>4)*512 + (seg*16 + (tok&15))*8) = kk;
      const u16* vp = reinterpret_cast<const u16*>(&vv);
      #pragma unroll
      for (int e = 0; e < 8; ++e)
        pool[VT_ + (seg*8 + e)*168 + tok] = vp[e];
    }
    __syncthreads();

    f32x4 S[5];
    #pragma unroll
    for (int t = 0; t < 5; ++t) S[t] = z4;
    {
      bf16x8 a = *reinterpret_cast<const bf16x8*>(pool + OQ_ + arow*LDW + h*24 + ((l>>4)<<3));
      #pragma unroll
      for (int t = 0; t < 5; ++t)
        if (t < ntn)
          S[t] = mfma16(a, *reinterpret_cast<const bf16x8*>(pool + KF_ + (ntlo + t)*512 + l*8), z4);
    }
    #pragma unroll
    for (int r = 0; r < 4; ++r){
      float mx = -3.0e38f;
      #pragma unroll
      for (int t = 0; t < 5; ++t) if (t < ntn) mx = fmaxf(mx, S[t][r]);
      mx = fmaxf(mx, __shfl_xor(mx, 1, 64));
      mx = fmaxf(mx, __shfl_xor(mx, 2, 64));
      mx = fmaxf(mx, __shfl_xor(mx, 4, 64));
      mx = fmaxf(mx, __shfl_xor(mx, 8, 64));
      if ((l & 15) == 0) stm[(rbase + r)*2 + ng] = mx;
    }
    __syncthreads();

    #pragma unroll
    for (int r = 0; r < 4; ++r){
      int row = rbase + r;
      float m = fmaxf(stm[row*2], stm[row*2 + 1]);
      float sum = 0.f;
      #pragma unroll
      for (int t = 0; t < 5; ++t) if (t < ntn){
        float p = __expf(S[t][r] - m);
        sum += p;
        pool[P_ + row*168 + (ntlo + t)*16 + (l & 15)] = f2bf(p);
      }
      sum += __shfl_xor(sum, 1, 64);
      sum += __shfl_xor(sum, 2, 64);
      sum += __shfl_xor(sum, 4, 64);
      sum += __shfl_xor(sum, 8, 64);
      if ((l & 15) == 0) sts[row*2 + ng] = sum;
    }
    __syncthreads();

    {
      f32x4 O = z4;
      #pragma unroll
      for (int kt = 0; kt < 5; ++kt){
        bf16x8 pa = *reinterpret_cast<const bf16x8*>(pool + P_  + arow*168 + kt*32 + ((l>>4)<<3));
        bf16x8 vb = *reinterpret_cast<const bf16x8*>(pool + VT_ + (ng*16 + (l & 15))*168 + kt*32 + ((l>>4)<<3));
        O = mfma16(pa, vb, O);
      }
      int d = ng*16 + (l & 15);
      if (d < 24){
        #pragma unroll
        for (int r = 0; r < 4; ++r){
          int row = rbase + r;
          float inv = 1.f / (sts[row*2] + sts[row*2 + 1]);
          pool[OQ_ + row*LDW + h*24 + d] = f2bf(O[r]*inv);
        }
      }
    }
    __syncthreads();
  }

  {
    const int half = w & 1;
    f32x4 acc[6];
    #pragma unroll
    for (int j = 0; j < 6; ++j) acc[j] = z4;
    for (int kt = 0; kt < 6; ++kt){
      bf16x8 a = afrag(pool, OQ_, LDW, arow, kt, l);
      #pragma unroll
      for (int j = 0; j < 6; ++j)
        acc[j] = mfma16(a, bfrag(WO, (half*6 + j)*6 + kt, l), acc[j]);
    }
    __syncthreads();
    #pragma unroll
    for (int j = 0; j < 6; ++j){
      int col = (half*6 + j)*16 + (l & 15);
      #pragma unroll
      for (int r = 0; r < 4; ++r)
        pool[XO_ + (rbase + r)*LDW + col] = f2bf(acc[j][r]);
    }
  }
  __syncthreads();

  if (MODE == 0){
    float beta = 1.f - alpha_p[0];
    float xg = 1.f + beta;
    for (int j = tid; j < 1536; j += 512){
      int c = j >> 3, ty = j & 7;
      size_t goff = ((size_t)c*HWD + hrow + ty)*HWD + wcol;
      const float* src = xb + goff;
      float4 a = *reinterpret_cast<const float4*>(src);
      float4 q = *reinterpret_cast<const float4*>(src + 4);
      float wv[8];
      #pragma unroll
      for (int e = 0; e < 8; ++e) wv[e] = bf2f(pool[XO_ + (ty*8 + e)*LDW + c]);
      float4 o1 = make_float4(xg*a.x + beta*wv[0], xg*a.y + beta*wv[1], xg*a.z + beta*wv[2], xg*a.w + beta*wv[3]);
      float4 o2 = make_float4(xg*q.x + beta*wv[4], xg*q.y + beta*wv[5], xg*q.z + beta*wv[6], xg*q.w + beta*wv[7]);
      *reinterpret_cast<float4*>(outb + goff)     = o1;
      *reinterpret_cast<float4*>(outb + goff + 4) = o2;
    }
  } else {
    u16* xw = xoca + (size_t)win*12288;
    for (int j = tid; j < 1536; j += 512){
      int c = j >> 3, ty = j & 7;
      size_t goff = ((size_t)c*HWD + hrow + ty)*HWD + wcol;
      const float* src = xb + goff;
      float4 a = *reinterpret_cast<const float4*>(src);
      float4 q = *reinterpret_cast<const float4*>(src + 4);
      float xv[8] = {a.x,a.y,a.z,a.w,q.x,q.y,q.z,q.w};
      u32 wds[4];
      #pragma unroll
      for (int e = 0; e < 4; ++e){
        u32 lo = f2bf(bf2f(pool[XO_ + (ty*8 + 2*e  )*LDW + c]) + xv[2*e]);
        u32 hi = f2bf(bf2f(pool[XO_ + (ty*8 + 2*e+1)*LDW + c]) + xv[2*e+1]);
        wds[e] = lo | (hi << 16);
      }
      uint4 o; o.x = wds[0]; o.y = wds[1]; o.z = wds[2]; o.w = wds[3];
      *reinterpret_cast<uint4*>(xw + c*64 + ty*8) = o;
    }
  }
}

// ---------------- k_msa: window MSA (MFMA attention) + MLP; final combine ----------------
// LDS (u16 offsets):
#define MSX  0        // x window [64][200]; later (with MSQ) gelu SG [64][392]
#define MSQ  12800    // q (scaled) [64][200]; attn-out overwrites per head
#define MKF  25600    // K frag order: 8 heads x 4 tiles x 512; later SN [64][200]
#define MVT  41984    // V^T [8][32][72]; later (from 38400) XW [64][200]
#define MP0  60416    // P ping [64][72]
#define MP1  65024    // P pong [64][72]
#define MSN  25600
#define MXW  38400
#define MSG  0
#define MSTM 69632    // f32 [4][64][2]
#define MSTS 70656    // f32 [2][64][2]
#define MST  71168    // f32 LN stats [128]
#define MPOOL 71424   // 142,848 bytes

template<int MODE>
__global__ __launch_bounds__(512) void k_msa(
    const float* __restrict__ x, const u16* __restrict__ ws16, const float* __restrict__ wsf,
    const float* __restrict__ rpe, const float* __restrict__ alpha_p, float* __restrict__ out,
    const u16* __restrict__ xoca)
{
  __shared__ __align__(16) u16 pool[MPOOL];
  float* stm = reinterpret_cast<float*>(pool + MSTM);
  float* sts = reinterpret_cast<float*>(pool + MSTS);
  float* st  = reinterpret_cast<float*>(pool + MST);
  const u16* W1  = ws16 + WS_W1/2;
  const u16* WP  = ws16 + WS_WP/2;
  const u16* WM1 = ws16 + WS_WM1/2;
  const u16* WM2 = ws16 + WS_WM2/2;
  const float* c1  = wsf + WS_C1/4;
  const float* c2  = wsf + WS_C2/4;
  const float* c1m = wsf + WS_C1M/4;
  const float* c2m = wsf + WS_C2M/4;

  const int tid = threadIdx.x;
  const int win = blockIdx.x;
  const int b  = win >> 10;
  const int wy = (win >> 5) & 31;
  const int wx = win & 31;
  const int hrow = wy*8, wcol = wx*8;
  const float* xb = x + (size_t)b*CH*HWD*HWD;
  float* outb = out + (size_t)b*CH*HWD*HWD;
  const f32x4 z4 = {0.f,0.f,0.f,0.f};

  // P0: window -> MSX; zero KF/VT/q-pad regions
  for (int j = tid; j < 1536; j += 512){
    int c = j >> 3, ty = j & 7;
    const float* src = xb + ((size_t)c*HWD + hrow + ty)*HWD + wcol;
    float4 a = *reinterpret_cast<const float4*>(src);
    float4 q = *reinterpret_cast<const float4*>(src + 4);
    u16* dst = &pool[MSX + (ty*8)*LDW + c];
    dst[0*LDW]=f2bf(a.x); dst[1*LDW]=f2bf(a.y); dst[2*LDW]=f2bf(a.z); dst[3*LDW]=f2bf(a.w);
    dst[4*LDW]=f2bf(q.x); dst[5*LDW]=f2bf(q.y); dst[6*LDW]=f2bf(q.z); dst[7*LDW]=f2bf(q.w);
  }
  {
    const uint4 zz = make_uint4(0,0,0,0);
    for (int i = tid; i < 2048; i += 512)           // all of MKF
      *reinterpret_cast<uint4*>(pool + MKF + i*8) = zz;
    for (int i = tid; i < 2304; i += 512)           // all of MVT
      *reinterpret_cast<uint4*>(pool + MVT + i*8) = zz;
    for (int i = tid; i < 64; i += 512)             // q pad cols 192..199
      *reinterpret_cast<uint4*>(pool + MSQ + i*LDW + 192) = zz;
  }
  __syncthreads();
  ln_stats(pool + MSX, st, tid);
  __syncthreads();

  const int w = tid >> 6, l = tid & 63;
  const int mt = w >> 1, half = w & 1;
  const int arow = mt*16 + (l & 15);
  const int rbase = mt*16 + ((l>>4)<<2);

  // P2a: qkv (LN folded) -> scatter q/K-frag/V^T
  {
    f32x4 acc[18];
    #pragma unroll
    for (int j = 0; j < 18; ++j) acc[j] = z4;
    for (int kt = 0; kt < 6; ++kt){
      bf16x8 a = afrag(pool, MSX, LDW, arow, kt, l);
      #pragma unroll
      for (int j = 0; j < 18; ++j)
        acc[j] = mfma16(a, bfrag(W1, (half*18 + j)*6 + kt, l), acc[j]);
    }
    float mr[4], rr[4];
    #pragma unroll
    for (int r = 0; r < 4; ++r){ mr[r] = st[(rbase+r)*2]; rr[r] = st[(rbase+r)*2+1]; }
    #pragma unroll
    for (int j = 0; j < 18; ++j){
      int tile = half*18 + j;
      int col = tile*16 + (l & 15);
      float c1v = c1[col], c2v = c2[col];
      if (tile < 12){
        #pragma unroll
        for (int r = 0; r < 4; ++r){
          int row = rbase + r;
          float v = rr[r]*(acc[j][r] - mr[r]*c1v) + c2v;
          pool[MSQ + row*LDW + col] = f2bf(SCALE*v);
        }
      } else if (tile < 24){
        int d = col - 192; int h = d/24; int dd = d - h*24;
        int base = MKF + h*2048 + ((((dd>>3)<<4))<<3) + (dd&7);
        #pragma unroll
        for (int r = 0; r < 4; ++r){
          int row = rbase + r;
          float v = rr[r]*(acc[j][r] - mr[r]*c1v) + c2v;
          pool[base + ((row>>4)<<9) + ((row&15)<<3)] = f2bf(v);
        }
      } else {
        int d = col - 384; int h = d/24; int dd = d - h*24;
        int base = MVT + h*2304 + dd*72;
        #pragma unroll
        for (int r = 0; r < 4; ++r){
          int row = rbase + r;
          float v = rr[r]*(acc[j][r] - mr[r]*c1v) + c2v;
          pool[base + row] = f2bf(v);
        }
      }
    }
  }
  __syncthreads();

  // P2b: MFMA window attention (RPE bias), heads in 2 groups of 4
  {
    const int ng = half;
    int bidx[2][4];
    #pragma unroll
    for (int t = 0; t < 2; ++t)
      #pragma unroll
      for (int r = 0; r < 4; ++r){
        int row = rbase + r, col = (ng*2 + t)*16 + (l & 15);
        bidx[t][r] = (((row>>3)-(col>>3)+7)*15 + ((row&7)-(col&7)+7))*NH;
      }
    for (int hg = 0; hg < 2; ++hg){
      f32x4 S[4][2];
      #pragma unroll
      for (int hh = 0; hh < 4; ++hh){
        int h = hg*4 + hh;
        bf16x8 a = *reinterpret_cast<const bf16x8*>(pool + MSQ + arow*LDW + h*24 + ((l>>4)<<3));
        #pragma unroll
        for (int t = 0; t < 2; ++t)
          S[hh][t] = mfma16(a, *reinterpret_cast<const bf16x8*>(pool + MKF + h*2048 + (ng*2+t)*512 + l*8), z4);
      }
      #pragma unroll
      for (int hh = 0; hh < 4; ++hh){
        int h = hg*4 + hh;
        #pragma unroll
        for (int t = 0; t < 2; ++t)
          #pragma unroll
          for (int r = 0; r < 4; ++r)
            S[hh][t][r] += rpe[bidx[t][r] + h];
        #pragma unroll
        for (int r = 0; r < 4; ++r){
          float mx = fmaxf(S[hh][0][r], S[hh][1][r]);
          mx = fmaxf(mx, __shfl_xor(mx, 1, 64));
          mx = fmaxf(mx, __shfl_xor(mx, 2, 64));
          mx = fmaxf(mx, __shfl_xor(mx, 4, 64));
          mx = fmaxf(mx, __shfl_xor(mx, 8, 64));
          if ((l & 15) == 0) stm[hh*128 + (rbase+r)*2 + ng] = mx;
        }
      }
      __syncthreads();   // group stats ready
      #pragma unroll
      for (int hh = 0; hh < 4; ++hh){
        int h = hg*4 + hh;
        u16* Pb = pool + ((h & 1) ? MP1 : MP0);
        float* sb = sts + (h & 1)*128;
        #pragma unroll
        for (int r = 0; r < 4; ++r){
          int row = rbase + r;
          float m = fmaxf(stm[hh*128 + row*2], stm[hh*128 + row*2 + 1]);
          float sum = 0.f;
          #pragma unroll
          for (int t = 0; t < 2; ++t){
            float p = __expf(S[hh][t][r] - m);
            sum += p;
            Pb[row*72 + (ng*2+t)*16 + (l & 15)] = f2bf(p);
          }
          sum += __shfl_xor(sum, 1, 64);
          sum += __shfl_xor(sum, 2, 64);
          sum += __shfl_xor(sum, 4, 64);
          sum += __shfl_xor(sum, 8, 64);
          if ((l & 15) == 0) sb[row*2 + ng] = sum;
        }
        __syncthreads();   // P + sums ready
        f32x4 O = z4;
        #pragma unroll
        for (int kt = 0; kt < 2; ++kt){
          bf16x8 pa = *reinterpret_cast<const bf16x8*>(Pb + arow*72 + kt*32 + ((l>>4)<<3));
          bf16x8 vb = *reinterpret_cast<const bf16x8*>(pool + MVT + h*2304 + (ng*16 + (l & 15))*72 + kt*32 + ((l>>4)<<3));
          O = mfma16(pa, vb, O);
        }
        int d = ng*16 + (l & 15);
        if (d < 24){
          #pragma unroll
          for (int r = 0; r < 4; ++r){
            int row = rbase + r;
            float inv = 1.f / (sb[row*2] + sb[row*2 + 1]);
            pool[MSQ + row*LDW + h*24 + d] = f2bf(O[r]*inv);
          }
        }
      }
    }
  }
  __syncthreads();

  // P3: xw2 = attn(MSQ) @ wproj^T + x(MSX) -> MSN
  {
    f32x4 acc[6];
    #pragma unroll
    for (int j = 0; j < 6; ++j) acc[j] = z4;
    for (int kt = 0; kt < 6; ++kt){
      bf16x8 a = afrag(pool, MSQ, LDW, arow, kt, l);
      #pragma unroll
      for (int j = 0; j < 6; ++j)
        acc[j] = mfma16(a, bfrag(WP, (half*6 + j)*6 + kt, l), acc[j]);
    }
    __syncthreads();  // MSN overlays MKF: ensure attention reads of MKF done (already by loop barriers; order store)
    #pragma unroll
    for (int j = 0; j < 6; ++j){
      int col = (half*6 + j)*16 + (l & 15);
      #pragma unroll
      for (int r = 0; r < 4; ++r){
        int row = rbase + r;
        pool[MSN + row*LDW + col] = f2bf(acc[j][r] + bf2f(pool[MSX + row*LDW + col]));
      }
    }
  }
  __syncthreads();
  ln_stats(pool + MSN, st, tid);
  __syncthreads();

  // P5: gelu(LN2-folded mlp1) -> MSG [64][392] (overlays MSX+MSQ)
  {
    f32x4 acc[12];
    #pragma unroll
    for (int j = 0; j < 12; ++j) acc[j] = z4;
    for (int kt = 0; kt < 6; ++kt){
      bf16x8 a = afrag(pool, MSN, LDW, arow, kt, l);
      #pragma unroll
      for (int j = 0; j < 12; ++j)
        acc[j] = mfma16(a, bfrag(WM1, (half*12 + j)*6 + kt, l), acc[j]);
    }
    float mr[4], rr[4];
    #pragma unroll
    for (int r = 0; r < 4; ++r){ mr[r] = st[(rbase+r)*2]; rr[r] = st[(rbase+r)*2+1]; }
    __syncthreads();  // MSG overlays MSX/MSQ: ensure P3's MSX reads complete
    #pragma unroll
    for (int j = 0; j < 12; ++j){
      int col = (half*12 + j)*16 + (l & 15);
      float c1v = c1m[col], c2v = c2m[col];
      #pragma unroll
      for (int r = 0; r < 4; ++r){
        float hv = rr[r]*(acc[j][r] - mr[r]*c1v) + c2v;
        float gl = 0.5f*hv*(1.f + erff(hv*0.70710678118654752f));
        pool[MSG + (rbase + r)*392 + col] = f2bf(gl);
      }
    }
  }
  __syncthreads();

  // P6: x_win = gelu @ mlp2^T + xw2 -> MXW
  {
    f32x4 acc[6];
    #pragma unroll
    for (int j = 0; j < 6; ++j) acc[j] = z4;
    for (int kt = 0; kt < 12; ++kt){
      bf16x8 a = afrag(pool, MSG, 392, arow, kt, l);
      #pragma unroll
      for (int j = 0; j < 6; ++j)
        acc[j] = mfma16(a, bfrag(WM2, (half*6 + j)*12 + kt, l), acc[j]);
    }
    #pragma unroll
    for (int j = 0; j < 6; ++j){
      int col = (half*6 + j)*16 + (l & 15);
      #pragma unroll
      for (int r = 0; r < 4; ++r){
        int row = rbase + r;
        pool[MXW + row*LDW + col] = f2bf(acc[j][r] + bf2f(pool[MSN + row*LDW + col]));
      }
    }
  }
  __syncthreads();

  // P7: final combine
  float alpha = alpha_p[0];
  if (MODE == 0){
    for (int j = tid; j < 1536; j += 512){
      int c = j >> 3, ty = j & 7;
      size_t goff = ((size_t)c*HWD + hrow + ty)*HWD + wcol;
      float* dst = outb + goff;
      float4 a = *reinterpret_cast<const float4*>(dst);
      float4 q = *reinterpret_cast<const float4*>(dst + 4);
      float wv[8];
      #pragma unroll
      for (int e = 0; e < 8; ++e) wv[e] = bf2f(pool[MXW + (ty*8 + e)*LDW + c]);
      float4 o1 = make_float4(a.x + alpha*wv[0], a.y + alpha*wv[1], a.z + alpha*wv[2], a.w + alpha*wv[3]);
      float4 o2 = make_float4(q.x + alpha*wv[4], q.y + alpha*wv[5], q.z + alpha*wv[6], q.w + alpha*wv[7]);
      *reinterpret_cast<float4*>(dst)     = o1;
      *reinterpret_cast<float4*>(dst + 4) = o2;
    }
  } else {
    float beta = 1.f - alpha;
    const u16* xw = xoca + (size_t)win*12288;
    for (int j = tid; j < 1536; j += 512){
      int c = j >> 3, ty = j & 7;
      size_t goff = ((size_t)c*HWD + hrow + ty)*HWD + wcol;
      const float* src = xb + goff;
      float4 a = *reinterpret_cast<const float4*>(src);
      float4 q = *reinterpret_cast<const float4*>(src + 4);
      uint4 oc = *reinterpret_cast<const uint4*>(xw + c*64 + ty*8);
      float ov[8]; up8(oc, ov);
      float wv[8];
      #pragma unroll
      for (int e = 0; e < 8; ++e) wv[e] = bf2f(pool[MXW + (ty*8 + e)*LDW + c]);
      float4 o1 = make_float4(a.x + alpha*wv[0] + beta*ov[0], a.y + alpha*wv[1] + beta*ov[1],
                              a.z + alpha*wv[2] + beta*ov[2], a.w + alpha*wv[3] + beta*ov[3]);
      float4 o2 = make_float4(q.x + alpha*wv[4] + beta*ov[4], q.y + alpha*wv[5] + beta*ov[5],
                              q.z + alpha*wv[6] + beta*ov[6], q.w + alpha*wv[7] + beta*ov[7]);
      *reinterpret_cast<float4*>(outb + goff)     = o1;
      *reinterpret_cast<float4*>(outb + goff + 4) = o2;
    }
  }
}

// ================= FALLBACK (round-2, VALU-only, no workspace) =================
__device__ __forceinline__ void layernorm_fb(const u16* __restrict__ src, u16* __restrict__ dst,
                                             const float* __restrict__ g, const float* __restrict__ b,
                                             int tid)
{
  int r = tid >> 3, sub = tid & 7;
  const u16* row = src + r*LDW + sub*24;
  float v[24];
  float s = 0.f, s2 = 0.f;
  #pragma unroll
  for (int e = 0; e < 24; ++e){ v[e] = bf2f(row[e]); s += v[e]; s2 += v[e]*v[e]; }
  s  += __shfl_xor(s, 1, 64);  s  += __shfl_xor(s, 2, 64);  s  += __shfl_xor(s, 4, 64);
  s2 += __shfl_xor(s2, 1, 64); s2 += __shfl_xor(s2, 2, 64); s2 += __shfl_xor(s2, 4, 64);
  float m   = s * (1.f/192.f);
  float var = s2 * (1.f/192.f) - m*m;
  float rs  = rsqrtf(var + 1e-5f);
  u16* drow = dst + r*LDW + sub*24;
  #pragma unroll
  for (int e = 0; e < 24; ++e)
    drow[e] = f2bf((v[e] - m) * rs * g[sub*24+e] + b[sub*24+e]);
}
__device__ __forceinline__ void gemm83(const u16* __restrict__ a_lds,
                                       const float* __restrict__ w0,
                                       const float* __restrict__ w1,
                                       const float* __restrict__ w2,
                                       int tg, float (*acc)[3])
{
  for (int k0 = 0; k0 < 192; k0 += 8){
    float wv[3][8];
    ldw8(w0 + k0, wv[0]); ldw8(w1 + k0, wv[1]); ldw8(w2 + k0, wv[2]);
    #pragma unroll
    for (int tt = 0; tt < 8; ++tt){
      float a[8];
      up8(*reinterpret_cast<const uint4*>(a_lds + (tg*8+tt)*LDW + k0), a);
      #pragma unroll
      for (int e = 0; e < 8; ++e){
        acc[tt][0] += a[e]*wv[0][e];
        acc[tt][1] += a[e]*wv[1][e];
        acc[tt][2] += a[e]*wv[2][e];
      }
    }
  }
}
__global__ __launch_bounds__(512) void k_msa_fb(
    const float* __restrict__ x, const float* __restrict__ g1, const float* __restrict__ b1,
    const float* __restrict__ qkv_w, const float* __restrict__ rpe, const float* __restrict__ wproj,
    const float* __restrict__ g2, const float* __restrict__ b2,
    const float* __restrict__ mlp1, const float* __restrict__ mlp2,
    const float* __restrict__ alpha_p, float* __restrict__ out)
{
  __shared__ __align__(16) u16 sX[64*LDW];
  __shared__ __align__(16) u16 sN[64*LDW];
  __shared__ __align__(16) u16 sM[64*LDW];
  __shared__ __align__(16) float sQ[64*QSTR];
  __shared__ __align__(16) float sK[64*QSTR];
  __shared__ __align__(16) float sV[64*QSTR];
  const int tid = threadIdx.x;
  const int win = blockIdx.x;
  const int b  = win >> 10;
  const int wy = (win >> 5) & 31;
  const int wx = win & 31;
  const int hrow = wy*8, wcol = wx*8;
  const float* xb = x + (size_t)b*CH*HWD*HWD;
  float* outb = out + (size_t)b*CH*HWD*HWD;
  for (int j = tid; j < 1536; j += 512){
    int c = j >> 3, ty = j & 7;
    const float* src = xb + ((size_t)c*HWD + hrow + ty)*HWD + wcol;
    float4 a = *reinterpret_cast<const float4*>(src);
    float4 q = *reinterpret_cast<const float4*>(src + 4);
    u16* dst = &sX[(ty*8)*LDW + c];
    dst[0*LDW]=f2bf(a.x); dst[1*LDW]=f2bf(a.y); dst[2*LDW]=f2bf(a.z); dst[3*LDW]=f2bf(a.w);
    dst[4*LDW]=f2bf(q.x); dst[5*LDW]=f2bf(q.y); dst[6*LDW]=f2bf(q.z); dst[7*LDW]=f2bf(q.w);
  }
  __syncthreads();
  layernorm_fb(sX, sN, g1, b1, tid);
  __syncthreads();
  const int t8 = tid >> 3, s8 = tid & 7;
  for (int h = 0; h < NH; ++h){
    {
      const u16* arow = &sN[t8*LDW];
      float acc[9];
      #pragma unroll
      for (int o = 0; o < 9; ++o) acc[o] = 0.f;
      const float* wp[9];
      #pragma unroll
      for (int o = 0; o < 3; ++o){
        const float* base = qkv_w + (size_t)(h*24 + s8*3 + o)*192;
        wp[o] = base; wp[3+o] = base + 192*192; wp[6+o] = base + 2*192*192;
      }
      for (int k0 = 0; k0 < 192; k0 += 8){
        float a[8]; up8(*reinterpret_cast<const uint4*>(arow + k0), a);
        #pragma unroll
        for (int o = 0; o < 9; ++o){
          float wv[8]; ldw8(wp[o] + k0, wv);
          #pragma unroll
          for (int e = 0; e < 8; ++e) acc[o] += a[e]*wv[e];
        }
      }
      #pragma unroll
      for (int o = 0; o < 3; ++o){
        sQ[t8*QSTR + s8*3 + o] = acc[o];
        sK[t8*QSTR + s8*3 + o] = acc[3+o];
        sV[t8*QSTR + s8*3 + o] = acc[6+o];
      }
    }
    __syncthreads();
    {
      float q24[24];
      #pragma unroll
      for (int e = 0; e < 24; ++e) q24[e] = sQ[t8*QSTR + e];
      const int ry = t8 >> 3, rx = t8 & 7;
      float p[8];
      #pragma unroll
      for (int j = 0; j < 8; ++j){
        int c = s8*8 + j;
        const float* kr = &sK[c*QSTR];
        float s = 0.f;
        #pragma unroll
        for (int e = 0; e < 24; ++e) s += q24[e]*kr[e];
        int cy = c >> 3, cx = c & 7;
        p[j] = s*SCALE + rpe[((ry-cy+7)*15 + (rx-cx+7))*NH + h];
      }
      float mx = p[0];
      #pragma unroll
      for (int j = 1; j < 8; ++j) mx = fmaxf(mx, p[j]);
      mx = fmaxf(mx, __shfl_xor(mx, 1, 64));
      mx = fmaxf(mx, __shfl_xor(mx, 2, 64));
      mx = fmaxf(mx, __shfl_xor(mx, 4, 64));
      float sum = 0.f;
      #pragma unroll
      for (int j = 0; j < 8; ++j){ p[j] = __expf(p[j] - mx); sum += p[j]; }
      sum += __shfl_xor(sum, 1, 64); sum += __shfl_xor(sum, 2, 64); sum += __shfl_xor(sum, 4, 64);
      float inv = 1.f / sum;
      float o24[24];
      #pragma unroll
      for (int e = 0; e < 24; ++e) o24[e] = 0.f;
      #pragma unroll
      for (int j = 0; j < 8; ++j){
        const float* vr = &sV[(s8*8 + j)*QSTR];
        #pragma unroll
        for (int e = 0; e < 24; ++e) o24[e] += p[j]*vr[e];
      }
      #pragma unroll
      for (int e = 0; e < 24; ++e){
        o24[e] += __shfl_xor(o24[e], 1, 64);
        o24[e] += __shfl_xor(o24[e], 2, 64);
        o24[e] += __shfl_xor(o24[e], 4, 64);
      }
      u16* mrow = &sM[t8*LDW + h*24 + s8*3];
      #pragma unroll
      for (int o = 0; o < 3; ++o) mrow[o] = f2bf(o24[s8*3 + o]*inv);
    }
    __syncthreads();
  }
  const int tg = tid >> 6, cg = tid & 63;
  {
    float acc[8][3];
    #pragma unroll
    for (int tt = 0; tt < 8; ++tt){ acc[tt][0]=0.f; acc[tt][1]=0.f; acc[tt][2]=0.f; }
    gemm83(sM, wproj + (size_t)(cg*3+0)*192, wproj + (size_t)(cg*3+1)*192, wproj + (size_t)(cg*3+2)*192, tg, acc);
    #pragma unroll
    for (int tt = 0; tt < 8; ++tt)
      #pragma unroll
      for (int j = 0; j < 3; ++j){
        int t = tg*8+tt, c = cg*3+j;
        sN[t*LDW + c] = f2bf(acc[tt][j] + bf2f(sX[t*LDW + c]));
      }
  }
  __syncthreads();
  layernorm_fb(sN, sX, g2, b2, tid);
  __syncthreads();
  float facc[8][3];
  #pragma unroll
  for (int tt = 0; tt < 8; ++tt){ facc[tt][0]=0.f; facc[tt][1]=0.f; facc[tt][2]=0.f; }
  for (int half = 0; half < 2; ++half){
    {
      float acc[8][3];
      #pragma unroll
      for (int tt = 0; tt < 8; ++tt){ acc[tt][0]=0.f; acc[tt][1]=0.f; acc[tt][2]=0.f; }
      gemm83(sX, mlp1 + (size_t)(half*192 + cg*3+0)*192, mlp1 + (size_t)(half*192 + cg*3+1)*192,
                 mlp1 + (size_t)(half*192 + cg*3+2)*192, tg, acc);
      #pragma unroll
      for (int tt = 0; tt < 8; ++tt)
        #pragma unroll
        for (int j = 0; j < 3; ++j){
          float vv = acc[tt][j];
          sM[(tg*8+tt)*LDW + cg*3+j] = f2bf(0.5f*vv*(1.f + erff(vv*0.70710678118654752f)));
        }
    }
    __syncthreads();
    gemm83(sM, mlp2 + (size_t)(cg*3+0)*384 + half*192, mlp2 + (size_t)(cg*3+1)*384 + half*192,
               mlp2 + (size_t)(cg*3+2)*384 + half*192, tg, facc);
    __syncthreads();
  }
  #pragma unroll
  for (int tt = 0; tt < 8; ++tt)
    #pragma unroll
    for (int j = 0; j < 3; ++j){
      int t = tg*8+tt, c = cg*3+j;
      sM[t*LDW + c] = f2bf(bf2f(sN[t*LDW + c]) + facc[tt][j]);
    }
  __syncthreads();
  float alpha = alpha_p[0];
  for (int j = tid; j < 1536; j += 512){
    int c = j >> 3, ty = j & 7;
    size_t goff = ((size_t)c*HWD + hrow + ty)*HWD + wcol;
    const float* src = xb + goff;
    float4 a = *reinterpret_cast<const float4*>(src);
    float4 q = *reinterpret_cast<const float4*>(src + 4);
    float wv[8];
    #pragma unroll
    for (int e = 0; e < 8; ++e) wv[e] = bf2f(sM[(ty*8 + e)*LDW + c]);
    float4 o1 = make_float4(a.x + alpha*wv[0], a.y + alpha*wv[1], a.z + alpha*wv[2], a.w + alpha*wv[3]);
    float4 o2 = make_float4(q.x + alpha*wv[4], q.y + alpha*wv[5], q.z + alpha*wv[6], q.w + alpha*wv[7]);
    *reinterpret_cast<float4*>(outb + goff)     = o1;
    *reinterpret_cast<float4*>(outb + goff + 4) = o2;
  }
}
__global__ __launch_bounds__(512) void k_oca_fb(
    const float* __restrict__ x, const float* __restrict__ og_p, const float* __restrict__ ob_p,
    const float* __restrict__ q_w, const float* __restrict__ kv_w, const float* __restrict__ oproj,
    const float* __restrict__ alpha_p, float* __restrict__ out)
{
  __shared__ __align__(16) u16 sW[64*LDW];
  __shared__ __align__(16) u16 sN[64*LDW];
  __shared__ __align__(16) u16 sQa[64*LDW];
  __shared__ __align__(16) u16 sU[144*LDW];
  __shared__ __align__(16) u16 sKb[144*32];
  __shared__ __align__(16) u16 sVb[144*32];
  const int tid = threadIdx.x;
  const int win = blockIdx.x;
  const int b  = win >> 10;
  const int wy = (win >> 5) & 31;
  const int wx = win & 31;
  const int hrow = wy*8, wcol = wx*8;
  const float* xb = x + (size_t)b*CH*HWD*HWD;
  float* outb = out + (size_t)b*CH*HWD*HWD;
  for (int j = tid; j < 1536; j += 512){
    int c = j >> 3, ty = j & 7;
    const float* src = xb + ((size_t)c*HWD + hrow + ty)*HWD + wcol;
    float4 a = *reinterpret_cast<const float4*>(src);
    float4 q = *reinterpret_cast<const float4*>(src + 4);
    u16* dst = &sW[(ty*8)*LDW + c];
    dst[0*LDW]=f2bf(a.x); dst[1*LDW]=f2bf(a.y); dst[2*LDW]=f2bf(a.z); dst[3*LDW]=f2bf(a.w);
    dst[4*LDW]=f2bf(q.x); dst[5*LDW]=f2bf(q.y); dst[6*LDW]=f2bf(q.z); dst[7*LDW]=f2bf(q.w);
  }
  for (int i = tid; i < 144*192; i += 512){
    int c = i / 144, t = i - c*144;
    int ti = t / 12, tj = t - ti*12;
    sU[t*LDW + c] = f2bf(xb[((size_t)c*HWD + refl(hrow + ti - 2))*HWD + refl(wcol + tj - 2)]);
  }
  __syncthreads();
  layernorm_fb(sW, sN, og_p, ob_p, tid);
  __syncthreads();
  const int tg = tid >> 6, cg = tid & 63;
  {
    float acc[8][3];
    #pragma unroll
    for (int tt = 0; tt < 8; ++tt){ acc[tt][0]=0.f; acc[tt][1]=0.f; acc[tt][2]=0.f; }
    gemm83(sN, q_w + (size_t)(cg*3+0)*192, q_w + (size_t)(cg*3+1)*192, q_w + (size_t)(cg*3+2)*192, tg, acc);
    #pragma unroll
    for (int tt = 0; tt < 8; ++tt)
      #pragma unroll
      for (int j = 0; j < 3; ++j)
        sQa[(tg*8+tt)*LDW + cg*3+j] = f2bf(acc[tt][j]);
  }
  __syncthreads();
  const int t8 = tid >> 3, s8 = tid & 7;
  for (int h = 0; h < NH; ++h){
    for (int i = tid; i < 144*24; i += 512){
      int tok = i / 24, d = i - tok*24;
      const float* kw = kv_w + (size_t)(h*24 + d)*192;
      const float* vw = kv_w + (size_t)(192 + h*24 + d)*192;
      const u16* arow = &sU[tok*LDW];
      float ka[4] = {0.f,0.f,0.f,0.f}, va[4] = {0.f,0.f,0.f,0.f};
      for (int k0 = 0; k0 < 192; k0 += 8){
        float a[8]; up8(*reinterpret_cast<const uint4*>(arow + k0), a);
        float kk[8]; ldw8(kw + k0, kk);
        float vv[8]; ldw8(vw + k0, vv);
        #pragma unroll
        for (int e = 0; e < 8; ++e){ ka[e&3] += a[e]*kk[e]; va[e&3] += a[e]*vv[e]; }
      }
      sKb[tok*32 + d] = f2bf(ka[0]+ka[1]+ka[2]+ka[3]);
      sVb[tok*32 + d] = f2bf(va[0]+va[1]+va[2]+va[3]);
    }
    __syncthreads();
    {
      float q24[24];
      #pragma unroll
      for (int e = 0; e < 24; ++e) q24[e] = bf2f(sQa[t8*LDW + h*24 + e]);
      float p[18];
      #pragma unroll
      for (int j = 0; j < 18; ++j){
        int c = s8*18 + j;
        const u16* kr = &sKb[c*32];
        float s = 0.f;
        #pragma unroll
        for (int e = 0; e < 24; ++e) s += q24[e]*bf2f(kr[e]);
        p[j] = s*SCALE;
      }
      float mx = p[0];
      #pragma unroll
      for (int j = 1; j < 18; ++j) mx = fmaxf(mx, p[j]);
      mx = fmaxf(mx, __shfl_xor(mx, 1, 64));
      mx = fmaxf(mx, __shfl_xor(mx, 2, 64));
      mx = fmaxf(mx, __shfl_xor(mx, 4, 64));
      float sum = 0.f;
      #pragma unroll
      for (int j = 0; j < 18; ++j){ p[j] = __expf(p[j] - mx); sum += p[j]; }
      sum += __shfl_xor(sum, 1, 64); sum += __shfl_xor(sum, 2, 64); sum += __shfl_xor(sum, 4, 64);
      float inv = 1.f / sum;
      float o24[24];
      #pragma unroll
      for (int e = 0; e < 24; ++e) o24[e] = 0.f;
      #pragma unroll
      for (int j = 0; j < 18; ++j){
        const u16* vr = &sVb[(s8*18 + j)*32];
        #pragma unroll
        for (int e = 0; e < 24; ++e) o24[e] += p[j]*bf2f(vr[e]);
      }
      #pragma unroll
      for (int e = 0; e < 24; ++e){
        o24[e] += __shfl_xor(o24[e], 1, 64);
        o24[e] += __shfl_xor(o24[e], 2, 64);
        o24[e] += __shfl_xor(o24[e], 4, 64);
      }
      u16* orow = &sN[t8*LDW + h*24 + s8*3];
      #pragma unroll
      for (int o = 0; o < 3; ++o) orow[o] = f2bf(o24[s8*3 + o]*inv);
    }
    __syncthreads();
  }
  {
    float acc[8][3];
    #pragma unroll
    for (int tt = 0; tt < 8; ++tt){ acc[tt][0]=0.f; acc[tt][1]=0.f; acc[tt][2]=0.f; }
    gemm83(sN, oproj + (size_t)(cg*3+0)*192, oproj + (size_t)(cg*3+1)*192, oproj + (size_t)(cg*3+2)*192, tg, acc);
    #pragma unroll
    for (int tt = 0; tt < 8; ++tt)
      #pragma unroll
      for (int j = 0; j < 3; ++j){
        int t = tg*8+tt, c = cg*3+j;
        sQa[t*LDW + c] = f2bf(acc[tt][j] + bf2f(sW[t*LDW + c]));
      }
  }
  __syncthreads();
  float beta = 1.f - alpha_p[0];
  for (int j = tid; j < 1536; j += 512){
    int c = j >> 3, ty = j & 7;
    size_t goff = ((size_t)c*HWD + hrow + ty)*HWD + wcol;
    float* dst = outb + goff;
    float4 a = *reinterpret_cast<const float4*>(dst);
    float4 q = *reinterpret_cast<const float4*>(dst + 4);
    float wv[8];
    #pragma unroll
    for (int e = 0; e < 8; ++e) wv[e] = bf2f(sQa[(ty*8 + e)*LDW + c]);
    float4 o1 = make_float4(a.x + beta*wv[0], a.y + beta*wv[1], a.z + beta*wv[2], a.w + beta*wv[3]);
    float4 o2 = make_float4(q.x + beta*wv[4], q.y + beta*wv[5], q.z + beta*wv[6], q.w + beta*wv[7]);
    *reinterpret_cast<float4*>(dst)     = o1;
    *reinterpret_cast<float4*>(dst + 4) = o2;
  }
}

extern "C" void kernel_launch(void* const* d_in, const int* in_sizes, int n_in,
                              void* d_out, int out_size, void* d_ws, size_t ws_size,
                              hipStream_t stream) {
  const float* x     = (const float*)d_in[0];
  const float* g1    = (const float*)d_in[1];
  const float* b1    = (const float*)d_in[2];
  const float* qkvw  = (const float*)d_in[3];
  const float* rpe   = (const float*)d_in[4];
  const float* wproj = (const float*)d_in[5];
  const float* g2    = (const float*)d_in[6];
  const float* b2    = (const float*)d_in[7];
  const float* mlp1  = (const float*)d_in[8];
  const float* mlp2  = (const float*)d_in[9];
  const float* alpha = (const float*)d_in[10];
  const float* og    = (const float*)d_in[11];
  const float* ob    = (const float*)d_in[12];
  const float* q_w   = (const float*)d_in[13];
  const float* kv_w  = (const float*)d_in[14];
  const float* oproj = (const float*)d_in[15];
  float* out = (float*)d_out;

  if (ws_size >= (size_t)WS_NEED) {
    u16*   ws16 = (u16*)d_ws;
    float* wsf  = (float*)d_ws;
    k_swz<<<36*6, 64, 0, stream>>>(qkvw,  g1,      ws16 + WS_W1/2,  6, 192);
    k_swz<<<24*6, 64, 0, stream>>>(kv_w,  nullptr, ws16 + WS_WKV/2, 6, 192);
    k_swz<<<12*6, 64, 0, stream>>>(q_w,   og,      ws16 + WS_WQ/2,  6, 192);
    k_swz<<<12*6, 64, 0, stream>>>(wproj, nullptr, ws16 + WS_WP/2,  6, 192);
    k_swz<<<24*6, 64, 0, stream>>>(mlp1,  g2,      ws16 + WS_WM1/2, 6, 192);
    k_swz<<<12*12,64, 0, stream>>>(mlp2,  nullptr, ws16 + WS_WM2/2, 12, 384);
    k_swz<<<12*6, 64, 0, stream>>>(oproj, nullptr, ws16 + WS_WO/2,  6, 192);
    k_cvec<<<576, 64, 0, stream>>>(qkvw, g1, b1, (float*)((char*)d_ws + WS_C1),  (float*)((char*)d_ws + WS_C2),  192);
    k_cvec<<<192, 64, 0, stream>>>(q_w,  og, ob, (float*)((char*)d_ws + WS_C1O), (float*)((char*)d_ws + WS_C2O), 192);
    k_cvec<<<384, 64, 0, stream>>>(mlp1, g2, b2, (float*)((char*)d_ws + WS_C1M), (float*)((char*)d_ws + WS_C2M), 192);
    k_kv<<<2048, 512, 0, stream>>>(x, ws16 + WS_WKV/2, ws16 + WS_KV/2);
    if (ws_size >= (size_t)WS_NEED1) {
      u16* xoca = ws16 + WS_XOCA/2;
      k_oca_attn<1><<<2048, 512, 0, stream>>>(x, ws16, wsf, alpha, out, xoca);
      k_msa<1><<<2048, 512, 0, stream>>>(x, ws16, wsf, rpe, alpha, out, xoca);
    } else {
      k_oca_attn<0><<<2048, 512, 0, stream>>>(x, ws16, wsf, alpha, out, nullptr);
      k_msa<0><<<2048, 512, 0, stream>>>(x, ws16, wsf, rpe, alpha, out, nullptr);
    }
  } else {
    k_msa_fb<<<2048, 512, 0, stream>>>(x, g1, b1, qkvw, rpe, wproj, g2, b2, mlp1, mlp2, alpha, out);
    k_oca_fb<<<2048, 512, 0, stream>>>(x, og, ob, q_w, kv_w, oproj, alpha, out);
  }
}